// Round 1
// baseline (4155.333 us; speedup 1.0000x reference)
//
#include <hip/hip_runtime.h>
#include <math.h>

#define NI 100000
#define NF 2000
#define NE 800000
#define NEF 200000
#define DN 16
#define NL 11

__device__ __forceinline__ float elu1(float x) { return x > 0.f ? x : expm1f(x); }

// ---------------- CSR build ----------------
__global__ __launch_bounds__(256) void k_count(const int* __restrict__ prev_src,
                                               const int* __restrict__ prev_dst,
                                               const int* __restrict__ tf_dst,
                                               int* cntP, int* cntS, int* cntF) {
    int i = blockIdx.x * blockDim.x + threadIdx.x;
    if (i < NE) {
        atomicAdd(&cntP[prev_dst[i]], 1);
        atomicAdd(&cntS[prev_src[i]], 1);
    }
    if (i < NEF) atomicAdd(&cntF[tf_dst[i]], 1);
}

__global__ __launch_bounds__(256) void k_scan1(const int* __restrict__ cnt, int n,
                                               int* __restrict__ rp, int* __restrict__ bsum) {
    __shared__ int s[256];
    int t = threadIdx.x, b = blockIdx.x, i = b * 256 + t;
    int v = (i < n) ? cnt[i] : 0;
    s[t] = v; __syncthreads();
    for (int o = 1; o < 256; o <<= 1) {
        int x = (t >= o) ? s[t - o] : 0;
        __syncthreads();
        s[t] += x;
        __syncthreads();
    }
    if (i < n) rp[i + 1] = s[t];
    if (t == 255) bsum[b] = s[255];
}

__global__ __launch_bounds__(512) void k_scan2(int* __restrict__ bsum, int nb) {
    __shared__ int s[512];
    int t = threadIdx.x;
    int v = (t < nb) ? bsum[t] : 0;
    s[t] = v; __syncthreads();
    for (int o = 1; o < 512; o <<= 1) {
        int x = (t >= o) ? s[t - o] : 0;
        __syncthreads();
        s[t] += x;
        __syncthreads();
    }
    if (t < nb) bsum[t] = s[t] - v;   // exclusive block offsets
}

__global__ __launch_bounds__(256) void k_scan3(int* __restrict__ rp, const int* __restrict__ bsum, int n) {
    int i = blockIdx.x * blockDim.x + threadIdx.x;
    if (i < n) rp[i + 1] += bsum[i >> 8];
    if (i == 0) rp[0] = 0;
}

__global__ __launch_bounds__(256) void k_scatter(const int* __restrict__ prev_src,
                                                 const int* __restrict__ prev_dst,
                                                 const int* __restrict__ tf_src,
                                                 const int* __restrict__ tf_dst,
                                                 const int* __restrict__ rpP,
                                                 const int* __restrict__ rpS,
                                                 const int* __restrict__ rpF,
                                                 int* fillP, int* fillS, int* fillF,
                                                 int* colP, int* colS, int* colF) {
    int i = blockIdx.x * blockDim.x + threadIdx.x;
    if (i < NE) {
        int s = prev_src[i], d = prev_dst[i];
        colP[rpP[d] + atomicAdd(&fillP[d], 1)] = s;
        colS[rpS[s] + atomicAdd(&fillS[s], 1)] = d;
    }
    if (i < NEF) {
        int s = tf_src[i], d = tf_dst[i];
        colF[rpF[d] + atomicAdd(&fillF[d], 1)] = s;
    }
}

// ---------------- edge embed + scatter-add of edge-feature sums ----------------
__global__ __launch_bounds__(256) void k_edge_embed(const float* __restrict__ xe,
                                                    const float* __restrict__ xef,
                                                    const int* __restrict__ prev_src,
                                                    const int* __restrict__ prev_dst,
                                                    const int* __restrict__ tf_dst,
                                                    const float* __restrict__ Wep, const float* __restrict__ bep,
                                                    const float* __restrict__ Wes, const float* __restrict__ bes,
                                                    const float* __restrict__ Wef, const float* __restrict__ bef,
                                                    float* aggEp, float* aggEs, float* aggEf) {
    int i = blockIdx.x * blockDim.x + threadIdx.x;
    if (i < NE) {
        float x[8];
#pragma unroll
        for (int k = 0; k < 8; k++) x[k] = xe[(size_t)i * 8 + k];
        int dP = prev_dst[i], dS = prev_src[i];
#pragma unroll
        for (int j = 0; j < 8; j++) {
            float ap = bep[j], as = bes[j];
#pragma unroll
            for (int k = 0; k < 8; k++) { ap += x[k] * Wep[k * 8 + j]; as += x[k] * Wes[k * 8 + j]; }
            ap = elu1(ap); as = elu1(as);
            atomicAdd(&aggEp[(size_t)dP * 8 + j], ap);
            atomicAdd(&aggEs[(size_t)dS * 8 + j], as);
        }
    }
    if (i < NEF) {
        float x[8];
#pragma unroll
        for (int k = 0; k < 8; k++) x[k] = xef[(size_t)i * 8 + k];
        int d = tf_dst[i];
#pragma unroll
        for (int j = 0; j < 8; j++) {
            float a = bef[j];
#pragma unroll
            for (int k = 0; k < 8; k++) a += x[k] * Wef[k * 8 + j];
            a = elu1(a);
            atomicAdd(&aggEf[(size_t)d * 8 + j], a);
        }
    }
}

// ---------------- node embedding (wave per node, lane = output feature) ----------------
__global__ __launch_bounds__(256) void k_node_embed(const float* __restrict__ xi,
                                                    const float* __restrict__ xf,
                                                    const float* __restrict__ Wit, const float* __restrict__ bit,
                                                    const float* __restrict__ Wft, const float* __restrict__ bft,
                                                    float* __restrict__ inst, float* __restrict__ fin) {
    const int NPW = 16;
    int lane = threadIdx.x & 63;
    int wave = (blockIdx.x * blockDim.x + threadIdx.x) >> 6;
    int base = wave * NPW;
    float wi[DN], wf[DN];
#pragma unroll
    for (int k = 0; k < DN; k++) { wi[k] = Wit[k * 64 + lane]; wf[k] = Wft[k * 64 + lane]; }
    float bi = bit[lane], bf = bft[lane];
    for (int n = 0; n < NPW; n++) {
        int i = base + n;
        if (i < NI) {
            const float* x = xi + (size_t)i * DN;
            float acc = bi;
#pragma unroll
            for (int k = 0; k < DN; k++) acc += x[k] * wi[k];
            inst[(size_t)i * 64 + lane] = elu1(acc);
        } else if (i < NI + NF) {
            int f = i - NI;
            const float* x = xf + (size_t)f * DN;
            float acc = bf;
#pragma unroll
            for (int k = 0; k < DN; k++) acc += x[k] * wf[k];
            fin[(size_t)f * 64 + lane] = elu1(acc);
        }
    }
}

// ---------------- SpMM (gather-mean), wave per dst node, lane = feature ----------------
__global__ __launch_bounds__(256) void k_spmm(const float* __restrict__ inst,
                                              const int* __restrict__ rpP, const int* __restrict__ colP, float* __restrict__ aggHp,
                                              const int* __restrict__ rpS, const int* __restrict__ colS, float* __restrict__ aggHs,
                                              const int* __restrict__ rpF, const int* __restrict__ colF, float* __restrict__ aggHf) {
    int lane = threadIdx.x & 63;
    int w = (blockIdx.x * blockDim.x + threadIdx.x) >> 6;
    const int* rp; const int* col; float* out; int i;
    if (w < NI)            { i = w;          rp = rpP; col = colP; out = aggHp; }
    else if (w < 2 * NI)   { i = w - NI;     rp = rpS; col = colS; out = aggHs; }
    else if (w < 2 * NI + NF) { i = w - 2 * NI; rp = rpF; col = colF; out = aggHf; }
    else return;

    int s = rp[i], e1 = rp[i + 1];
    float acc = 0.f;
    for (int cs = s; cs < e1; cs += 64) {
        int nch = min(64, e1 - cs);
        int cv = (cs + lane < e1) ? col[cs + lane] : 0;
        int t = 0;
        for (; t + 8 <= nch; t += 8) {
#pragma unroll
            for (int u = 0; u < 8; u++) {
                int c = __shfl(cv, t + u, 64);
                acc += inst[(size_t)c * 64 + lane];
            }
        }
        for (; t < nch; t++) {
            int c = __shfl(cv, t, 64);
            acc += inst[(size_t)c * 64 + lane];
        }
    }
    int cnt = e1 - s;
    out[(size_t)i * 64 + lane] = acc * (cnt > 0 ? 1.f / (float)cnt : 0.f);
}

// ---------------- dense layer update for instruction nodes ----------------
// lane = node (64 nodes/block), h staged in LDS with stride-65 padding,
// W read with wave-uniform indices (-> s_load, SGPR-operand v_fmac).
__global__ __launch_bounds__(64, 1) void k_dense_inst(
    float* __restrict__ inst,
    const float* __restrict__ aggHp, const float* __restrict__ aggHs,
    const float* __restrict__ aggEp, const float* __restrict__ aggEs,
    const int* __restrict__ rpP, const int* __restrict__ rpS,
    const float* __restrict__ Wp, const float* __restrict__ bp,
    const float* __restrict__ Ws, const float* __restrict__ bs) {
    __shared__ float hL[64 * 65];
    const int lane = threadIdx.x;
    const int base = blockIdx.x * 64;
    const int i = base + lane;
    const bool valid = i < NI;
    const int ii = valid ? i : (NI - 1);

    int cP = rpP[ii + 1] - rpP[ii];
    int cS = rpS[ii + 1] - rpS[ii];
    float mP = (valid && cP > 0) ? 0.5f : 0.f;   // fold the 0.5 and the zero-degree mask
    float mS = (valid && cS > 0) ? 0.5f : 0.f;
    float invP = 1.f / (float)max(cP, 1);
    float invS = 1.f / (float)max(cS, 1);
    float meP[8], meS[8];
#pragma unroll
    for (int k = 0; k < 8; k++) {
        meP[k] = aggEp[(size_t)ii * 8 + k] * invP;
        meS[k] = aggEs[(size_t)ii * 8 + k] * invS;
    }

    float accP[64], accS[64];
#pragma unroll
    for (int j = 0; j < 64; j++) { accP[j] = bp[j]; accS[j] = bs[j]; }

    // ---- pass P: stage aggHp tile, accumulate
    for (int idx = lane; idx < 1024; idx += 64) {
        int n = idx >> 4, k4 = idx & 15;
        float4 v = ((const float4*)aggHp)[(size_t)min(base + n, NI - 1) * 16 + k4];
        float* d = &hL[n * 65 + k4 * 4];
        d[0] = v.x; d[1] = v.y; d[2] = v.z; d[3] = v.w;
    }
    __syncthreads();
#pragma unroll 4
    for (int k = 0; k < 64; k++) {
        float h = hL[lane * 65 + k];
#pragma unroll
        for (int j = 0; j < 64; j++) accP[j] += h * Wp[k * 64 + j];
    }
#pragma unroll
    for (int k = 0; k < 8; k++) {
#pragma unroll
        for (int j = 0; j < 64; j++) accP[j] += meP[k] * Wp[(64 + k) * 64 + j];
    }
    __syncthreads();

    // ---- pass S
    for (int idx = lane; idx < 1024; idx += 64) {
        int n = idx >> 4, k4 = idx & 15;
        float4 v = ((const float4*)aggHs)[(size_t)min(base + n, NI - 1) * 16 + k4];
        float* d = &hL[n * 65 + k4 * 4];
        d[0] = v.x; d[1] = v.y; d[2] = v.z; d[3] = v.w;
    }
    __syncthreads();
#pragma unroll 4
    for (int k = 0; k < 64; k++) {
        float h = hL[lane * 65 + k];
#pragma unroll
        for (int j = 0; j < 64; j++) accS[j] += h * Ws[k * 64 + j];
    }
#pragma unroll
    for (int k = 0; k < 8; k++) {
#pragma unroll
        for (int j = 0; j < 64; j++) accS[j] += meS[k] * Ws[(64 + k) * 64 + j];
    }
    __syncthreads();

    // ---- residual + elu + coalesced write-back
    for (int idx = lane; idx < 1024; idx += 64) {
        int n = idx >> 4, k4 = idx & 15;
        float4 v = ((const float4*)inst)[(size_t)min(base + n, NI - 1) * 16 + k4];
        float* d = &hL[n * 65 + k4 * 4];
        d[0] = v.x; d[1] = v.y; d[2] = v.z; d[3] = v.w;
    }
    __syncthreads();
#pragma unroll
    for (int j = 0; j < 64; j++) {
        float x = hL[lane * 65 + j] + mP * accP[j] + mS * accS[j];
        hL[lane * 65 + j] = elu1(x);
    }
    __syncthreads();
    for (int idx = lane; idx < 1024; idx += 64) {
        int n = idx >> 4, k4 = idx & 15;
        if (base + n < NI) {
            const float* sp = &hL[n * 65 + k4 * 4];
            ((float4*)inst)[(size_t)(base + n) * 16 + k4] = make_float4(sp[0], sp[1], sp[2], sp[3]);
        }
    }
}

// ---------------- dense layer update for final nodes ----------------
__global__ __launch_bounds__(64, 1) void k_dense_fin(
    float* __restrict__ fin,
    const float* __restrict__ aggHf, const float* __restrict__ aggEf,
    const int* __restrict__ rpF,
    const float* __restrict__ Wf, const float* __restrict__ bf) {
    __shared__ float hL[64 * 65];
    const int lane = threadIdx.x;
    const int base = blockIdx.x * 64;
    const int i = base + lane;
    const bool valid = i < NF;
    const int ii = valid ? i : (NF - 1);

    int cF = rpF[ii + 1] - rpF[ii];
    float mF = (valid && cF > 0) ? 1.f : 0.f;
    float invF = 1.f / (float)max(cF, 1);
    float meF[8];
#pragma unroll
    for (int k = 0; k < 8; k++) meF[k] = aggEf[(size_t)ii * 8 + k] * invF;

    float acc[64];
#pragma unroll
    for (int j = 0; j < 64; j++) acc[j] = bf[j];

    for (int idx = lane; idx < 1024; idx += 64) {
        int n = idx >> 4, k4 = idx & 15;
        float4 v = ((const float4*)aggHf)[(size_t)min(base + n, NF - 1) * 16 + k4];
        float* d = &hL[n * 65 + k4 * 4];
        d[0] = v.x; d[1] = v.y; d[2] = v.z; d[3] = v.w;
    }
    __syncthreads();
#pragma unroll 4
    for (int k = 0; k < 64; k++) {
        float h = hL[lane * 65 + k];
#pragma unroll
        for (int j = 0; j < 64; j++) acc[j] += h * Wf[k * 64 + j];
    }
#pragma unroll
    for (int k = 0; k < 8; k++) {
#pragma unroll
        for (int j = 0; j < 64; j++) acc[j] += meF[k] * Wf[(64 + k) * 64 + j];
    }
    __syncthreads();

    for (int idx = lane; idx < 1024; idx += 64) {
        int n = idx >> 4, k4 = idx & 15;
        float4 v = ((const float4*)fin)[(size_t)min(base + n, NF - 1) * 16 + k4];
        float* d = &hL[n * 65 + k4 * 4];
        d[0] = v.x; d[1] = v.y; d[2] = v.z; d[3] = v.w;
    }
    __syncthreads();
#pragma unroll
    for (int j = 0; j < 64; j++) {
        float x = hL[lane * 65 + j] + mF * acc[j];
        hL[lane * 65 + j] = elu1(x);
    }
    __syncthreads();
    for (int idx = lane; idx < 1024; idx += 64) {
        int n = idx >> 4, k4 = idx & 15;
        if (base + n < NF) {
            const float* sp = &hL[n * 65 + k4 * 4];
            ((float4*)fin)[(size_t)(base + n) * 16 + k4] = make_float4(sp[0], sp[1], sp[2], sp[3]);
        }
    }
}

// ---------------- readout head: elu(fin@Wr1+b) -> elu(@Wr2+b) -> @Wr3+b ----------------
__global__ __launch_bounds__(64, 1) void k_head(
    const float* __restrict__ fin,
    const float* __restrict__ Wr1, const float* __restrict__ br1,
    const float* __restrict__ Wr2, const float* __restrict__ br2,
    const float* __restrict__ Wr3, const float* __restrict__ br3,
    float* __restrict__ out) {
    __shared__ float hL[64 * 65];
    const int lane = threadIdx.x;
    const int base = blockIdx.x * 64;

    for (int idx = lane; idx < 1024; idx += 64) {
        int n = idx >> 4, k4 = idx & 15;
        float4 v = ((const float4*)fin)[(size_t)min(base + n, NF - 1) * 16 + k4];
        float* d = &hL[n * 65 + k4 * 4];
        d[0] = v.x; d[1] = v.y; d[2] = v.z; d[3] = v.w;
    }
    __syncthreads();

    float acc[64];
#pragma unroll
    for (int j = 0; j < 64; j++) acc[j] = br1[j];
#pragma unroll 4
    for (int k = 0; k < 64; k++) {
        float h = hL[lane * 65 + k];
#pragma unroll
        for (int j = 0; j < 64; j++) acc[j] += h * Wr1[k * 64 + j];
    }
    // store elu(layer1) to own LDS row (lane-exclusive, no cross-lane use)
#pragma unroll
    for (int j = 0; j < 64; j++) hL[lane * 65 + j] = elu1(acc[j]);

#pragma unroll
    for (int j = 0; j < 64; j++) acc[j] = br2[j];
#pragma unroll 4
    for (int k = 0; k < 64; k++) {
        float h = hL[lane * 65 + k];
#pragma unroll
        for (int j = 0; j < 64; j++) acc[j] += h * Wr2[k * 64 + j];
    }
    float r = br3[0];
#pragma unroll
    for (int j = 0; j < 64; j++) r += elu1(acc[j]) * Wr3[j];

    int i = base + lane;
    if (i < NF) out[i] = r;
}

extern "C" void kernel_launch(void* const* d_in, const int* in_sizes, int n_in,
                              void* d_out, int out_size, void* d_ws, size_t ws_size,
                              hipStream_t stream) {
    const float* xi  = (const float*)d_in[0];
    const float* xf  = (const float*)d_in[1];
    const float* xe  = (const float*)d_in[2];
    const float* xef = (const float*)d_in[3];
    const int* prev_src = (const int*)d_in[4];
    const int* prev_dst = (const int*)d_in[5];
    const int* tf_src = (const int*)d_in[6];
    const int* tf_dst = (const int*)d_in[7];
    const float* W_it = (const float*)d_in[8];  const float* b_it = (const float*)d_in[9];
    const float* W_ft = (const float*)d_in[10]; const float* b_ft = (const float*)d_in[11];
    const float* W_ep = (const float*)d_in[12]; const float* b_ep = (const float*)d_in[13];
    const float* W_es = (const float*)d_in[14]; const float* b_es = (const float*)d_in[15];
    const float* W_ef = (const float*)d_in[16]; const float* b_ef = (const float*)d_in[17];
    const float* Wg_prev = (const float*)d_in[18]; const float* bg_prev = (const float*)d_in[19];
    const float* Wg_succ = (const float*)d_in[20]; const float* bg_succ = (const float*)d_in[21];
    const float* Wg_tf   = (const float*)d_in[22]; const float* bg_tf   = (const float*)d_in[23];
    const float* Wr1 = (const float*)d_in[24]; const float* br1 = (const float*)d_in[25];
    const float* Wr2 = (const float*)d_in[26]; const float* br2 = (const float*)d_in[27];
    const float* Wr3 = (const float*)d_in[28]; const float* br3 = (const float*)d_in[29];

    char* ws = (char*)d_ws;
    size_t off = 0;
    auto alloc = [&](size_t bytes) -> char* {
        char* p = ws + off;
        off += (bytes + 255) & ~(size_t)255;
        return p;
    };
    float* inst  = (float*)alloc((size_t)NI * 64 * 4);
    float* fin   = (float*)alloc((size_t)NF * 64 * 4);
    float* aggHp = (float*)alloc((size_t)NI * 64 * 4);
    float* aggHs = (float*)alloc((size_t)NI * 64 * 4);
    float* aggHf = (float*)alloc((size_t)NF * 64 * 4);
    char* zero_begin = ws + off;
    float* aggEp = (float*)alloc((size_t)NI * 8 * 4);
    float* aggEs = (float*)alloc((size_t)NI * 8 * 4);
    float* aggEf = (float*)alloc((size_t)NF * 8 * 4);
    int* cntP = (int*)alloc((size_t)NI * 4);
    int* cntS = (int*)alloc((size_t)NI * 4);
    int* cntF = (int*)alloc((size_t)NF * 4);
    int* fillP = (int*)alloc((size_t)NI * 4);
    int* fillS = (int*)alloc((size_t)NI * 4);
    int* fillF = (int*)alloc((size_t)NF * 4);
    char* zero_end = ws + off;
    int* rpP = (int*)alloc((size_t)(NI + 1) * 4);
    int* rpS = (int*)alloc((size_t)(NI + 1) * 4);
    int* rpF = (int*)alloc((size_t)(NF + 1) * 4);
    int* colP = (int*)alloc((size_t)NE * 4);
    int* colS = (int*)alloc((size_t)NE * 4);
    int* colF = (int*)alloc((size_t)NEF * 4);
    int* bsum = (int*)alloc(512 * 4);
    (void)ws_size; (void)in_sizes; (void)n_in; (void)out_size;

    hipMemsetAsync(zero_begin, 0, (size_t)(zero_end - zero_begin), stream);

    k_count<<<(NE + 255) / 256, 256, 0, stream>>>(prev_src, prev_dst, tf_dst, cntP, cntS, cntF);

    // CSR row pointers (3 independent two-level scans, bsum reused serially)
    k_scan1<<<(NI + 255) / 256, 256, 0, stream>>>(cntP, NI, rpP, bsum);
    k_scan2<<<1, 512, 0, stream>>>(bsum, (NI + 255) / 256);
    k_scan3<<<(NI + 255) / 256, 256, 0, stream>>>(rpP, bsum, NI);
    k_scan1<<<(NI + 255) / 256, 256, 0, stream>>>(cntS, NI, rpS, bsum);
    k_scan2<<<1, 512, 0, stream>>>(bsum, (NI + 255) / 256);
    k_scan3<<<(NI + 255) / 256, 256, 0, stream>>>(rpS, bsum, NI);
    k_scan1<<<(NF + 255) / 256, 256, 0, stream>>>(cntF, NF, rpF, bsum);
    k_scan2<<<1, 512, 0, stream>>>(bsum, (NF + 255) / 256);
    k_scan3<<<(NF + 255) / 256, 256, 0, stream>>>(rpF, bsum, NF);

    k_scatter<<<(NE + 255) / 256, 256, 0, stream>>>(prev_src, prev_dst, tf_src, tf_dst,
                                                    rpP, rpS, rpF, fillP, fillS, fillF,
                                                    colP, colS, colF);
    k_edge_embed<<<(NE + 255) / 256, 256, 0, stream>>>(xe, xef, prev_src, prev_dst, tf_dst,
                                                       W_ep, b_ep, W_es, b_es, W_ef, b_ef,
                                                       aggEp, aggEs, aggEf);

    {
        int waves = (NI + NF + 15) / 16;
        int blocks = (waves + 3) / 4;
        k_node_embed<<<blocks, 256, 0, stream>>>(xi, xf, W_it, b_it, W_ft, b_ft, inst, fin);
    }

    for (int l = 0; l < NL; l++) {
        int waves = 2 * NI + NF;
        k_spmm<<<(waves + 3) / 4, 256, 0, stream>>>(inst,
                                                    rpP, colP, aggHp,
                                                    rpS, colS, aggHs,
                                                    rpF, colF, aggHf);
        k_dense_inst<<<(NI + 63) / 64, 64, 0, stream>>>(inst, aggHp, aggHs, aggEp, aggEs, rpP, rpS,
                                                        Wg_prev + (size_t)l * 72 * 64, bg_prev + (size_t)l * 64,
                                                        Wg_succ + (size_t)l * 72 * 64, bg_succ + (size_t)l * 64);
        k_dense_fin<<<(NF + 63) / 64, 64, 0, stream>>>(fin, aggHf, aggEf, rpF,
                                                       Wg_tf + (size_t)l * 72 * 64, bg_tf + (size_t)l * 64);
    }

    k_head<<<(NF + 63) / 64, 64, 0, stream>>>(fin, Wr1, br1, Wr2, br2, Wr3, br3, (float*)d_out);
}

// Round 2
// 3652.890 us; speedup vs baseline: 1.1375x; 1.1375x over previous
//
#include <hip/hip_runtime.h>
#include <math.h>

#define NI 100000
#define NF 2000
#define NE 800000
#define NEF 200000
#define DN 16
#define NL 11

__device__ __forceinline__ float elu1(float x) { return x > 0.f ? x : expm1f(x); }

// ---------------- CSR build ----------------
__global__ __launch_bounds__(256) void k_count(const int* __restrict__ prev_src,
                                               const int* __restrict__ prev_dst,
                                               const int* __restrict__ tf_dst,
                                               int* cntP, int* cntS, int* cntF) {
    int i = blockIdx.x * blockDim.x + threadIdx.x;
    if (i < NE) {
        atomicAdd(&cntP[prev_dst[i]], 1);
        atomicAdd(&cntS[prev_src[i]], 1);
    }
    if (i < NEF) atomicAdd(&cntF[tf_dst[i]], 1);
}

__global__ __launch_bounds__(256) void k_scan1(const int* __restrict__ cnt, int n,
                                               int* __restrict__ rp, int* __restrict__ bsum) {
    __shared__ int s[256];
    int t = threadIdx.x, b = blockIdx.x, i = b * 256 + t;
    int v = (i < n) ? cnt[i] : 0;
    s[t] = v; __syncthreads();
    for (int o = 1; o < 256; o <<= 1) {
        int x = (t >= o) ? s[t - o] : 0;
        __syncthreads();
        s[t] += x;
        __syncthreads();
    }
    if (i < n) rp[i + 1] = s[t];
    if (t == 255) bsum[b] = s[255];
}

__global__ __launch_bounds__(512) void k_scan2(int* __restrict__ bsum, int nb) {
    __shared__ int s[512];
    int t = threadIdx.x;
    int v = (t < nb) ? bsum[t] : 0;
    s[t] = v; __syncthreads();
    for (int o = 1; o < 512; o <<= 1) {
        int x = (t >= o) ? s[t - o] : 0;
        __syncthreads();
        s[t] += x;
        __syncthreads();
    }
    if (t < nb) bsum[t] = s[t] - v;   // exclusive block offsets
}

__global__ __launch_bounds__(256) void k_scan3(int* __restrict__ rp, const int* __restrict__ bsum, int n) {
    int i = blockIdx.x * blockDim.x + threadIdx.x;
    if (i < n) rp[i + 1] += bsum[i >> 8];
    if (i == 0) rp[0] = 0;
}

__global__ __launch_bounds__(256) void k_scatter(const int* __restrict__ prev_src,
                                                 const int* __restrict__ prev_dst,
                                                 const int* __restrict__ tf_src,
                                                 const int* __restrict__ tf_dst,
                                                 const int* __restrict__ rpP,
                                                 const int* __restrict__ rpS,
                                                 const int* __restrict__ rpF,
                                                 int* fillP, int* fillS, int* fillF,
                                                 int* colP, int* colS, int* colF,
                                                 int* eidP, int* eidS, int* eidF) {
    int i = blockIdx.x * blockDim.x + threadIdx.x;
    if (i < NE) {
        int s = prev_src[i], d = prev_dst[i];
        int tP = rpP[d] + atomicAdd(&fillP[d], 1);
        colP[tP] = s; eidP[tP] = i;
        int tS = rpS[s] + atomicAdd(&fillS[s], 1);
        colS[tS] = d; eidS[tS] = i;
    }
    if (i < NEF) {
        int s = tf_src[i], d = tf_dst[i];
        int t = rpF[d] + atomicAdd(&fillF[d], 1);
        colF[t] = s; eidF[t] = i;
    }
}

// ---------------- per-dst edge-embed aggregation (atomic-free, layer-invariant) ----------------
// thread per destination node; gathers raw edge feats by edge id, computes the
// 8x8 embed + elu inline (W/b wave-uniform -> scalar loads), accumulates SUM.
__global__ __launch_bounds__(256) void k_eagg(const float* __restrict__ xe,
                                              const float* __restrict__ xef,
                                              const int* __restrict__ rpP, const int* __restrict__ eidP,
                                              const int* __restrict__ rpS, const int* __restrict__ eidS,
                                              const int* __restrict__ rpF, const int* __restrict__ eidF,
                                              const float* __restrict__ Wep, const float* __restrict__ bep,
                                              const float* __restrict__ Wes, const float* __restrict__ bes,
                                              const float* __restrict__ Wef, const float* __restrict__ bef,
                                              float* __restrict__ aggEp,
                                              float* __restrict__ aggEs,
                                              float* __restrict__ aggEf) {
    int i = blockIdx.x * blockDim.x + threadIdx.x;
    if (i < NI) {
        float aP[8], aS[8];
#pragma unroll
        for (int j = 0; j < 8; j++) { aP[j] = 0.f; aS[j] = 0.f; }
        for (int t = rpP[i]; t < rpP[i + 1]; ++t) {
            int e = eidP[t];
            float4 x0 = ((const float4*)xe)[(size_t)e * 2];
            float4 x1 = ((const float4*)xe)[(size_t)e * 2 + 1];
            float x[8] = {x0.x, x0.y, x0.z, x0.w, x1.x, x1.y, x1.z, x1.w};
#pragma unroll
            for (int j = 0; j < 8; j++) {
                float v = bep[j];
#pragma unroll
                for (int k = 0; k < 8; k++) v += x[k] * Wep[k * 8 + j];
                aP[j] += elu1(v);
            }
        }
        for (int t = rpS[i]; t < rpS[i + 1]; ++t) {
            int e = eidS[t];
            float4 x0 = ((const float4*)xe)[(size_t)e * 2];
            float4 x1 = ((const float4*)xe)[(size_t)e * 2 + 1];
            float x[8] = {x0.x, x0.y, x0.z, x0.w, x1.x, x1.y, x1.z, x1.w};
#pragma unroll
            for (int j = 0; j < 8; j++) {
                float v = bes[j];
#pragma unroll
                for (int k = 0; k < 8; k++) v += x[k] * Wes[k * 8 + j];
                aS[j] += elu1(v);
            }
        }
        ((float4*)aggEp)[(size_t)i * 2]     = make_float4(aP[0], aP[1], aP[2], aP[3]);
        ((float4*)aggEp)[(size_t)i * 2 + 1] = make_float4(aP[4], aP[5], aP[6], aP[7]);
        ((float4*)aggEs)[(size_t)i * 2]     = make_float4(aS[0], aS[1], aS[2], aS[3]);
        ((float4*)aggEs)[(size_t)i * 2 + 1] = make_float4(aS[4], aS[5], aS[6], aS[7]);
    } else if (i < NI + NF) {
        int f = i - NI;
        float aF[8];
#pragma unroll
        for (int j = 0; j < 8; j++) aF[j] = 0.f;
        for (int t = rpF[f]; t < rpF[f + 1]; ++t) {
            int e = eidF[t];
            float4 x0 = ((const float4*)xef)[(size_t)e * 2];
            float4 x1 = ((const float4*)xef)[(size_t)e * 2 + 1];
            float x[8] = {x0.x, x0.y, x0.z, x0.w, x1.x, x1.y, x1.z, x1.w};
#pragma unroll
            for (int j = 0; j < 8; j++) {
                float v = bef[j];
#pragma unroll
                for (int k = 0; k < 8; k++) v += x[k] * Wef[k * 8 + j];
                aF[j] += elu1(v);
            }
        }
        ((float4*)aggEf)[(size_t)f * 2]     = make_float4(aF[0], aF[1], aF[2], aF[3]);
        ((float4*)aggEf)[(size_t)f * 2 + 1] = make_float4(aF[4], aF[5], aF[6], aF[7]);
    }
}

// ---------------- node embedding (wave per node, lane = output feature) ----------------
__global__ __launch_bounds__(256) void k_node_embed(const float* __restrict__ xi,
                                                    const float* __restrict__ xf,
                                                    const float* __restrict__ Wit, const float* __restrict__ bit,
                                                    const float* __restrict__ Wft, const float* __restrict__ bft,
                                                    float* __restrict__ inst, float* __restrict__ fin) {
    const int NPW = 16;
    int lane = threadIdx.x & 63;
    int wave = (blockIdx.x * blockDim.x + threadIdx.x) >> 6;
    int base = wave * NPW;
    float wi[DN], wf[DN];
#pragma unroll
    for (int k = 0; k < DN; k++) { wi[k] = Wit[k * 64 + lane]; wf[k] = Wft[k * 64 + lane]; }
    float bi = bit[lane], bf = bft[lane];
    for (int n = 0; n < NPW; n++) {
        int i = base + n;
        if (i < NI) {
            const float* x = xi + (size_t)i * DN;
            float acc = bi;
#pragma unroll
            for (int k = 0; k < DN; k++) acc += x[k] * wi[k];
            inst[(size_t)i * 64 + lane] = elu1(acc);
        } else if (i < NI + NF) {
            int f = i - NI;
            const float* x = xf + (size_t)f * DN;
            float acc = bf;
#pragma unroll
            for (int k = 0; k < DN; k++) acc += x[k] * wf[k];
            fin[(size_t)f * 64 + lane] = elu1(acc);
        }
    }
}

// ---------------- SpMM (gather-mean), wave per dst node, lane = feature ----------------
__global__ __launch_bounds__(256) void k_spmm(const float* __restrict__ inst,
                                              const int* __restrict__ rpP, const int* __restrict__ colP, float* __restrict__ aggHp,
                                              const int* __restrict__ rpS, const int* __restrict__ colS, float* __restrict__ aggHs,
                                              const int* __restrict__ rpF, const int* __restrict__ colF, float* __restrict__ aggHf) {
    int lane = threadIdx.x & 63;
    int w = (blockIdx.x * blockDim.x + threadIdx.x) >> 6;
    const int* rp; const int* col; float* out; int i;
    if (w < NI)            { i = w;          rp = rpP; col = colP; out = aggHp; }
    else if (w < 2 * NI)   { i = w - NI;     rp = rpS; col = colS; out = aggHs; }
    else if (w < 2 * NI + NF) { i = w - 2 * NI; rp = rpF; col = colF; out = aggHf; }
    else return;

    int s = rp[i], e1 = rp[i + 1];
    float acc = 0.f;
    for (int cs = s; cs < e1; cs += 64) {
        int nch = min(64, e1 - cs);
        int cv = (cs + lane < e1) ? col[cs + lane] : 0;
        int t = 0;
        for (; t + 8 <= nch; t += 8) {
#pragma unroll
            for (int u = 0; u < 8; u++) {
                int c = __shfl(cv, t + u, 64);
                acc += inst[(size_t)c * 64 + lane];
            }
        }
        for (; t < nch; t++) {
            int c = __shfl(cv, t, 64);
            acc += inst[(size_t)c * 64 + lane];
        }
    }
    int cnt = e1 - s;
    out[(size_t)i * 64 + lane] = acc * (cnt > 0 ? 1.f / (float)cnt : 0.f);
}

// ---------------- dense layer update for instruction nodes ----------------
// lane = node (64 nodes/block), h staged in LDS with stride-65 padding,
// W read with wave-uniform indices (-> s_load, SGPR-operand v_fmac).
__global__ __launch_bounds__(64, 1) void k_dense_inst(
    float* __restrict__ inst,
    const float* __restrict__ aggHp, const float* __restrict__ aggHs,
    const float* __restrict__ aggEp, const float* __restrict__ aggEs,
    const int* __restrict__ rpP, const int* __restrict__ rpS,
    const float* __restrict__ Wp, const float* __restrict__ bp,
    const float* __restrict__ Ws, const float* __restrict__ bs) {
    __shared__ float hL[64 * 65];
    const int lane = threadIdx.x;
    const int base = blockIdx.x * 64;
    const int i = base + lane;
    const bool valid = i < NI;
    const int ii = valid ? i : (NI - 1);

    int cP = rpP[ii + 1] - rpP[ii];
    int cS = rpS[ii + 1] - rpS[ii];
    float mP = (valid && cP > 0) ? 0.5f : 0.f;   // fold the 0.5 and the zero-degree mask
    float mS = (valid && cS > 0) ? 0.5f : 0.f;
    float invP = 1.f / (float)max(cP, 1);
    float invS = 1.f / (float)max(cS, 1);
    float meP[8], meS[8];
#pragma unroll
    for (int k = 0; k < 8; k++) {
        meP[k] = aggEp[(size_t)ii * 8 + k] * invP;
        meS[k] = aggEs[(size_t)ii * 8 + k] * invS;
    }

    float accP[64], accS[64];
#pragma unroll
    for (int j = 0; j < 64; j++) { accP[j] = bp[j]; accS[j] = bs[j]; }

    // ---- pass P: stage aggHp tile, accumulate
    for (int idx = lane; idx < 1024; idx += 64) {
        int n = idx >> 4, k4 = idx & 15;
        float4 v = ((const float4*)aggHp)[(size_t)min(base + n, NI - 1) * 16 + k4];
        float* d = &hL[n * 65 + k4 * 4];
        d[0] = v.x; d[1] = v.y; d[2] = v.z; d[3] = v.w;
    }
    __syncthreads();
#pragma unroll 4
    for (int k = 0; k < 64; k++) {
        float h = hL[lane * 65 + k];
#pragma unroll
        for (int j = 0; j < 64; j++) accP[j] += h * Wp[k * 64 + j];
    }
#pragma unroll
    for (int k = 0; k < 8; k++) {
#pragma unroll
        for (int j = 0; j < 64; j++) accP[j] += meP[k] * Wp[(64 + k) * 64 + j];
    }
    __syncthreads();

    // ---- pass S
    for (int idx = lane; idx < 1024; idx += 64) {
        int n = idx >> 4, k4 = idx & 15;
        float4 v = ((const float4*)aggHs)[(size_t)min(base + n, NI - 1) * 16 + k4];
        float* d = &hL[n * 65 + k4 * 4];
        d[0] = v.x; d[1] = v.y; d[2] = v.z; d[3] = v.w;
    }
    __syncthreads();
#pragma unroll 4
    for (int k = 0; k < 64; k++) {
        float h = hL[lane * 65 + k];
#pragma unroll
        for (int j = 0; j < 64; j++) accS[j] += h * Ws[k * 64 + j];
    }
#pragma unroll
    for (int k = 0; k < 8; k++) {
#pragma unroll
        for (int j = 0; j < 64; j++) accS[j] += meS[k] * Ws[(64 + k) * 64 + j];
    }
    __syncthreads();

    // ---- residual + elu + coalesced write-back
    for (int idx = lane; idx < 1024; idx += 64) {
        int n = idx >> 4, k4 = idx & 15;
        float4 v = ((const float4*)inst)[(size_t)min(base + n, NI - 1) * 16 + k4];
        float* d = &hL[n * 65 + k4 * 4];
        d[0] = v.x; d[1] = v.y; d[2] = v.z; d[3] = v.w;
    }
    __syncthreads();
#pragma unroll
    for (int j = 0; j < 64; j++) {
        float x = hL[lane * 65 + j] + mP * accP[j] + mS * accS[j];
        hL[lane * 65 + j] = elu1(x);
    }
    __syncthreads();
    for (int idx = lane; idx < 1024; idx += 64) {
        int n = idx >> 4, k4 = idx & 15;
        if (base + n < NI) {
            const float* sp = &hL[n * 65 + k4 * 4];
            ((float4*)inst)[(size_t)(base + n) * 16 + k4] = make_float4(sp[0], sp[1], sp[2], sp[3]);
        }
    }
}

// ---------------- dense layer update for final nodes ----------------
__global__ __launch_bounds__(64, 1) void k_dense_fin(
    float* __restrict__ fin,
    const float* __restrict__ aggHf, const float* __restrict__ aggEf,
    const int* __restrict__ rpF,
    const float* __restrict__ Wf, const float* __restrict__ bf) {
    __shared__ float hL[64 * 65];
    const int lane = threadIdx.x;
    const int base = blockIdx.x * 64;
    const int i = base + lane;
    const bool valid = i < NF;
    const int ii = valid ? i : (NF - 1);

    int cF = rpF[ii + 1] - rpF[ii];
    float mF = (valid && cF > 0) ? 1.f : 0.f;
    float invF = 1.f / (float)max(cF, 1);
    float meF[8];
#pragma unroll
    for (int k = 0; k < 8; k++) meF[k] = aggEf[(size_t)ii * 8 + k] * invF;

    float acc[64];
#pragma unroll
    for (int j = 0; j < 64; j++) acc[j] = bf[j];

    for (int idx = lane; idx < 1024; idx += 64) {
        int n = idx >> 4, k4 = idx & 15;
        float4 v = ((const float4*)aggHf)[(size_t)min(base + n, NF - 1) * 16 + k4];
        float* d = &hL[n * 65 + k4 * 4];
        d[0] = v.x; d[1] = v.y; d[2] = v.z; d[3] = v.w;
    }
    __syncthreads();
#pragma unroll 4
    for (int k = 0; k < 64; k++) {
        float h = hL[lane * 65 + k];
#pragma unroll
        for (int j = 0; j < 64; j++) acc[j] += h * Wf[k * 64 + j];
    }
#pragma unroll
    for (int k = 0; k < 8; k++) {
#pragma unroll
        for (int j = 0; j < 64; j++) acc[j] += meF[k] * Wf[(64 + k) * 64 + j];
    }
    __syncthreads();

    for (int idx = lane; idx < 1024; idx += 64) {
        int n = idx >> 4, k4 = idx & 15;
        float4 v = ((const float4*)fin)[(size_t)min(base + n, NF - 1) * 16 + k4];
        float* d = &hL[n * 65 + k4 * 4];
        d[0] = v.x; d[1] = v.y; d[2] = v.z; d[3] = v.w;
    }
    __syncthreads();
#pragma unroll
    for (int j = 0; j < 64; j++) {
        float x = hL[lane * 65 + j] + mF * acc[j];
        hL[lane * 65 + j] = elu1(x);
    }
    __syncthreads();
    for (int idx = lane; idx < 1024; idx += 64) {
        int n = idx >> 4, k4 = idx & 15;
        if (base + n < NF) {
            const float* sp = &hL[n * 65 + k4 * 4];
            ((float4*)fin)[(size_t)(base + n) * 16 + k4] = make_float4(sp[0], sp[1], sp[2], sp[3]);
        }
    }
}

// ---------------- readout head: elu(fin@Wr1+b) -> elu(@Wr2+b) -> @Wr3+b ----------------
__global__ __launch_bounds__(64, 1) void k_head(
    const float* __restrict__ fin,
    const float* __restrict__ Wr1, const float* __restrict__ br1,
    const float* __restrict__ Wr2, const float* __restrict__ br2,
    const float* __restrict__ Wr3, const float* __restrict__ br3,
    float* __restrict__ out) {
    __shared__ float hL[64 * 65];
    const int lane = threadIdx.x;
    const int base = blockIdx.x * 64;

    for (int idx = lane; idx < 1024; idx += 64) {
        int n = idx >> 4, k4 = idx & 15;
        float4 v = ((const float4*)fin)[(size_t)min(base + n, NF - 1) * 16 + k4];
        float* d = &hL[n * 65 + k4 * 4];
        d[0] = v.x; d[1] = v.y; d[2] = v.z; d[3] = v.w;
    }
    __syncthreads();

    float acc[64];
#pragma unroll
    for (int j = 0; j < 64; j++) acc[j] = br1[j];
#pragma unroll 4
    for (int k = 0; k < 64; k++) {
        float h = hL[lane * 65 + k];
#pragma unroll
        for (int j = 0; j < 64; j++) acc[j] += h * Wr1[k * 64 + j];
    }
    // store elu(layer1) to own LDS row (lane-exclusive, no cross-lane use)
#pragma unroll
    for (int j = 0; j < 64; j++) hL[lane * 65 + j] = elu1(acc[j]);

#pragma unroll
    for (int j = 0; j < 64; j++) acc[j] = br2[j];
#pragma unroll 4
    for (int k = 0; k < 64; k++) {
        float h = hL[lane * 65 + k];
#pragma unroll
        for (int j = 0; j < 64; j++) acc[j] += h * Wr2[k * 64 + j];
    }
    float r = br3[0];
#pragma unroll
    for (int j = 0; j < 64; j++) r += elu1(acc[j]) * Wr3[j];

    int i = base + lane;
    if (i < NF) out[i] = r;
}

extern "C" void kernel_launch(void* const* d_in, const int* in_sizes, int n_in,
                              void* d_out, int out_size, void* d_ws, size_t ws_size,
                              hipStream_t stream) {
    const float* xi  = (const float*)d_in[0];
    const float* xf  = (const float*)d_in[1];
    const float* xe  = (const float*)d_in[2];
    const float* xef = (const float*)d_in[3];
    const int* prev_src = (const int*)d_in[4];
    const int* prev_dst = (const int*)d_in[5];
    const int* tf_src = (const int*)d_in[6];
    const int* tf_dst = (const int*)d_in[7];
    const float* W_it = (const float*)d_in[8];  const float* b_it = (const float*)d_in[9];
    const float* W_ft = (const float*)d_in[10]; const float* b_ft = (const float*)d_in[11];
    const float* W_ep = (const float*)d_in[12]; const float* b_ep = (const float*)d_in[13];
    const float* W_es = (const float*)d_in[14]; const float* b_es = (const float*)d_in[15];
    const float* W_ef = (const float*)d_in[16]; const float* b_ef = (const float*)d_in[17];
    const float* Wg_prev = (const float*)d_in[18]; const float* bg_prev = (const float*)d_in[19];
    const float* Wg_succ = (const float*)d_in[20]; const float* bg_succ = (const float*)d_in[21];
    const float* Wg_tf   = (const float*)d_in[22]; const float* bg_tf   = (const float*)d_in[23];
    const float* Wr1 = (const float*)d_in[24]; const float* br1 = (const float*)d_in[25];
    const float* Wr2 = (const float*)d_in[26]; const float* br2 = (const float*)d_in[27];
    const float* Wr3 = (const float*)d_in[28]; const float* br3 = (const float*)d_in[29];

    char* ws = (char*)d_ws;
    size_t off = 0;
    auto alloc = [&](size_t bytes) -> char* {
        char* p = ws + off;
        off += (bytes + 255) & ~(size_t)255;
        return p;
    };
    float* inst  = (float*)alloc((size_t)NI * 64 * 4);
    float* fin   = (float*)alloc((size_t)NF * 64 * 4);
    float* aggHp = (float*)alloc((size_t)NI * 64 * 4);
    float* aggHs = (float*)alloc((size_t)NI * 64 * 4);
    float* aggHf = (float*)alloc((size_t)NF * 64 * 4);
    float* aggEp = (float*)alloc((size_t)NI * 8 * 4);
    float* aggEs = (float*)alloc((size_t)NI * 8 * 4);
    float* aggEf = (float*)alloc((size_t)NF * 8 * 4);
    char* zero_begin = ws + off;
    int* cntP = (int*)alloc((size_t)NI * 4);
    int* cntS = (int*)alloc((size_t)NI * 4);
    int* cntF = (int*)alloc((size_t)NF * 4);
    int* fillP = (int*)alloc((size_t)NI * 4);
    int* fillS = (int*)alloc((size_t)NI * 4);
    int* fillF = (int*)alloc((size_t)NF * 4);
    char* zero_end = ws + off;
    int* rpP = (int*)alloc((size_t)(NI + 1) * 4);
    int* rpS = (int*)alloc((size_t)(NI + 1) * 4);
    int* rpF = (int*)alloc((size_t)(NF + 1) * 4);
    int* colP = (int*)alloc((size_t)NE * 4);
    int* colS = (int*)alloc((size_t)NE * 4);
    int* colF = (int*)alloc((size_t)NEF * 4);
    int* eidP = (int*)alloc((size_t)NE * 4);
    int* eidS = (int*)alloc((size_t)NE * 4);
    int* eidF = (int*)alloc((size_t)NEF * 4);
    int* bsum = (int*)alloc(512 * 4);
    (void)ws_size; (void)in_sizes; (void)n_in; (void)out_size;

    hipMemsetAsync(zero_begin, 0, (size_t)(zero_end - zero_begin), stream);

    k_count<<<(NE + 255) / 256, 256, 0, stream>>>(prev_src, prev_dst, tf_dst, cntP, cntS, cntF);

    // CSR row pointers (3 independent two-level scans, bsum reused serially)
    k_scan1<<<(NI + 255) / 256, 256, 0, stream>>>(cntP, NI, rpP, bsum);
    k_scan2<<<1, 512, 0, stream>>>(bsum, (NI + 255) / 256);
    k_scan3<<<(NI + 255) / 256, 256, 0, stream>>>(rpP, bsum, NI);
    k_scan1<<<(NI + 255) / 256, 256, 0, stream>>>(cntS, NI, rpS, bsum);
    k_scan2<<<1, 512, 0, stream>>>(bsum, (NI + 255) / 256);
    k_scan3<<<(NI + 255) / 256, 256, 0, stream>>>(rpS, bsum, NI);
    k_scan1<<<(NF + 255) / 256, 256, 0, stream>>>(cntF, NF, rpF, bsum);
    k_scan2<<<1, 512, 0, stream>>>(bsum, (NF + 255) / 256);
    k_scan3<<<(NF + 255) / 256, 256, 0, stream>>>(rpF, bsum, NF);

    k_scatter<<<(NE + 255) / 256, 256, 0, stream>>>(prev_src, prev_dst, tf_src, tf_dst,
                                                    rpP, rpS, rpF, fillP, fillS, fillF,
                                                    colP, colS, colF, eidP, eidS, eidF);

    // layer-invariant edge-embed sums, atomic-free via CSR gather
    k_eagg<<<(NI + NF + 255) / 256, 256, 0, stream>>>(xe, xef,
                                                      rpP, eidP, rpS, eidS, rpF, eidF,
                                                      W_ep, b_ep, W_es, b_es, W_ef, b_ef,
                                                      aggEp, aggEs, aggEf);

    {
        int waves = (NI + NF + 15) / 16;
        int blocks = (waves + 3) / 4;
        k_node_embed<<<blocks, 256, 0, stream>>>(xi, xf, W_it, b_it, W_ft, b_ft, inst, fin);
    }

    for (int l = 0; l < NL; l++) {
        int waves = 2 * NI + NF;
        k_spmm<<<(waves + 3) / 4, 256, 0, stream>>>(inst,
                                                    rpP, colP, aggHp,
                                                    rpS, colS, aggHs,
                                                    rpF, colF, aggHf);
        k_dense_inst<<<(NI + 63) / 64, 64, 0, stream>>>(inst, aggHp, aggHs, aggEp, aggEs, rpP, rpS,
                                                        Wg_prev + (size_t)l * 72 * 64, bg_prev + (size_t)l * 64,
                                                        Wg_succ + (size_t)l * 72 * 64, bg_succ + (size_t)l * 64);
        k_dense_fin<<<(NF + 63) / 64, 64, 0, stream>>>(fin, aggHf, aggEf, rpF,
                                                       Wg_tf + (size_t)l * 72 * 64, bg_tf + (size_t)l * 64);
    }

    k_head<<<(NF + 63) / 64, 64, 0, stream>>>(fin, Wr1, br1, Wr2, br2, Wr3, br3, (float*)d_out);
}

// Round 3
// 3446.524 us; speedup vs baseline: 1.2057x; 1.0599x over previous
//
#include <hip/hip_runtime.h>
#include <math.h>

#define NI 100000
#define NF 2000
#define NE 800000
#define NEF 200000
#define DN 16
#define NL 11
#define NT (2 * NI + NF)   // concatenated node-direction count: P | S | F

__device__ __forceinline__ float elu1(float x) { return x > 0.f ? x : expm1f(x); }

__device__ __forceinline__ unsigned short f2bf(float f) {
    unsigned x = __float_as_uint(f);
    return (unsigned short)((x + 0x7fffu + ((x >> 16) & 1u)) >> 16);
}
__device__ __forceinline__ float bf2f(unsigned short u) {
    return __uint_as_float(((unsigned)u) << 16);
}

// ---------------- CSR build (concatenated P|S|F degree array) ----------------
__global__ __launch_bounds__(256) void k_count(const int* __restrict__ prev_src,
                                               const int* __restrict__ prev_dst,
                                               const int* __restrict__ tf_dst,
                                               int* cnt) {
    int i = blockIdx.x * blockDim.x + threadIdx.x;
    if (i < NE) {
        atomicAdd(&cnt[prev_dst[i]], 1);
        atomicAdd(&cnt[NI + prev_src[i]], 1);
    }
    if (i < NEF) atomicAdd(&cnt[2 * NI + tf_dst[i]], 1);
}

__global__ __launch_bounds__(256) void k_scan1(const int* __restrict__ cnt, int n,
                                               int* __restrict__ rp, int* __restrict__ bsum) {
    __shared__ int s[256];
    int t = threadIdx.x, b = blockIdx.x, i = b * 256 + t;
    int v = (i < n) ? cnt[i] : 0;
    s[t] = v; __syncthreads();
    for (int o = 1; o < 256; o <<= 1) {
        int x = (t >= o) ? s[t - o] : 0;
        __syncthreads();
        s[t] += x;
        __syncthreads();
    }
    if (i < n) rp[i + 1] = s[t];
    if (t == 255) bsum[b] = s[255];
}

__global__ __launch_bounds__(1024) void k_scan2(int* __restrict__ bsum, int nb) {
    __shared__ int s[1024];
    int t = threadIdx.x;
    int v = (t < nb) ? bsum[t] : 0;
    s[t] = v; __syncthreads();
    for (int o = 1; o < 1024; o <<= 1) {
        int x = (t >= o) ? s[t - o] : 0;
        __syncthreads();
        s[t] += x;
        __syncthreads();
    }
    if (t < nb) bsum[t] = s[t] - v;   // exclusive block offsets
}

__global__ __launch_bounds__(256) void k_scan3(int* __restrict__ rp, const int* __restrict__ bsum, int n) {
    int i = blockIdx.x * blockDim.x + threadIdx.x;
    if (i < n) rp[i + 1] += bsum[i >> 8];
    if (i == 0) rp[0] = 0;
}

// ---------------- scatter: CSR cols + fused edge-embed written in CSR slot order ----
__global__ __launch_bounds__(256) void k_scatter(const int* __restrict__ prev_src,
                                                 const int* __restrict__ prev_dst,
                                                 const int* __restrict__ tf_src,
                                                 const int* __restrict__ tf_dst,
                                                 const float* __restrict__ xe,
                                                 const float* __restrict__ xef,
                                                 const int* __restrict__ rp,
                                                 int* fill,
                                                 int* colP, int* colS, int* colF,
                                                 float* __restrict__ ePbuf,
                                                 float* __restrict__ eSbuf,
                                                 float* __restrict__ eFbuf,
                                                 const float* __restrict__ Wep, const float* __restrict__ bep,
                                                 const float* __restrict__ Wes, const float* __restrict__ bes,
                                                 const float* __restrict__ Wef, const float* __restrict__ bef) {
    int i = blockIdx.x * blockDim.x + threadIdx.x;
    if (i < NE) {
        int s = prev_src[i], d = prev_dst[i];
        float4 x0 = ((const float4*)xe)[(size_t)i * 2];
        float4 x1 = ((const float4*)xe)[(size_t)i * 2 + 1];
        float x[8] = {x0.x, x0.y, x0.z, x0.w, x1.x, x1.y, x1.z, x1.w};
        float eP[8], eS[8];
#pragma unroll
        for (int j = 0; j < 8; j++) {
            float vp = bep[j], vs = bes[j];
#pragma unroll
            for (int k = 0; k < 8; k++) { vp += x[k] * Wep[k * 8 + j]; vs += x[k] * Wes[k * 8 + j]; }
            eP[j] = elu1(vp); eS[j] = elu1(vs);
        }
        int tP = rp[d] + atomicAdd(&fill[d], 1);
        colP[tP] = s;
        ((float4*)ePbuf)[(size_t)tP * 2]     = make_float4(eP[0], eP[1], eP[2], eP[3]);
        ((float4*)ePbuf)[(size_t)tP * 2 + 1] = make_float4(eP[4], eP[5], eP[6], eP[7]);
        int tS = rp[NI + s] - NE + atomicAdd(&fill[NI + s], 1);
        colS[tS] = d;
        ((float4*)eSbuf)[(size_t)tS * 2]     = make_float4(eS[0], eS[1], eS[2], eS[3]);
        ((float4*)eSbuf)[(size_t)tS * 2 + 1] = make_float4(eS[4], eS[5], eS[6], eS[7]);
    }
    if (i < NEF) {
        int s = tf_src[i], d = tf_dst[i];
        float4 x0 = ((const float4*)xef)[(size_t)i * 2];
        float4 x1 = ((const float4*)xef)[(size_t)i * 2 + 1];
        float x[8] = {x0.x, x0.y, x0.z, x0.w, x1.x, x1.y, x1.z, x1.w};
        float eF[8];
#pragma unroll
        for (int j = 0; j < 8; j++) {
            float v = bef[j];
#pragma unroll
            for (int k = 0; k < 8; k++) v += x[k] * Wef[k * 8 + j];
            eF[j] = elu1(v);
        }
        int tF = rp[2 * NI + d] - 2 * NE + atomicAdd(&fill[2 * NI + d], 1);
        colF[tF] = s;
        ((float4*)eFbuf)[(size_t)tF * 2]     = make_float4(eF[0], eF[1], eF[2], eF[3]);
        ((float4*)eFbuf)[(size_t)tF * 2 + 1] = make_float4(eF[4], eF[5], eF[6], eF[7]);
    }
}

// ---------------- edge-embed aggregation: sequential run-sum per node ----------------
// F nodes (deg ~100) mapped to lowest thread ids so long runs start first.
__global__ __launch_bounds__(256) void k_eagg2(const int* __restrict__ rp,
                                               const float* __restrict__ ePbuf,
                                               const float* __restrict__ eSbuf,
                                               const float* __restrict__ eFbuf,
                                               float* __restrict__ aggEp,
                                               float* __restrict__ aggEs,
                                               float* __restrict__ aggEf) {
    int idx = blockIdx.x * blockDim.x + threadIdx.x;
    if (idx >= NT) return;
    const float* buf; float* out; int s, e;
    if (idx < NF) {
        int n = idx;
        s = rp[2 * NI + n] - 2 * NE; e = rp[2 * NI + n + 1] - 2 * NE;
        buf = eFbuf; out = aggEf + (size_t)n * 8;
    } else if (idx < NF + NI) {
        int n = idx - NF;
        s = rp[n]; e = rp[n + 1];
        buf = ePbuf; out = aggEp + (size_t)n * 8;
    } else {
        int n = idx - NF - NI;
        s = rp[NI + n] - NE; e = rp[NI + n + 1] - NE;
        buf = eSbuf; out = aggEs + (size_t)n * 8;
    }
    float a0 = 0.f, a1 = 0.f, a2 = 0.f, a3 = 0.f, a4 = 0.f, a5 = 0.f, a6 = 0.f, a7 = 0.f;
    for (int t = s; t < e; ++t) {
        float4 v0 = ((const float4*)buf)[(size_t)t * 2];
        float4 v1 = ((const float4*)buf)[(size_t)t * 2 + 1];
        a0 += v0.x; a1 += v0.y; a2 += v0.z; a3 += v0.w;
        a4 += v1.x; a5 += v1.y; a6 += v1.z; a7 += v1.w;
    }
    ((float4*)out)[0] = make_float4(a0, a1, a2, a3);
    ((float4*)out)[1] = make_float4(a4, a5, a6, a7);
}

// ---------------- node embedding (wave per node, lane = output feature) ----------------
__global__ __launch_bounds__(256) void k_node_embed(const float* __restrict__ xi,
                                                    const float* __restrict__ xf,
                                                    const float* __restrict__ Wit, const float* __restrict__ bit,
                                                    const float* __restrict__ Wft, const float* __restrict__ bft,
                                                    float* __restrict__ inst, unsigned short* __restrict__ inst_bf,
                                                    float* __restrict__ fin) {
    const int NPW = 16;
    int lane = threadIdx.x & 63;
    int wave = (blockIdx.x * blockDim.x + threadIdx.x) >> 6;
    int base = wave * NPW;
    float wi[DN], wf[DN];
#pragma unroll
    for (int k = 0; k < DN; k++) { wi[k] = Wit[k * 64 + lane]; wf[k] = Wft[k * 64 + lane]; }
    float bi = bit[lane], bf = bft[lane];
    for (int n = 0; n < NPW; n++) {
        int i = base + n;
        if (i < NI) {
            const float* x = xi + (size_t)i * DN;
            float acc = bi;
#pragma unroll
            for (int k = 0; k < DN; k++) acc += x[k] * wi[k];
            float v = elu1(acc);
            inst[(size_t)i * 64 + lane] = v;
            inst_bf[(size_t)i * 64 + lane] = f2bf(v);
        } else if (i < NI + NF) {
            int f = i - NI;
            const float* x = xf + (size_t)f * DN;
            float acc = bf;
#pragma unroll
            for (int k = 0; k < DN; k++) acc += x[k] * wf[k];
            fin[(size_t)f * 64 + lane] = elu1(acc);
        }
    }
}

// ---------------- SpMM (gather-mean over bf16 rows), wave per dst node, lane = feature
__global__ __launch_bounds__(256) void k_spmm(const unsigned short* __restrict__ inst_bf,
                                              const int* __restrict__ rp,
                                              const int* __restrict__ colP, float* __restrict__ aggHp,
                                              const int* __restrict__ colS, float* __restrict__ aggHs,
                                              const int* __restrict__ colF, float* __restrict__ aggHf) {
    int lane = threadIdx.x & 63;
    int w = (blockIdx.x * blockDim.x + threadIdx.x) >> 6;
    const int* col; float* out; int i, rbase, ebase;
    if (w < NI)               { i = w;          rbase = 0;      ebase = 0;      col = colP; out = aggHp; }
    else if (w < 2 * NI)      { i = w - NI;     rbase = NI;     ebase = NE;     col = colS; out = aggHs; }
    else if (w < 2 * NI + NF) { i = w - 2 * NI; rbase = 2 * NI; ebase = 2 * NE; col = colF; out = aggHf; }
    else return;

    int s = rp[rbase + i] - ebase, e1 = rp[rbase + i + 1] - ebase;
    float acc = 0.f;
    for (int cs = s; cs < e1; cs += 64) {
        int nch = min(64, e1 - cs);
        int cv = (cs + lane < e1) ? col[cs + lane] : 0;
        int t = 0;
        for (; t + 8 <= nch; t += 8) {
#pragma unroll
            for (int u = 0; u < 8; u++) {
                int c = __shfl(cv, t + u, 64);
                acc += bf2f(inst_bf[(size_t)c * 64 + lane]);
            }
        }
        for (; t < nch; t++) {
            int c = __shfl(cv, t, 64);
            acc += bf2f(inst_bf[(size_t)c * 64 + lane]);
        }
    }
    int cnt = e1 - s;
    out[(size_t)i * 64 + lane] = acc * (cnt > 0 ? 1.f / (float)cnt : 0.f);
}

// ---------------- dense layer update for instruction nodes ----------------
__global__ __launch_bounds__(64, 1) void k_dense_inst(
    float* __restrict__ inst, unsigned short* __restrict__ inst_bf,
    const float* __restrict__ aggHp, const float* __restrict__ aggHs,
    const float* __restrict__ aggEp, const float* __restrict__ aggEs,
    const int* __restrict__ rpP, const int* __restrict__ rpS,
    const float* __restrict__ Wp, const float* __restrict__ bp,
    const float* __restrict__ Ws, const float* __restrict__ bs) {
    __shared__ float hL[64 * 65];
    const int lane = threadIdx.x;
    const int base = blockIdx.x * 64;
    const int i = base + lane;
    const bool valid = i < NI;
    const int ii = valid ? i : (NI - 1);

    int cP = rpP[ii + 1] - rpP[ii];
    int cS = rpS[ii + 1] - rpS[ii];
    float mP = (valid && cP > 0) ? 0.5f : 0.f;
    float mS = (valid && cS > 0) ? 0.5f : 0.f;
    float invP = 1.f / (float)max(cP, 1);
    float invS = 1.f / (float)max(cS, 1);
    float meP[8], meS[8];
#pragma unroll
    for (int k = 0; k < 8; k++) {
        meP[k] = aggEp[(size_t)ii * 8 + k] * invP;
        meS[k] = aggEs[(size_t)ii * 8 + k] * invS;
    }

    float accP[64], accS[64];
#pragma unroll
    for (int j = 0; j < 64; j++) { accP[j] = bp[j]; accS[j] = bs[j]; }

    for (int idx = lane; idx < 1024; idx += 64) {
        int n = idx >> 4, k4 = idx & 15;
        float4 v = ((const float4*)aggHp)[(size_t)min(base + n, NI - 1) * 16 + k4];
        float* d = &hL[n * 65 + k4 * 4];
        d[0] = v.x; d[1] = v.y; d[2] = v.z; d[3] = v.w;
    }
    __syncthreads();
#pragma unroll 4
    for (int k = 0; k < 64; k++) {
        float h = hL[lane * 65 + k];
#pragma unroll
        for (int j = 0; j < 64; j++) accP[j] += h * Wp[k * 64 + j];
    }
#pragma unroll
    for (int k = 0; k < 8; k++) {
#pragma unroll
        for (int j = 0; j < 64; j++) accP[j] += meP[k] * Wp[(64 + k) * 64 + j];
    }
    __syncthreads();

    for (int idx = lane; idx < 1024; idx += 64) {
        int n = idx >> 4, k4 = idx & 15;
        float4 v = ((const float4*)aggHs)[(size_t)min(base + n, NI - 1) * 16 + k4];
        float* d = &hL[n * 65 + k4 * 4];
        d[0] = v.x; d[1] = v.y; d[2] = v.z; d[3] = v.w;
    }
    __syncthreads();
#pragma unroll 4
    for (int k = 0; k < 64; k++) {
        float h = hL[lane * 65 + k];
#pragma unroll
        for (int j = 0; j < 64; j++) accS[j] += h * Ws[k * 64 + j];
    }
#pragma unroll
    for (int k = 0; k < 8; k++) {
#pragma unroll
        for (int j = 0; j < 64; j++) accS[j] += meS[k] * Ws[(64 + k) * 64 + j];
    }
    __syncthreads();

    for (int idx = lane; idx < 1024; idx += 64) {
        int n = idx >> 4, k4 = idx & 15;
        float4 v = ((const float4*)inst)[(size_t)min(base + n, NI - 1) * 16 + k4];
        float* d = &hL[n * 65 + k4 * 4];
        d[0] = v.x; d[1] = v.y; d[2] = v.z; d[3] = v.w;
    }
    __syncthreads();
#pragma unroll
    for (int j = 0; j < 64; j++) {
        float x = hL[lane * 65 + j] + mP * accP[j] + mS * accS[j];
        hL[lane * 65 + j] = elu1(x);
    }
    __syncthreads();
    for (int idx = lane; idx < 1024; idx += 64) {
        int n = idx >> 4, k4 = idx & 15;
        if (base + n < NI) {
            const float* sp = &hL[n * 65 + k4 * 4];
            ((float4*)inst)[(size_t)(base + n) * 16 + k4] = make_float4(sp[0], sp[1], sp[2], sp[3]);
            ushort4 bf;
            bf.x = f2bf(sp[0]); bf.y = f2bf(sp[1]); bf.z = f2bf(sp[2]); bf.w = f2bf(sp[3]);
            ((ushort4*)inst_bf)[(size_t)(base + n) * 16 + k4] = bf;
        }
    }
}

// ---------------- dense layer update for final nodes ----------------
__global__ __launch_bounds__(64, 1) void k_dense_fin(
    float* __restrict__ fin,
    const float* __restrict__ aggHf, const float* __restrict__ aggEf,
    const int* __restrict__ rpF,
    const float* __restrict__ Wf, const float* __restrict__ bf) {
    __shared__ float hL[64 * 65];
    const int lane = threadIdx.x;
    const int base = blockIdx.x * 64;
    const int i = base + lane;
    const bool valid = i < NF;
    const int ii = valid ? i : (NF - 1);

    int cF = rpF[ii + 1] - rpF[ii];
    float mF = (valid && cF > 0) ? 1.f : 0.f;
    float invF = 1.f / (float)max(cF, 1);
    float meF[8];
#pragma unroll
    for (int k = 0; k < 8; k++) meF[k] = aggEf[(size_t)ii * 8 + k] * invF;

    float acc[64];
#pragma unroll
    for (int j = 0; j < 64; j++) acc[j] = bf[j];

    for (int idx = lane; idx < 1024; idx += 64) {
        int n = idx >> 4, k4 = idx & 15;
        float4 v = ((const float4*)aggHf)[(size_t)min(base + n, NF - 1) * 16 + k4];
        float* d = &hL[n * 65 + k4 * 4];
        d[0] = v.x; d[1] = v.y; d[2] = v.z; d[3] = v.w;
    }
    __syncthreads();
#pragma unroll 4
    for (int k = 0; k < 64; k++) {
        float h = hL[lane * 65 + k];
#pragma unroll
        for (int j = 0; j < 64; j++) acc[j] += h * Wf[k * 64 + j];
    }
#pragma unroll
    for (int k = 0; k < 8; k++) {
#pragma unroll
        for (int j = 0; j < 64; j++) acc[j] += meF[k] * Wf[(64 + k) * 64 + j];
    }
    __syncthreads();

    for (int idx = lane; idx < 1024; idx += 64) {
        int n = idx >> 4, k4 = idx & 15;
        float4 v = ((const float4*)fin)[(size_t)min(base + n, NF - 1) * 16 + k4];
        float* d = &hL[n * 65 + k4 * 4];
        d[0] = v.x; d[1] = v.y; d[2] = v.z; d[3] = v.w;
    }
    __syncthreads();
#pragma unroll
    for (int j = 0; j < 64; j++) {
        float x = hL[lane * 65 + j] + mF * acc[j];
        hL[lane * 65 + j] = elu1(x);
    }
    __syncthreads();
    for (int idx = lane; idx < 1024; idx += 64) {
        int n = idx >> 4, k4 = idx & 15;
        if (base + n < NF) {
            const float* sp = &hL[n * 65 + k4 * 4];
            ((float4*)fin)[(size_t)(base + n) * 16 + k4] = make_float4(sp[0], sp[1], sp[2], sp[3]);
        }
    }
}

// ---------------- readout head ----------------
__global__ __launch_bounds__(64, 1) void k_head(
    const float* __restrict__ fin,
    const float* __restrict__ Wr1, const float* __restrict__ br1,
    const float* __restrict__ Wr2, const float* __restrict__ br2,
    const float* __restrict__ Wr3, const float* __restrict__ br3,
    float* __restrict__ out) {
    __shared__ float hL[64 * 65];
    const int lane = threadIdx.x;
    const int base = blockIdx.x * 64;

    for (int idx = lane; idx < 1024; idx += 64) {
        int n = idx >> 4, k4 = idx & 15;
        float4 v = ((const float4*)fin)[(size_t)min(base + n, NF - 1) * 16 + k4];
        float* d = &hL[n * 65 + k4 * 4];
        d[0] = v.x; d[1] = v.y; d[2] = v.z; d[3] = v.w;
    }
    __syncthreads();

    float acc[64];
#pragma unroll
    for (int j = 0; j < 64; j++) acc[j] = br1[j];
#pragma unroll 4
    for (int k = 0; k < 64; k++) {
        float h = hL[lane * 65 + k];
#pragma unroll
        for (int j = 0; j < 64; j++) acc[j] += h * Wr1[k * 64 + j];
    }
#pragma unroll
    for (int j = 0; j < 64; j++) hL[lane * 65 + j] = elu1(acc[j]);

#pragma unroll
    for (int j = 0; j < 64; j++) acc[j] = br2[j];
#pragma unroll 4
    for (int k = 0; k < 64; k++) {
        float h = hL[lane * 65 + k];
#pragma unroll
        for (int j = 0; j < 64; j++) acc[j] += h * Wr2[k * 64 + j];
    }
    float r = br3[0];
#pragma unroll
    for (int j = 0; j < 64; j++) r += elu1(acc[j]) * Wr3[j];

    int i = base + lane;
    if (i < NF) out[i] = r;
}

extern "C" void kernel_launch(void* const* d_in, const int* in_sizes, int n_in,
                              void* d_out, int out_size, void* d_ws, size_t ws_size,
                              hipStream_t stream) {
    const float* xi  = (const float*)d_in[0];
    const float* xf  = (const float*)d_in[1];
    const float* xe  = (const float*)d_in[2];
    const float* xef = (const float*)d_in[3];
    const int* prev_src = (const int*)d_in[4];
    const int* prev_dst = (const int*)d_in[5];
    const int* tf_src = (const int*)d_in[6];
    const int* tf_dst = (const int*)d_in[7];
    const float* W_it = (const float*)d_in[8];  const float* b_it = (const float*)d_in[9];
    const float* W_ft = (const float*)d_in[10]; const float* b_ft = (const float*)d_in[11];
    const float* W_ep = (const float*)d_in[12]; const float* b_ep = (const float*)d_in[13];
    const float* W_es = (const float*)d_in[14]; const float* b_es = (const float*)d_in[15];
    const float* W_ef = (const float*)d_in[16]; const float* b_ef = (const float*)d_in[17];
    const float* Wg_prev = (const float*)d_in[18]; const float* bg_prev = (const float*)d_in[19];
    const float* Wg_succ = (const float*)d_in[20]; const float* bg_succ = (const float*)d_in[21];
    const float* Wg_tf   = (const float*)d_in[22]; const float* bg_tf   = (const float*)d_in[23];
    const float* Wr1 = (const float*)d_in[24]; const float* br1 = (const float*)d_in[25];
    const float* Wr2 = (const float*)d_in[26]; const float* br2 = (const float*)d_in[27];
    const float* Wr3 = (const float*)d_in[28]; const float* br3 = (const float*)d_in[29];

    char* ws = (char*)d_ws;
    size_t off = 0;
    auto alloc = [&](size_t bytes) -> char* {
        char* p = ws + off;
        off += (bytes + 255) & ~(size_t)255;
        return p;
    };
    float* inst  = (float*)alloc((size_t)NI * 64 * 4);
    unsigned short* inst_bf = (unsigned short*)alloc((size_t)NI * 64 * 2);
    float* fin   = (float*)alloc((size_t)NF * 64 * 4);
    float* aggHp = (float*)alloc((size_t)NI * 64 * 4);
    float* aggHs = (float*)alloc((size_t)NI * 64 * 4);
    float* aggHf = (float*)alloc((size_t)NF * 64 * 4);
    float* aggEp = (float*)alloc((size_t)NI * 8 * 4);
    float* aggEs = (float*)alloc((size_t)NI * 8 * 4);
    float* aggEf = (float*)alloc((size_t)NF * 8 * 4);
    char* zero_begin = ws + off;
    int* cnt  = (int*)alloc((size_t)NT * 4);
    int* fill = (int*)alloc((size_t)NT * 4);
    char* zero_end = ws + off;
    int* rpAll = (int*)alloc((size_t)(NT + 1) * 4);
    int* colP = (int*)alloc((size_t)NE * 4);
    int* colS = (int*)alloc((size_t)NE * 4);
    int* colF = (int*)alloc((size_t)NEF * 4);
    int* bsum = (int*)alloc(1024 * 4);
    (void)ws_size; (void)in_sizes; (void)n_in; (void)out_size;

    // scatter-stage edge-embed buffers alias dead regions:
    //   ePbuf ~ aggHp, eSbuf ~ aggHs (first written by spmm, after eagg2)
    //   eFbuf ~ inst  (first written by node_embed, after eagg2)
    float* ePbuf = aggHp;
    float* eSbuf = aggHs;
    float* eFbuf = inst;

    hipMemsetAsync(zero_begin, 0, (size_t)(zero_end - zero_begin), stream);

    k_count<<<(NE + 255) / 256, 256, 0, stream>>>(prev_src, prev_dst, tf_dst, cnt);

    int nb = (NT + 255) / 256;
    k_scan1<<<nb, 256, 0, stream>>>(cnt, NT, rpAll, bsum);
    k_scan2<<<1, 1024, 0, stream>>>(bsum, nb);
    k_scan3<<<nb, 256, 0, stream>>>(rpAll, bsum, NT);

    k_scatter<<<(NE + 255) / 256, 256, 0, stream>>>(prev_src, prev_dst, tf_src, tf_dst,
                                                    xe, xef, rpAll, fill,
                                                    colP, colS, colF,
                                                    ePbuf, eSbuf, eFbuf,
                                                    W_ep, b_ep, W_es, b_es, W_ef, b_ef);

    k_eagg2<<<(NT + 255) / 256, 256, 0, stream>>>(rpAll, ePbuf, eSbuf, eFbuf,
                                                  aggEp, aggEs, aggEf);

    {
        int waves = (NI + NF + 15) / 16;
        int blocks = (waves + 3) / 4;
        k_node_embed<<<blocks, 256, 0, stream>>>(xi, xf, W_it, b_it, W_ft, b_ft,
                                                 inst, inst_bf, fin);
    }

    for (int l = 0; l < NL; l++) {
        int waves = 2 * NI + NF;
        k_spmm<<<(waves + 3) / 4, 256, 0, stream>>>(inst_bf, rpAll,
                                                    colP, aggHp,
                                                    colS, aggHs,
                                                    colF, aggHf);
        k_dense_inst<<<(NI + 63) / 64, 64, 0, stream>>>(inst, inst_bf, aggHp, aggHs, aggEp, aggEs,
                                                        rpAll, rpAll + NI,
                                                        Wg_prev + (size_t)l * 72 * 64, bg_prev + (size_t)l * 64,
                                                        Wg_succ + (size_t)l * 72 * 64, bg_succ + (size_t)l * 64);
        k_dense_fin<<<(NF + 63) / 64, 64, 0, stream>>>(fin, aggHf, aggEf, rpAll + 2 * NI,
                                                       Wg_tf + (size_t)l * 72 * 64, bg_tf + (size_t)l * 64);
    }

    k_head<<<(NF + 63) / 64, 64, 0, stream>>>(fin, Wr1, br1, Wr2, br2, Wr3, br3, (float*)d_out);
}

// Round 4
// 2327.012 us; speedup vs baseline: 1.7857x; 1.4811x over previous
//
#include <hip/hip_runtime.h>
#include <math.h>

#define NI 100000
#define NF 2000
#define NE 800000
#define NEF 200000
#define DN 16
#define NL 11
#define NT (2 * NI + NF)   // concatenated node-direction count: P | S | F
#define KX 160             // padded K stride of X (bf16): 64 P | 8 meP | 64 S | 8 meS | 16 zero

typedef short bf16x8 __attribute__((ext_vector_type(8)));
typedef float f32x4 __attribute__((ext_vector_type(4)));

__device__ __forceinline__ float elu1(float x) { return x > 0.f ? x : expm1f(x); }

__device__ __forceinline__ unsigned short f2bf(float f) {
    unsigned x = __float_as_uint(f);
    return (unsigned short)((x + 0x7fffu + ((x >> 16) & 1u)) >> 16);
}
__device__ __forceinline__ float bf2f(unsigned short u) {
    return __uint_as_float(((unsigned)u) << 16);
}

// ---------------- CSR build (concatenated P|S|F degree array) ----------------
__global__ __launch_bounds__(256) void k_count(const int* __restrict__ prev_src,
                                               const int* __restrict__ prev_dst,
                                               const int* __restrict__ tf_dst,
                                               int* cnt) {
    int i = blockIdx.x * blockDim.x + threadIdx.x;
    if (i < NE) {
        atomicAdd(&cnt[prev_dst[i]], 1);
        atomicAdd(&cnt[NI + prev_src[i]], 1);
    }
    if (i < NEF) atomicAdd(&cnt[2 * NI + tf_dst[i]], 1);
}

__global__ __launch_bounds__(256) void k_scan1(const int* __restrict__ cnt, int n,
                                               int* __restrict__ rp, int* __restrict__ bsum) {
    __shared__ int s[256];
    int t = threadIdx.x, b = blockIdx.x, i = b * 256 + t;
    int v = (i < n) ? cnt[i] : 0;
    s[t] = v; __syncthreads();
    for (int o = 1; o < 256; o <<= 1) {
        int x = (t >= o) ? s[t - o] : 0;
        __syncthreads();
        s[t] += x;
        __syncthreads();
    }
    if (i < n) rp[i + 1] = s[t];
    if (t == 255) bsum[b] = s[255];
}

__global__ __launch_bounds__(1024) void k_scan2(int* __restrict__ bsum, int nb) {
    __shared__ int s[1024];
    int t = threadIdx.x;
    int v = (t < nb) ? bsum[t] : 0;
    s[t] = v; __syncthreads();
    for (int o = 1; o < 1024; o <<= 1) {
        int x = (t >= o) ? s[t - o] : 0;
        __syncthreads();
        s[t] += x;
        __syncthreads();
    }
    if (t < nb) bsum[t] = s[t] - v;   // exclusive block offsets
}

__global__ __launch_bounds__(256) void k_scan3(int* __restrict__ rp, const int* __restrict__ bsum, int n) {
    int i = blockIdx.x * blockDim.x + threadIdx.x;
    if (i < n) rp[i + 1] += bsum[i >> 8];
    if (i == 0) rp[0] = 0;
}

// ---------------- scatter: CSR cols + fused edge-embed written in CSR slot order ----
__global__ __launch_bounds__(256) void k_scatter(const int* __restrict__ prev_src,
                                                 const int* __restrict__ prev_dst,
                                                 const int* __restrict__ tf_src,
                                                 const int* __restrict__ tf_dst,
                                                 const float* __restrict__ xe,
                                                 const float* __restrict__ xef,
                                                 const int* __restrict__ rp,
                                                 int* fill,
                                                 int* colP, int* colS, int* colF,
                                                 float* __restrict__ ePbuf,
                                                 float* __restrict__ eSbuf,
                                                 float* __restrict__ eFbuf,
                                                 const float* __restrict__ Wep, const float* __restrict__ bep,
                                                 const float* __restrict__ Wes, const float* __restrict__ bes,
                                                 const float* __restrict__ Wef, const float* __restrict__ bef) {
    int i = blockIdx.x * blockDim.x + threadIdx.x;
    if (i < NE) {
        int s = prev_src[i], d = prev_dst[i];
        float4 x0 = ((const float4*)xe)[(size_t)i * 2];
        float4 x1 = ((const float4*)xe)[(size_t)i * 2 + 1];
        float x[8] = {x0.x, x0.y, x0.z, x0.w, x1.x, x1.y, x1.z, x1.w};
        float eP[8], eS[8];
#pragma unroll
        for (int j = 0; j < 8; j++) {
            float vp = bep[j], vs = bes[j];
#pragma unroll
            for (int k = 0; k < 8; k++) { vp += x[k] * Wep[k * 8 + j]; vs += x[k] * Wes[k * 8 + j]; }
            eP[j] = elu1(vp); eS[j] = elu1(vs);
        }
        int tP = rp[d] + atomicAdd(&fill[d], 1);
        colP[tP] = s;
        ((float4*)ePbuf)[(size_t)tP * 2]     = make_float4(eP[0], eP[1], eP[2], eP[3]);
        ((float4*)ePbuf)[(size_t)tP * 2 + 1] = make_float4(eP[4], eP[5], eP[6], eP[7]);
        int tS = rp[NI + s] - NE + atomicAdd(&fill[NI + s], 1);
        colS[tS] = d;
        ((float4*)eSbuf)[(size_t)tS * 2]     = make_float4(eS[0], eS[1], eS[2], eS[3]);
        ((float4*)eSbuf)[(size_t)tS * 2 + 1] = make_float4(eS[4], eS[5], eS[6], eS[7]);
    }
    if (i < NEF) {
        int s = tf_src[i], d = tf_dst[i];
        float4 x0 = ((const float4*)xef)[(size_t)i * 2];
        float4 x1 = ((const float4*)xef)[(size_t)i * 2 + 1];
        float x[8] = {x0.x, x0.y, x0.z, x0.w, x1.x, x1.y, x1.z, x1.w};
        float eF[8];
#pragma unroll
        for (int j = 0; j < 8; j++) {
            float v = bef[j];
#pragma unroll
            for (int k = 0; k < 8; k++) v += x[k] * Wef[k * 8 + j];
            eF[j] = elu1(v);
        }
        int tF = rp[2 * NI + d] - 2 * NE + atomicAdd(&fill[2 * NI + d], 1);
        colF[tF] = s;
        ((float4*)eFbuf)[(size_t)tF * 2]     = make_float4(eF[0], eF[1], eF[2], eF[3]);
        ((float4*)eFbuf)[(size_t)tF * 2 + 1] = make_float4(eF[4], eF[5], eF[6], eF[7]);
    }
}

// ---------------- edge-embed aggregation: sequential run-sum per node ----------------
__global__ __launch_bounds__(256) void k_eagg2(const int* __restrict__ rp,
                                               const float* __restrict__ ePbuf,
                                               const float* __restrict__ eSbuf,
                                               const float* __restrict__ eFbuf,
                                               float* __restrict__ aggEp,
                                               float* __restrict__ aggEs,
                                               float* __restrict__ aggEf) {
    int idx = blockIdx.x * blockDim.x + threadIdx.x;
    if (idx >= NT) return;
    const float* buf; float* out; int s, e;
    if (idx < NF) {
        int n = idx;
        s = rp[2 * NI + n] - 2 * NE; e = rp[2 * NI + n + 1] - 2 * NE;
        buf = eFbuf; out = aggEf + (size_t)n * 8;
    } else if (idx < NF + NI) {
        int n = idx - NF;
        s = rp[n]; e = rp[n + 1];
        buf = ePbuf; out = aggEp + (size_t)n * 8;
    } else {
        int n = idx - NF - NI;
        s = rp[NI + n] - NE; e = rp[NI + n + 1] - NE;
        buf = eSbuf; out = aggEs + (size_t)n * 8;
    }
    float a0 = 0.f, a1 = 0.f, a2 = 0.f, a3 = 0.f, a4 = 0.f, a5 = 0.f, a6 = 0.f, a7 = 0.f;
    for (int t = s; t < e; ++t) {
        float4 v0 = ((const float4*)buf)[(size_t)t * 2];
        float4 v1 = ((const float4*)buf)[(size_t)t * 2 + 1];
        a0 += v0.x; a1 += v0.y; a2 += v0.z; a3 += v0.w;
        a4 += v1.x; a5 += v1.y; a6 += v1.z; a7 += v1.w;
    }
    ((float4*)out)[0] = make_float4(a0, a1, a2, a3);
    ((float4*)out)[1] = make_float4(a4, a5, a6, a7);
}

// ---------------- prep X: layer-invariant me-columns + zero pad ----------------
__global__ __launch_bounds__(256) void k_prep_x(const int* __restrict__ rpAll,
                                                const float* __restrict__ aggEp,
                                                const float* __restrict__ aggEs,
                                                unsigned short* __restrict__ X) {
    int i = blockIdx.x * blockDim.x + threadIdx.x;
    if (i >= NI) return;
    int cP = rpAll[i + 1] - rpAll[i];
    int cS = rpAll[NI + i + 1] - rpAll[NI + i];
    float invP = 1.f / (float)max(cP, 1);
    float invS = 1.f / (float)max(cS, 1);
    unsigned short* xr = X + (size_t)i * KX;
#pragma unroll
    for (int c = 0; c < 2; c++) {
        float4 ep = ((const float4*)(aggEp + (size_t)i * 8))[c];
        float4 es = ((const float4*)(aggEs + (size_t)i * 8))[c];
        ushort4 up; up.x = f2bf(ep.x * invP); up.y = f2bf(ep.y * invP);
                    up.z = f2bf(ep.z * invP); up.w = f2bf(ep.w * invP);
        ushort4 us; us.x = f2bf(es.x * invS); us.y = f2bf(es.y * invS);
                    us.z = f2bf(es.z * invS); us.w = f2bf(es.w * invS);
        ((ushort4*)(xr + 64))[c]  = up;
        ((ushort4*)(xr + 136))[c] = us;
    }
    ushort4 z; z.x = z.y = z.z = z.w = 0;
#pragma unroll
    for (int c = 0; c < 4; c++) ((ushort4*)(xr + 144))[c] = z;
}

// ---------------- node embedding (wave per node, lane = output feature) ----------------
__global__ __launch_bounds__(256) void k_node_embed(const float* __restrict__ xi,
                                                    const float* __restrict__ xf,
                                                    const float* __restrict__ Wit, const float* __restrict__ bit,
                                                    const float* __restrict__ Wft, const float* __restrict__ bft,
                                                    float* __restrict__ inst, unsigned short* __restrict__ inst_bf,
                                                    float* __restrict__ fin) {
    const int NPW = 16;
    int lane = threadIdx.x & 63;
    int wave = (blockIdx.x * blockDim.x + threadIdx.x) >> 6;
    int base = wave * NPW;
    float wi[DN], wf[DN];
#pragma unroll
    for (int k = 0; k < DN; k++) { wi[k] = Wit[k * 64 + lane]; wf[k] = Wft[k * 64 + lane]; }
    float bi = bit[lane], bf = bft[lane];
    for (int n = 0; n < NPW; n++) {
        int i = base + n;
        if (i < NI) {
            const float* x = xi + (size_t)i * DN;
            float acc = bi;
#pragma unroll
            for (int k = 0; k < DN; k++) acc += x[k] * wi[k];
            float v = elu1(acc);
            inst[(size_t)i * 64 + lane] = v;
            inst_bf[(size_t)i * 64 + lane] = f2bf(v);
        } else if (i < NI + NF) {
            int f = i - NI;
            const float* x = xf + (size_t)f * DN;
            float acc = bf;
#pragma unroll
            for (int k = 0; k < DN; k++) acc += x[k] * wf[k];
            fin[(size_t)f * 64 + lane] = elu1(acc);
        }
    }
}

// ---------------- SpMM (gather-mean over bf16 rows), wave per dst node, lane = feature
// P/S write bf16 means straight into X columns; F writes fp32 aggHf.
__global__ __launch_bounds__(256) void k_spmm(const unsigned short* __restrict__ inst_bf,
                                              const int* __restrict__ rp,
                                              const int* __restrict__ colP,
                                              const int* __restrict__ colS,
                                              const int* __restrict__ colF,
                                              unsigned short* __restrict__ X,
                                              float* __restrict__ aggHf) {
    int lane = threadIdx.x & 63;
    int w = (blockIdx.x * blockDim.x + threadIdx.x) >> 6;
    const int* col; int i, rbase, ebase, xoff;
    if (w < NI)               { i = w;          rbase = 0;      ebase = 0;      col = colP; xoff = 0;  }
    else if (w < 2 * NI)      { i = w - NI;     rbase = NI;     ebase = NE;     col = colS; xoff = 72; }
    else if (w < 2 * NI + NF) { i = w - 2 * NI; rbase = 2 * NI; ebase = 2 * NE; col = colF; xoff = -1; }
    else return;

    int s = rp[rbase + i] - ebase, e1 = rp[rbase + i + 1] - ebase;
    float acc = 0.f;
    for (int cs = s; cs < e1; cs += 64) {
        int nch = min(64, e1 - cs);
        int cv = (cs + lane < e1) ? col[cs + lane] : 0;
        int t = 0;
        for (; t + 8 <= nch; t += 8) {
#pragma unroll
            for (int u = 0; u < 8; u++) {
                int c = __shfl(cv, t + u, 64);
                acc += bf2f(inst_bf[(size_t)c * 64 + lane]);
            }
        }
        for (; t < nch; t++) {
            int c = __shfl(cv, t, 64);
            acc += bf2f(inst_bf[(size_t)c * 64 + lane]);
        }
    }
    int cnt = e1 - s;
    float mean = acc * (cnt > 0 ? 1.f / (float)cnt : 0.f);
    if (xoff >= 0) X[(size_t)i * KX + xoff + lane] = f2bf(mean);
    else           aggHf[(size_t)i * 64 + lane] = mean;
}

// ---------------- dense layer update for instruction nodes: bf16 MFMA GEMM ----------------
// X[NI][160] @ Wcat[160][64], Wcat = 0.5*[Wp(72); Ws(72); 0(16)], epilogue residual+elu.
__global__ __launch_bounds__(256) void k_dense_mfma(
    const unsigned short* __restrict__ X,
    float* __restrict__ inst, unsigned short* __restrict__ inst_bf,
    const int* __restrict__ rpAll,
    const float* __restrict__ Wp, const float* __restrict__ bp,
    const float* __restrict__ Ws, const float* __restrict__ bs) {
    __shared__ __align__(16) unsigned short Wt[64][168];  // [n][k] transposed 0.5*Wcat, +8 pad
    int t = threadIdx.x;
    for (int idx = t; idx < 64 * 168; idx += 256) {
        int n = idx / 168, k = idx % 168;
        float v = 0.f;
        if (k < 72)       v = 0.5f * Wp[k * 64 + n];
        else if (k < 144) v = 0.5f * Ws[(k - 72) * 64 + n];
        Wt[n][k] = f2bf(v);
    }
    __syncthreads();

    int wave = t >> 6, lane = t & 63;
    int rowbase = blockIdx.x * 128 + wave * 32;   // this wave's 32 rows
    int lrow = lane & 15, lk = (lane >> 4) * 8;

    f32x4 acc[2][4];
#pragma unroll
    for (int rb = 0; rb < 2; rb++)
#pragma unroll
        for (int nb = 0; nb < 4; nb++) acc[rb][nb] = (f32x4){0.f, 0.f, 0.f, 0.f};

#pragma unroll
    for (int kc = 0; kc < 5; kc++) {
        int k0 = kc * 32 + lk;
        bf16x8 a[2], b[4];
#pragma unroll
        for (int rb = 0; rb < 2; rb++) {
            int r = min(rowbase + rb * 16 + lrow, NI - 1);
            a[rb] = *(const bf16x8*)(X + (size_t)r * KX + k0);
        }
#pragma unroll
        for (int nb = 0; nb < 4; nb++)
            b[nb] = *(const bf16x8*)(&Wt[nb * 16 + lrow][k0]);
#pragma unroll
        for (int rb = 0; rb < 2; rb++)
#pragma unroll
            for (int nb = 0; nb < 4; nb++)
                acc[rb][nb] = __builtin_amdgcn_mfma_f32_16x16x32_bf16(a[rb], b[nb], acc[rb][nb], 0, 0, 0);
    }

    // epilogue: C[row= (lane>>4)*4+j, col= nb*16 + (lane&15)]
#pragma unroll
    for (int rb = 0; rb < 2; rb++) {
#pragma unroll
        for (int j = 0; j < 4; j++) {
            int node = rowbase + rb * 16 + (lane >> 4) * 4 + j;
            bool v = node < NI;
            int nn = v ? node : NI - 1;
            float mP = (v && (rpAll[nn + 1] > rpAll[nn])) ? 0.5f : 0.f;
            float mS = (v && (rpAll[NI + nn + 1] > rpAll[NI + nn])) ? 0.5f : 0.f;
#pragma unroll
            for (int nb = 0; nb < 4; nb++) {
                int col = nb * 16 + lrow;
                float x = inst[(size_t)nn * 64 + col] + acc[rb][nb][j] + mP * bp[col] + mS * bs[col];
                x = elu1(x);
                if (v) {
                    inst[(size_t)nn * 64 + col] = x;
                    inst_bf[(size_t)nn * 64 + col] = f2bf(x);
                }
            }
        }
    }
}

// ---------------- dense layer update for final nodes (fp32 vector, tiny) ----------------
__global__ __launch_bounds__(64, 1) void k_dense_fin(
    float* __restrict__ fin,
    const float* __restrict__ aggHf, const float* __restrict__ aggEf,
    const int* __restrict__ rpF,
    const float* __restrict__ Wf, const float* __restrict__ bf) {
    __shared__ float hL[64 * 65];
    const int lane = threadIdx.x;
    const int base = blockIdx.x * 64;
    const int i = base + lane;
    const bool valid = i < NF;
    const int ii = valid ? i : (NF - 1);

    int cF = rpF[ii + 1] - rpF[ii];
    float mF = (valid && cF > 0) ? 1.f : 0.f;
    float invF = 1.f / (float)max(cF, 1);
    float meF[8];
#pragma unroll
    for (int k = 0; k < 8; k++) meF[k] = aggEf[(size_t)ii * 8 + k] * invF;

    float acc[64];
#pragma unroll
    for (int j = 0; j < 64; j++) acc[j] = bf[j];

    for (int idx = lane; idx < 1024; idx += 64) {
        int n = idx >> 4, k4 = idx & 15;
        float4 v = ((const float4*)aggHf)[(size_t)min(base + n, NF - 1) * 16 + k4];
        float* d = &hL[n * 65 + k4 * 4];
        d[0] = v.x; d[1] = v.y; d[2] = v.z; d[3] = v.w;
    }
    __syncthreads();
#pragma unroll 4
    for (int k = 0; k < 64; k++) {
        float h = hL[lane * 65 + k];
#pragma unroll
        for (int j = 0; j < 64; j++) acc[j] += h * Wf[k * 64 + j];
    }
#pragma unroll
    for (int k = 0; k < 8; k++) {
#pragma unroll
        for (int j = 0; j < 64; j++) acc[j] += meF[k] * Wf[(64 + k) * 64 + j];
    }
    __syncthreads();

    for (int idx = lane; idx < 1024; idx += 64) {
        int n = idx >> 4, k4 = idx & 15;
        float4 v = ((const float4*)fin)[(size_t)min(base + n, NF - 1) * 16 + k4];
        float* d = &hL[n * 65 + k4 * 4];
        d[0] = v.x; d[1] = v.y; d[2] = v.z; d[3] = v.w;
    }
    __syncthreads();
#pragma unroll
    for (int j = 0; j < 64; j++) {
        float x = hL[lane * 65 + j] + mF * acc[j];
        hL[lane * 65 + j] = elu1(x);
    }
    __syncthreads();
    for (int idx = lane; idx < 1024; idx += 64) {
        int n = idx >> 4, k4 = idx & 15;
        if (base + n < NF) {
            const float* sp = &hL[n * 65 + k4 * 4];
            ((float4*)fin)[(size_t)(base + n) * 16 + k4] = make_float4(sp[0], sp[1], sp[2], sp[3]);
        }
    }
}

// ---------------- readout head ----------------
__global__ __launch_bounds__(64, 1) void k_head(
    const float* __restrict__ fin,
    const float* __restrict__ Wr1, const float* __restrict__ br1,
    const float* __restrict__ Wr2, const float* __restrict__ br2,
    const float* __restrict__ Wr3, const float* __restrict__ br3,
    float* __restrict__ out) {
    __shared__ float hL[64 * 65];
    const int lane = threadIdx.x;
    const int base = blockIdx.x * 64;

    for (int idx = lane; idx < 1024; idx += 64) {
        int n = idx >> 4, k4 = idx & 15;
        float4 v = ((const float4*)fin)[(size_t)min(base + n, NF - 1) * 16 + k4];
        float* d = &hL[n * 65 + k4 * 4];
        d[0] = v.x; d[1] = v.y; d[2] = v.z; d[3] = v.w;
    }
    __syncthreads();

    float acc[64];
#pragma unroll
    for (int j = 0; j < 64; j++) acc[j] = br1[j];
#pragma unroll 4
    for (int k = 0; k < 64; k++) {
        float h = hL[lane * 65 + k];
#pragma unroll
        for (int j = 0; j < 64; j++) acc[j] += h * Wr1[k * 64 + j];
    }
#pragma unroll
    for (int j = 0; j < 64; j++) hL[lane * 65 + j] = elu1(acc[j]);

#pragma unroll
    for (int j = 0; j < 64; j++) acc[j] = br2[j];
#pragma unroll 4
    for (int k = 0; k < 64; k++) {
        float h = hL[lane * 65 + k];
#pragma unroll
        for (int j = 0; j < 64; j++) acc[j] += h * Wr2[k * 64 + j];
    }
    float r = br3[0];
#pragma unroll
    for (int j = 0; j < 64; j++) r += elu1(acc[j]) * Wr3[j];

    int i = base + lane;
    if (i < NF) out[i] = r;
}

extern "C" void kernel_launch(void* const* d_in, const int* in_sizes, int n_in,
                              void* d_out, int out_size, void* d_ws, size_t ws_size,
                              hipStream_t stream) {
    const float* xi  = (const float*)d_in[0];
    const float* xf  = (const float*)d_in[1];
    const float* xe  = (const float*)d_in[2];
    const float* xef = (const float*)d_in[3];
    const int* prev_src = (const int*)d_in[4];
    const int* prev_dst = (const int*)d_in[5];
    const int* tf_src = (const int*)d_in[6];
    const int* tf_dst = (const int*)d_in[7];
    const float* W_it = (const float*)d_in[8];  const float* b_it = (const float*)d_in[9];
    const float* W_ft = (const float*)d_in[10]; const float* b_ft = (const float*)d_in[11];
    const float* W_ep = (const float*)d_in[12]; const float* b_ep = (const float*)d_in[13];
    const float* W_es = (const float*)d_in[14]; const float* b_es = (const float*)d_in[15];
    const float* W_ef = (const float*)d_in[16]; const float* b_ef = (const float*)d_in[17];
    const float* Wg_prev = (const float*)d_in[18]; const float* bg_prev = (const float*)d_in[19];
    const float* Wg_succ = (const float*)d_in[20]; const float* bg_succ = (const float*)d_in[21];
    const float* Wg_tf   = (const float*)d_in[22]; const float* bg_tf   = (const float*)d_in[23];
    const float* Wr1 = (const float*)d_in[24]; const float* br1 = (const float*)d_in[25];
    const float* Wr2 = (const float*)d_in[26]; const float* br2 = (const float*)d_in[27];
    const float* Wr3 = (const float*)d_in[28]; const float* br3 = (const float*)d_in[29];

    char* ws = (char*)d_ws;
    size_t off = 0;
    auto alloc = [&](size_t bytes) -> char* {
        char* p = ws + off;
        off += (bytes + 255) & ~(size_t)255;
        return p;
    };
    float* inst  = (float*)alloc((size_t)NI * 64 * 4);
    unsigned short* inst_bf = (unsigned short*)alloc((size_t)NI * 64 * 2);
    unsigned short* X = (unsigned short*)alloc((size_t)NI * KX * 2);
    float* fin   = (float*)alloc((size_t)NF * 64 * 4);
    float* aggHf = (float*)alloc((size_t)NF * 64 * 4);
    float* aggEp = (float*)alloc((size_t)NI * 8 * 4);
    float* aggEs = (float*)alloc((size_t)NI * 8 * 4);
    float* aggEf = (float*)alloc((size_t)NF * 8 * 4);
    char* zero_begin = ws + off;
    int* cnt  = (int*)alloc((size_t)NT * 4);
    int* fill = (int*)alloc((size_t)NT * 4);
    char* zero_end = ws + off;
    int* rpAll = (int*)alloc((size_t)(NT + 1) * 4);
    int* colP = (int*)alloc((size_t)NE * 4);
    int* colS = (int*)alloc((size_t)NE * 4);
    int* colF = (int*)alloc((size_t)NEF * 4);
    int* bsum = (int*)alloc(1024 * 4);
    (void)ws_size; (void)in_sizes; (void)n_in; (void)out_size;

    // scatter-stage edge-embed buffers alias regions that are dead until after k_eagg2:
    //   ePbuf (NE*32B = 25.6MB) -> X (32MB, first live cols written by k_prep_x/spmm)
    //   eSbuf (NE*32B = 25.6MB) -> inst (25.6MB, first written by k_node_embed)
    //   eFbuf (NEF*32B = 6.4MB) -> inst_bf (12.8MB, first written by k_node_embed)
    float* ePbuf = (float*)X;
    float* eSbuf = inst;
    float* eFbuf = (float*)inst_bf;

    hipMemsetAsync(zero_begin, 0, (size_t)(zero_end - zero_begin), stream);

    k_count<<<(NE + 255) / 256, 256, 0, stream>>>(prev_src, prev_dst, tf_dst, cnt);

    int nb = (NT + 255) / 256;
    k_scan1<<<nb, 256, 0, stream>>>(cnt, NT, rpAll, bsum);
    k_scan2<<<1, 1024, 0, stream>>>(bsum, nb);
    k_scan3<<<nb, 256, 0, stream>>>(rpAll, bsum, NT);

    k_scatter<<<(NE + 255) / 256, 256, 0, stream>>>(prev_src, prev_dst, tf_src, tf_dst,
                                                    xe, xef, rpAll, fill,
                                                    colP, colS, colF,
                                                    ePbuf, eSbuf, eFbuf,
                                                    W_ep, b_ep, W_es, b_es, W_ef, b_ef);

    k_eagg2<<<(NT + 255) / 256, 256, 0, stream>>>(rpAll, ePbuf, eSbuf, eFbuf,
                                                  aggEp, aggEs, aggEf);

    k_prep_x<<<(NI + 255) / 256, 256, 0, stream>>>(rpAll, aggEp, aggEs, X);

    {
        int waves = (NI + NF + 15) / 16;
        int blocks = (waves + 3) / 4;
        k_node_embed<<<blocks, 256, 0, stream>>>(xi, xf, W_it, b_it, W_ft, b_ft,
                                                 inst, inst_bf, fin);
    }

    for (int l = 0; l < NL; l++) {
        int waves = 2 * NI + NF;
        k_spmm<<<(waves + 3) / 4, 256, 0, stream>>>(inst_bf, rpAll,
                                                    colP, colS, colF,
                                                    X, aggHf);
        k_dense_mfma<<<(NI + 127) / 128, 256, 0, stream>>>(X, inst, inst_bf, rpAll,
                                                           Wg_prev + (size_t)l * 72 * 64, bg_prev + (size_t)l * 64,
                                                           Wg_succ + (size_t)l * 72 * 64, bg_succ + (size_t)l * 64);
        k_dense_fin<<<(NF + 63) / 64, 64, 0, stream>>>(fin, aggHf, aggEf, rpAll + 2 * NI,
                                                       Wg_tf + (size_t)l * 72 * 64, bg_tf + (size_t)l * 64);
    }

    k_head<<<(NF + 63) / 64, 64, 0, stream>>>(fin, Wr1, br1, Wr2, br2, Wr3, br3, (float*)d_out);
}

// Round 8
// 2029.619 us; speedup vs baseline: 2.0473x; 1.1465x over previous
//
#include <hip/hip_runtime.h>
#include <math.h>

#define NI 100000
#define NF 2000
#define NE 800000
#define NEF 200000
#define DN 16
#define NL 11
#define NT (2 * NI + NF)   // concatenated node-direction count: P | S | F
#define KX 160             // padded K stride of X (bf16): 64 P | 8 meP | 64 S | 8 meS | 16 zero

typedef short bf16x8 __attribute__((ext_vector_type(8)));
typedef float f32x4 __attribute__((ext_vector_type(4)));

__device__ __forceinline__ float elu1(float x) { return x > 0.f ? x : expm1f(x); }

__device__ __forceinline__ unsigned short f2bf(float f) {
    unsigned x = __float_as_uint(f);
    return (unsigned short)((x + 0x7fffu + ((x >> 16) & 1u)) >> 16);
}
__device__ __forceinline__ float bf2f(unsigned short u) {
    return __uint_as_float(((unsigned)u) << 16);
}

// ---------------- CSR build (concatenated P|S|F degree array) ----------------
__global__ __launch_bounds__(256) void k_count(const int* __restrict__ prev_src,
                                               const int* __restrict__ prev_dst,
                                               const int* __restrict__ tf_dst,
                                               int* cnt) {
    int i = blockIdx.x * blockDim.x + threadIdx.x;
    if (i < NE) {
        atomicAdd(&cnt[prev_dst[i]], 1);
        atomicAdd(&cnt[NI + prev_src[i]], 1);
    }
    if (i < NEF) atomicAdd(&cnt[2 * NI + tf_dst[i]], 1);
}

__global__ __launch_bounds__(256) void k_scan1(const int* __restrict__ cnt, int n,
                                               int* __restrict__ rp, int* __restrict__ bsum) {
    __shared__ int s[256];
    int t = threadIdx.x, b = blockIdx.x, i = b * 256 + t;
    int v = (i < n) ? cnt[i] : 0;
    s[t] = v; __syncthreads();
    for (int o = 1; o < 256; o <<= 1) {
        int x = (t >= o) ? s[t - o] : 0;
        __syncthreads();
        s[t] += x;
        __syncthreads();
    }
    if (i < n) rp[i + 1] = s[t];
    if (t == 255) bsum[b] = s[255];
}

__global__ __launch_bounds__(1024) void k_scan2(int* __restrict__ bsum, int nb) {
    __shared__ int s[1024];
    int t = threadIdx.x;
    int v = (t < nb) ? bsum[t] : 0;
    s[t] = v; __syncthreads();
    for (int o = 1; o < 1024; o <<= 1) {
        int x = (t >= o) ? s[t - o] : 0;
        __syncthreads();
        s[t] += x;
        __syncthreads();
    }
    if (t < nb) bsum[t] = s[t] - v;   // exclusive block offsets
}

__global__ __launch_bounds__(256) void k_scan3(int* __restrict__ rp, const int* __restrict__ bsum, int n) {
    int i = blockIdx.x * blockDim.x + threadIdx.x;
    if (i < n) rp[i + 1] += bsum[i >> 8];
    if (i == 0) rp[0] = 0;
}

// ---------------- scatter: CSR cols + fused edge-embed (fp32) in CSR slot order ----
__global__ __launch_bounds__(256) void k_scatter(const int* __restrict__ prev_src,
                                                 const int* __restrict__ prev_dst,
                                                 const int* __restrict__ tf_src,
                                                 const int* __restrict__ tf_dst,
                                                 const float* __restrict__ xe,
                                                 const float* __restrict__ xef,
                                                 const int* __restrict__ rp,
                                                 int* fill,
                                                 int* colP, int* colS, int* colF,
                                                 float* __restrict__ ePbuf,
                                                 float* __restrict__ eSbuf,
                                                 float* __restrict__ eFbuf,
                                                 const float* __restrict__ Wep, const float* __restrict__ bep,
                                                 const float* __restrict__ Wes, const float* __restrict__ bes,
                                                 const float* __restrict__ Wef, const float* __restrict__ bef) {
    int i = blockIdx.x * blockDim.x + threadIdx.x;
    if (i < NE) {
        int s = prev_src[i], d = prev_dst[i];
        float4 x0 = ((const float4*)xe)[(size_t)i * 2];
        float4 x1 = ((const float4*)xe)[(size_t)i * 2 + 1];
        float x[8] = {x0.x, x0.y, x0.z, x0.w, x1.x, x1.y, x1.z, x1.w};
        float eP[8], eS[8];
#pragma unroll
        for (int j = 0; j < 8; j++) {
            float vp = bep[j], vs = bes[j];
#pragma unroll
            for (int k = 0; k < 8; k++) { vp += x[k] * Wep[k * 8 + j]; vs += x[k] * Wes[k * 8 + j]; }
            eP[j] = elu1(vp); eS[j] = elu1(vs);
        }
        int tP = rp[d] + atomicAdd(&fill[d], 1);
        colP[tP] = s;
        ((float4*)ePbuf)[(size_t)tP * 2]     = make_float4(eP[0], eP[1], eP[2], eP[3]);
        ((float4*)ePbuf)[(size_t)tP * 2 + 1] = make_float4(eP[4], eP[5], eP[6], eP[7]);
        int tS = rp[NI + s] - NE + atomicAdd(&fill[NI + s], 1);
        colS[tS] = d;
        ((float4*)eSbuf)[(size_t)tS * 2]     = make_float4(eS[0], eS[1], eS[2], eS[3]);
        ((float4*)eSbuf)[(size_t)tS * 2 + 1] = make_float4(eS[4], eS[5], eS[6], eS[7]);
    }
    if (i < NEF) {
        int s = tf_src[i], d = tf_dst[i];
        float4 x0 = ((const float4*)xef)[(size_t)i * 2];
        float4 x1 = ((const float4*)xef)[(size_t)i * 2 + 1];
        float x[8] = {x0.x, x0.y, x0.z, x0.w, x1.x, x1.y, x1.z, x1.w};
        float eF[8];
#pragma unroll
        for (int j = 0; j < 8; j++) {
            float v = bef[j];
#pragma unroll
            for (int k = 0; k < 8; k++) v += x[k] * Wef[k * 8 + j];
            eF[j] = elu1(v);
        }
        int tF = rp[2 * NI + d] - 2 * NE + atomicAdd(&fill[2 * NI + d], 1);
        colF[tF] = s;
        ((float4*)eFbuf)[(size_t)tF * 2]     = make_float4(eF[0], eF[1], eF[2], eF[3]);
        ((float4*)eFbuf)[(size_t)tF * 2 + 1] = make_float4(eF[4], eF[5], eF[6], eF[7]);
    }
}

// ---------------- edge-embed aggregation: sequential run-sum per node ----------------
__global__ __launch_bounds__(256) void k_eagg2(const int* __restrict__ rp,
                                               const float* __restrict__ ePbuf,
                                               const float* __restrict__ eSbuf,
                                               const float* __restrict__ eFbuf,
                                               float* __restrict__ aggEp,
                                               float* __restrict__ aggEs,
                                               float* __restrict__ aggEf) {
    int idx = blockIdx.x * blockDim.x + threadIdx.x;
    if (idx >= NT) return;
    const float* buf; float* out; int s, e;
    if (idx < NF) {
        int n = idx;
        s = rp[2 * NI + n] - 2 * NE; e = rp[2 * NI + n + 1] - 2 * NE;
        buf = eFbuf; out = aggEf + (size_t)n * 8;
    } else if (idx < NF + NI) {
        int n = idx - NF;
        s = rp[n]; e = rp[n + 1];
        buf = ePbuf; out = aggEp + (size_t)n * 8;
    } else {
        int n = idx - NF - NI;
        s = rp[NI + n] - NE; e = rp[NI + n + 1] - NE;
        buf = eSbuf; out = aggEs + (size_t)n * 8;
    }
    float a0 = 0.f, a1 = 0.f, a2 = 0.f, a3 = 0.f, a4 = 0.f, a5 = 0.f, a6 = 0.f, a7 = 0.f;
    for (int t = s; t < e; ++t) {
        float4 v0 = ((const float4*)buf)[(size_t)t * 2];
        float4 v1 = ((const float4*)buf)[(size_t)t * 2 + 1];
        a0 += v0.x; a1 += v0.y; a2 += v0.z; a3 += v0.w;
        a4 += v1.x; a5 += v1.y; a6 += v1.z; a7 += v1.w;
    }
    ((float4*)out)[0] = make_float4(a0, a1, a2, a3);
    ((float4*)out)[1] = make_float4(a4, a5, a6, a7);
}

// ---------------- prep X: layer-invariant me-columns + zero pad ----------------
__global__ __launch_bounds__(256) void k_prep_x(const int* __restrict__ rpAll,
                                                const float* __restrict__ aggEp,
                                                const float* __restrict__ aggEs,
                                                unsigned short* __restrict__ X) {
    int i = blockIdx.x * blockDim.x + threadIdx.x;
    if (i >= NI) return;
    int cP = rpAll[i + 1] - rpAll[i];
    int cS = rpAll[NI + i + 1] - rpAll[NI + i];
    float invP = 1.f / (float)max(cP, 1);
    float invS = 1.f / (float)max(cS, 1);
    unsigned short* xr = X + (size_t)i * KX;
#pragma unroll
    for (int c = 0; c < 2; c++) {
        float4 ep = ((const float4*)(aggEp + (size_t)i * 8))[c];
        float4 es = ((const float4*)(aggEs + (size_t)i * 8))[c];
        ushort4 up; up.x = f2bf(ep.x * invP); up.y = f2bf(ep.y * invP);
                    up.z = f2bf(ep.z * invP); up.w = f2bf(ep.w * invP);
        ushort4 us; us.x = f2bf(es.x * invS); us.y = f2bf(es.y * invS);
                    us.z = f2bf(es.z * invS); us.w = f2bf(es.w * invS);
        ((ushort4*)(xr + 64))[c]  = up;
        ((ushort4*)(xr + 136))[c] = us;
    }
    ushort4 z; z.x = z.y = z.z = z.w = 0;
#pragma unroll
    for (int c = 0; c < 4; c++) ((ushort4*)(xr + 144))[c] = z;
}

// ---------------- node embedding (wave per node, lane = output feature) ----------------
__global__ __launch_bounds__(256) void k_node_embed(const float* __restrict__ xi,
                                                    const float* __restrict__ xf,
                                                    const float* __restrict__ Wit, const float* __restrict__ bit,
                                                    const float* __restrict__ Wft, const float* __restrict__ bft,
                                                    float* __restrict__ inst, unsigned short* __restrict__ inst_bf,
                                                    float* __restrict__ fin) {
    const int NPW = 16;
    int lane = threadIdx.x & 63;
    int wave = (blockIdx.x * blockDim.x + threadIdx.x) >> 6;
    int base = wave * NPW;
    float wi[DN], wf[DN];
#pragma unroll
    for (int k = 0; k < DN; k++) { wi[k] = Wit[k * 64 + lane]; wf[k] = Wft[k * 64 + lane]; }
    float bi = bit[lane], bf = bft[lane];
    for (int n = 0; n < NPW; n++) {
        int i = base + n;
        if (i < NI) {
            const float* x = xi + (size_t)i * DN;
            float acc = bi;
#pragma unroll
            for (int k = 0; k < DN; k++) acc += x[k] * wi[k];
            float v = elu1(acc);
            inst[(size_t)i * 64 + lane] = v;
            inst_bf[(size_t)i * 64 + lane] = f2bf(v);
        } else if (i < NI + NF) {
            int f = i - NI;
            const float* x = xf + (size_t)f * DN;
            float acc = bf;
#pragma unroll
            for (int k = 0; k < DN; k++) acc += x[k] * wf[k];
            fin[(size_t)f * 64 + lane] = elu1(acc);
        }
    }
}

// ---------------- SpMM (gather-mean over bf16 rows), 4 tasks per wave ----------------
// lane = (node-slot n2 = lane>>4, feature-quad fq = lane&15). Each 16-lane slot
// owns one node-direction task; each lane loads ushort4 (8B) of its task's edge
// row -> one vmem instruction gathers 4 rows x 128B. Per-feature accumulation is
// a single fp32 chain over edges in CSR order — bit-identical to the verified
// round-4 spmm. No cross-lane ops at all.
__global__ __launch_bounds__(256) void k_spmm(const unsigned short* __restrict__ inst_bf,
                                              const int* __restrict__ rp,
                                              const int* __restrict__ colP,
                                              const int* __restrict__ colS,
                                              const int* __restrict__ colF,
                                              unsigned short* __restrict__ X,
                                              float* __restrict__ aggHf) {
    int lane = threadIdx.x & 63;
    int wv = (blockIdx.x * blockDim.x + threadIdx.x) >> 6;
    int n2 = lane >> 4;       // task slot 0..3
    int fq = lane & 15;       // feature quad
    int task = wv * 4 + n2;
    if (task >= NT) return;   // per-lane exit; no cross-lane ops below

    const int* col; int i, rbase, ebase, xoff;
    if (task < NI)            { i = task;          rbase = 0;      ebase = 0;      col = colP; xoff = 0;  }
    else if (task < 2 * NI)   { i = task - NI;     rbase = NI;     ebase = NE;     col = colS; xoff = 72; }
    else                      { i = task - 2 * NI; rbase = 2 * NI; ebase = 2 * NE; col = colF; xoff = -1; }

    int s = rp[rbase + i] - ebase, e1 = rp[rbase + i + 1] - ebase;
    const unsigned short* src = inst_bf + fq * 4;
    float4 acc = make_float4(0.f, 0.f, 0.f, 0.f);

    int pos = s;
    for (; pos + 4 <= e1; pos += 4) {            // 4 independent gathers in flight
        int c0 = col[pos], c1 = col[pos + 1], c2 = col[pos + 2], c3 = col[pos + 3];
        ushort4 v0 = *(const ushort4*)(src + (size_t)c0 * 64);
        ushort4 v1 = *(const ushort4*)(src + (size_t)c1 * 64);
        ushort4 v2 = *(const ushort4*)(src + (size_t)c2 * 64);
        ushort4 v3 = *(const ushort4*)(src + (size_t)c3 * 64);
        acc.x += bf2f(v0.x); acc.y += bf2f(v0.y); acc.z += bf2f(v0.z); acc.w += bf2f(v0.w);
        acc.x += bf2f(v1.x); acc.y += bf2f(v1.y); acc.z += bf2f(v1.z); acc.w += bf2f(v1.w);
        acc.x += bf2f(v2.x); acc.y += bf2f(v2.y); acc.z += bf2f(v2.z); acc.w += bf2f(v2.w);
        acc.x += bf2f(v3.x); acc.y += bf2f(v3.y); acc.z += bf2f(v3.z); acc.w += bf2f(v3.w);
    }
    for (; pos < e1; ++pos) {                    // tail, order preserved
        int c = col[pos];
        ushort4 v = *(const ushort4*)(src + (size_t)c * 64);
        acc.x += bf2f(v.x); acc.y += bf2f(v.y); acc.z += bf2f(v.z); acc.w += bf2f(v.w);
    }

    int cnt = e1 - s;
    float inv = cnt > 0 ? 1.f / (float)cnt : 0.f;
    if (xoff >= 0) {
        ushort4 o;
        o.x = f2bf(acc.x * inv); o.y = f2bf(acc.y * inv);
        o.z = f2bf(acc.z * inv); o.w = f2bf(acc.w * inv);
        *(ushort4*)(X + (size_t)i * KX + xoff + fq * 4) = o;
    } else {
        *(float4*)(aggHf + (size_t)i * 64 + fq * 4) =
            make_float4(acc.x * inv, acc.y * inv, acc.z * inv, acc.w * inv);
    }
}

// ---------------- dense layer update for instruction nodes: bf16 MFMA GEMM ----------------
__global__ __launch_bounds__(256) void k_dense_mfma(
    const unsigned short* __restrict__ X,
    float* __restrict__ inst, unsigned short* __restrict__ inst_bf,
    const int* __restrict__ rpAll,
    const float* __restrict__ Wp, const float* __restrict__ bp,
    const float* __restrict__ Ws, const float* __restrict__ bs) {
    __shared__ __align__(16) unsigned short Wt[64][168];  // [n][k] transposed 0.5*Wcat, +8 pad
    int t = threadIdx.x;
    for (int idx = t; idx < 64 * 168; idx += 256) {
        int n = idx / 168, k = idx % 168;
        float v = 0.f;
        if (k < 72)       v = 0.5f * Wp[k * 64 + n];
        else if (k < 144) v = 0.5f * Ws[(k - 72) * 64 + n];
        Wt[n][k] = f2bf(v);
    }
    __syncthreads();

    int wave = t >> 6, lane = t & 63;
    int rowbase = blockIdx.x * 128 + wave * 32;   // this wave's 32 rows
    int lrow = lane & 15, lk = (lane >> 4) * 8;

    f32x4 acc[2][4];
#pragma unroll
    for (int rb = 0; rb < 2; rb++)
#pragma unroll
        for (int nb = 0; nb < 4; nb++) acc[rb][nb] = (f32x4){0.f, 0.f, 0.f, 0.f};

#pragma unroll
    for (int kc = 0; kc < 5; kc++) {
        int k0 = kc * 32 + lk;
        bf16x8 a[2], b[4];
#pragma unroll
        for (int rb = 0; rb < 2; rb++) {
            int r = min(rowbase + rb * 16 + lrow, NI - 1);
            a[rb] = *(const bf16x8*)(X + (size_t)r * KX + k0);
        }
#pragma unroll
        for (int nb = 0; nb < 4; nb++)
            b[nb] = *(const bf16x8*)(&Wt[nb * 16 + lrow][k0]);
#pragma unroll
        for (int rb = 0; rb < 2; rb++)
#pragma unroll
            for (int nb = 0; nb < 4; nb++)
                acc[rb][nb] = __builtin_amdgcn_mfma_f32_16x16x32_bf16(a[rb], b[nb], acc[rb][nb], 0, 0, 0);
    }

    // epilogue: C[row= (lane>>4)*4+j, col= nb*16 + (lane&15)]
#pragma unroll
    for (int rb = 0; rb < 2; rb++) {
#pragma unroll
        for (int j = 0; j < 4; j++) {
            int node = rowbase + rb * 16 + (lane >> 4) * 4 + j;
            bool v = node < NI;
            int nn = v ? node : NI - 1;
            float mP = (v && (rpAll[nn + 1] > rpAll[nn])) ? 0.5f : 0.f;
            float mS = (v && (rpAll[NI + nn + 1] > rpAll[NI + nn])) ? 0.5f : 0.f;
#pragma unroll
            for (int nb = 0; nb < 4; nb++) {
                int col = nb * 16 + lrow;
                float x = inst[(size_t)nn * 64 + col] + acc[rb][nb][j] + mP * bp[col] + mS * bs[col];
                x = elu1(x);
                if (v) {
                    inst[(size_t)nn * 64 + col] = x;
                    inst_bf[(size_t)nn * 64 + col] = f2bf(x);
                }
            }
        }
    }
}

// ---------------- dense layer update for final nodes (fp32 vector, tiny) ----------------
__global__ __launch_bounds__(64, 1) void k_dense_fin(
    float* __restrict__ fin,
    const float* __restrict__ aggHf, const float* __restrict__ aggEf,
    const int* __restrict__ rpF,
    const float* __restrict__ Wf, const float* __restrict__ bf) {
    __shared__ float hL[64 * 65];
    const int lane = threadIdx.x;
    const int base = blockIdx.x * 64;
    const int i = base + lane;
    const bool valid = i < NF;
    const int ii = valid ? i : (NF - 1);

    int cF = rpF[ii + 1] - rpF[ii];
    float mF = (valid && cF > 0) ? 1.f : 0.f;
    float invF = 1.f / (float)max(cF, 1);
    float meF[8];
#pragma unroll
    for (int k = 0; k < 8; k++) meF[k] = aggEf[(size_t)ii * 8 + k] * invF;

    float acc[64];
#pragma unroll
    for (int j = 0; j < 64; j++) acc[j] = bf[j];

    for (int idx = lane; idx < 1024; idx += 64) {
        int n = idx >> 4, k4 = idx & 15;
        float4 v = ((const float4*)aggHf)[(size_t)min(base + n, NF - 1) * 16 + k4];
        float* d = &hL[n * 65 + k4 * 4];
        d[0] = v.x; d[1] = v.y; d[2] = v.z; d[3] = v.w;
    }
    __syncthreads();
#pragma unroll 4
    for (int k = 0; k < 64; k++) {
        float h = hL[lane * 65 + k];
#pragma unroll
        for (int j = 0; j < 64; j++) acc[j] += h * Wf[k * 64 + j];
    }
#pragma unroll
    for (int k = 0; k < 8; k++) {
#pragma unroll
        for (int j = 0; j < 64; j++) acc[j] += meF[k] * Wf[(64 + k) * 64 + j];
    }
    __syncthreads();

    for (int idx = lane; idx < 1024; idx += 64) {
        int n = idx >> 4, k4 = idx & 15;
        float4 v = ((const float4*)fin)[(size_t)min(base + n, NF - 1) * 16 + k4];
        float* d = &hL[n * 65 + k4 * 4];
        d[0] = v.x; d[1] = v.y; d[2] = v.z; d[3] = v.w;
    }
    __syncthreads();
#pragma unroll
    for (int j = 0; j < 64; j++) {
        float x = hL[lane * 65 + j] + mF * acc[j];
        hL[lane * 65 + j] = elu1(x);
    }
    __syncthreads();
    for (int idx = lane; idx < 1024; idx += 64) {
        int n = idx >> 4, k4 = idx & 15;
        if (base + n < NF) {
            const float* sp = &hL[n * 65 + k4 * 4];
            ((float4*)fin)[(size_t)(base + n) * 16 + k4] = make_float4(sp[0], sp[1], sp[2], sp[3]);
        }
    }
}

// ---------------- readout head ----------------
__global__ __launch_bounds__(64, 1) void k_head(
    const float* __restrict__ fin,
    const float* __restrict__ Wr1, const float* __restrict__ br1,
    const float* __restrict__ Wr2, const float* __restrict__ br2,
    const float* __restrict__ Wr3, const float* __restrict__ br3,
    float* __restrict__ out) {
    __shared__ float hL[64 * 65];
    const int lane = threadIdx.x;
    const int base = blockIdx.x * 64;

    for (int idx = lane; idx < 1024; idx += 64) {
        int n = idx >> 4, k4 = idx & 15;
        float4 v = ((const float4*)fin)[(size_t)min(base + n, NF - 1) * 16 + k4];
        float* d = &hL[n * 65 + k4 * 4];
        d[0] = v.x; d[1] = v.y; d[2] = v.z; d[3] = v.w;
    }
    __syncthreads();

    float acc[64];
#pragma unroll
    for (int j = 0; j < 64; j++) acc[j] = br1[j];
#pragma unroll 4
    for (int k = 0; k < 64; k++) {
        float h = hL[lane * 65 + k];
#pragma unroll
        for (int j = 0; j < 64; j++) acc[j] += h * Wr1[k * 64 + j];
    }
#pragma unroll
    for (int j = 0; j < 64; j++) hL[lane * 65 + j] = elu1(acc[j]);

#pragma unroll
    for (int j = 0; j < 64; j++) acc[j] = br2[j];
#pragma unroll 4
    for (int k = 0; k < 64; k++) {
        float h = hL[lane * 65 + k];
#pragma unroll
        for (int j = 0; j < 64; j++) acc[j] += h * Wr2[k * 64 + j];
    }
    float r = br3[0];
#pragma unroll
    for (int j = 0; j < 64; j++) r += elu1(acc[j]) * Wr3[j];

    int i = base + lane;
    if (i < NF) out[i] = r;
}

extern "C" void kernel_launch(void* const* d_in, const int* in_sizes, int n_in,
                              void* d_out, int out_size, void* d_ws, size_t ws_size,
                              hipStream_t stream) {
    const float* xi  = (const float*)d_in[0];
    const float* xf  = (const float*)d_in[1];
    const float* xe  = (const float*)d_in[2];
    const float* xef = (const float*)d_in[3];
    const int* prev_src = (const int*)d_in[4];
    const int* prev_dst = (const int*)d_in[5];
    const int* tf_src = (const int*)d_in[6];
    const int* tf_dst = (const int*)d_in[7];
    const float* W_it = (const float*)d_in[8];  const float* b_it = (const float*)d_in[9];
    const float* W_ft = (const float*)d_in[10]; const float* b_ft = (const float*)d_in[11];
    const float* W_ep = (const float*)d_in[12]; const float* b_ep = (const float*)d_in[13];
    const float* W_es = (const float*)d_in[14]; const float* b_es = (const float*)d_in[15];
    const float* W_ef = (const float*)d_in[16]; const float* b_ef = (const float*)d_in[17];
    const float* Wg_prev = (const float*)d_in[18]; const float* bg_prev = (const float*)d_in[19];
    const float* Wg_succ = (const float*)d_in[20]; const float* bg_succ = (const float*)d_in[21];
    const float* Wg_tf   = (const float*)d_in[22]; const float* bg_tf   = (const float*)d_in[23];
    const float* Wr1 = (const float*)d_in[24]; const float* br1 = (const float*)d_in[25];
    const float* Wr2 = (const float*)d_in[26]; const float* br2 = (const float*)d_in[27];
    const float* Wr3 = (const float*)d_in[28]; const float* br3 = (const float*)d_in[29];

    char* ws = (char*)d_ws;
    size_t off = 0;
    auto alloc = [&](size_t bytes) -> char* {
        char* p = ws + off;
        off += (bytes + 255) & ~(size_t)255;
        return p;
    };
    float* inst  = (float*)alloc((size_t)NI * 64 * 4);
    unsigned short* inst_bf = (unsigned short*)alloc((size_t)NI * 64 * 2);
    unsigned short* X = (unsigned short*)alloc((size_t)NI * KX * 2);
    float* fin   = (float*)alloc((size_t)NF * 64 * 4);
    float* aggHf = (float*)alloc((size_t)NF * 64 * 4);
    float* aggEp = (float*)alloc((size_t)NI * 8 * 4);
    float* aggEs = (float*)alloc((size_t)NI * 8 * 4);
    float* aggEf = (float*)alloc((size_t)NF * 8 * 4);
    char* zero_begin = ws + off;
    int* cnt  = (int*)alloc((size_t)NT * 4);
    int* fill = (int*)alloc((size_t)NT * 4);
    char* zero_end = ws + off;
    int* rpAll = (int*)alloc((size_t)(NT + 1) * 4);
    int* colP = (int*)alloc((size_t)NE * 4);
    int* colS = (int*)alloc((size_t)NE * 4);
    int* colF = (int*)alloc((size_t)NEF * 4);
    int* bsum = (int*)alloc(1024 * 4);
    (void)ws_size; (void)in_sizes; (void)n_in; (void)out_size;

    // scatter-stage fp32 edge-embed buffers alias regions dead until after k_eagg2:
    //   ePbuf (NE*32B = 25.6MB)  -> X (32MB, live cols written by k_prep_x/spmm later)
    //   eSbuf (NE*32B = 25.6MB)  -> inst (25.6MB, first written by k_node_embed)
    //   eFbuf (NEF*32B = 6.4MB)  -> inst_bf (12.8MB, first written by k_node_embed)
    float* ePbuf = (float*)X;
    float* eSbuf = inst;
    float* eFbuf = (float*)inst_bf;

    hipMemsetAsync(zero_begin, 0, (size_t)(zero_end - zero_begin), stream);

    k_count<<<(NE + 255) / 256, 256, 0, stream>>>(prev_src, prev_dst, tf_dst, cnt);

    int nb = (NT + 255) / 256;
    k_scan1<<<nb, 256, 0, stream>>>(cnt, NT, rpAll, bsum);
    k_scan2<<<1, 1024, 0, stream>>>(bsum, nb);
    k_scan3<<<nb, 256, 0, stream>>>(rpAll, bsum, NT);

    k_scatter<<<(NE + 255) / 256, 256, 0, stream>>>(prev_src, prev_dst, tf_src, tf_dst,
                                                    xe, xef, rpAll, fill,
                                                    colP, colS, colF,
                                                    ePbuf, eSbuf, eFbuf,
                                                    W_ep, b_ep, W_es, b_es, W_ef, b_ef);

    k_eagg2<<<(NT + 255) / 256, 256, 0, stream>>>(rpAll, ePbuf, eSbuf, eFbuf,
                                                  aggEp, aggEs, aggEf);

    k_prep_x<<<(NI + 255) / 256, 256, 0, stream>>>(rpAll, aggEp, aggEs, X);

    {
        int waves = (NI + NF + 15) / 16;
        int blocks = (waves + 3) / 4;
        k_node_embed<<<blocks, 256, 0, stream>>>(xi, xf, W_it, b_it, W_ft, b_ft,
                                                 inst, inst_bf, fin);
    }

    for (int l = 0; l < NL; l++) {
        // 4 tasks per wave, 16 tasks per 256-thread block
        k_spmm<<<(NT + 15) / 16, 256, 0, stream>>>(inst_bf, rpAll,
                                                   colP, colS, colF,
                                                   X, aggHf);
        k_dense_mfma<<<(NI + 127) / 128, 256, 0, stream>>>(X, inst, inst_bf, rpAll,
                                                           Wg_prev + (size_t)l * 72 * 64, bg_prev + (size_t)l * 64,
                                                           Wg_succ + (size_t)l * 72 * 64, bg_succ + (size_t)l * 64);
        k_dense_fin<<<(NF + 63) / 64, 64, 0, stream>>>(fin, aggHf, aggEf, rpAll + 2 * NI,
                                                       Wg_tf + (size_t)l * 72 * 64, bg_tf + (size_t)l * 64);
    }

    k_head<<<(NF + 63) / 64, 64, 0, stream>>>(fin, Wr1, br1, Wr2, br2, Wr3, br3, (float*)d_out);
}

// Round 9
// 1247.605 us; speedup vs baseline: 3.3306x; 1.6268x over previous
//
#include <hip/hip_runtime.h>
#include <math.h>

#define NI 100000
#define NF 2000
#define NE 800000
#define NEF 200000
#define DN 16
#define NL 11
#define NT (2 * NI + NF)   // concatenated node-direction count: P | S | F
#define KX 160             // padded K stride of X (bf16): 64 P | 8 meP | 64 S | 8 meS | 16 zero
#define NBI 782            // inst GEMM blocks: ceil(NI/128)
#define NBF 125            // fin blocks: NF*16/256

typedef short bf16x8 __attribute__((ext_vector_type(8)));
typedef float f32x4 __attribute__((ext_vector_type(4)));

__device__ __forceinline__ float elu1(float x) { return x > 0.f ? x : expm1f(x); }

__device__ __forceinline__ unsigned short f2bf(float f) {
    unsigned x = __float_as_uint(f);
    return (unsigned short)((x + 0x7fffu + ((x >> 16) & 1u)) >> 16);
}
__device__ __forceinline__ float bf2f(unsigned short u) {
    return __uint_as_float(((unsigned)u) << 16);
}

// ---------------- CSR build (concatenated P|S|F degree array) ----------------
__global__ __launch_bounds__(256) void k_count(const int* __restrict__ prev_src,
                                               const int* __restrict__ prev_dst,
                                               const int* __restrict__ tf_dst,
                                               int* cnt) {
    int i = blockIdx.x * blockDim.x + threadIdx.x;
    if (i < NE) {
        atomicAdd(&cnt[prev_dst[i]], 1);
        atomicAdd(&cnt[NI + prev_src[i]], 1);
    }
    if (i < NEF) atomicAdd(&cnt[2 * NI + tf_dst[i]], 1);
}

__global__ __launch_bounds__(256) void k_scan1(const int* __restrict__ cnt, int n,
                                               int* __restrict__ rp, int* __restrict__ bsum) {
    __shared__ int s[256];
    int t = threadIdx.x, b = blockIdx.x, i = b * 256 + t;
    int v = (i < n) ? cnt[i] : 0;
    s[t] = v; __syncthreads();
    for (int o = 1; o < 256; o <<= 1) {
        int x = (t >= o) ? s[t - o] : 0;
        __syncthreads();
        s[t] += x;
        __syncthreads();
    }
    if (i < n) rp[i + 1] = s[t];
    if (t == 255) bsum[b] = s[255];
}

__global__ __launch_bounds__(1024) void k_scan2(int* __restrict__ bsum, int nb) {
    __shared__ int s[1024];
    int t = threadIdx.x;
    int v = (t < nb) ? bsum[t] : 0;
    s[t] = v; __syncthreads();
    for (int o = 1; o < 1024; o <<= 1) {
        int x = (t >= o) ? s[t - o] : 0;
        __syncthreads();
        s[t] += x;
        __syncthreads();
    }
    if (t < nb) bsum[t] = s[t] - v;   // exclusive block offsets
}

__global__ __launch_bounds__(256) void k_scan3(int* __restrict__ rp, const int* __restrict__ bsum, int n) {
    int i = blockIdx.x * blockDim.x + threadIdx.x;
    if (i < n) rp[i + 1] += bsum[i >> 8];
    if (i == 0) rp[0] = 0;
}

// ---------------- scatter: CSR cols + fused edge-embed (fp32) in CSR slot order ----
__global__ __launch_bounds__(256) void k_scatter(const int* __restrict__ prev_src,
                                                 const int* __restrict__ prev_dst,
                                                 const int* __restrict__ tf_src,
                                                 const int* __restrict__ tf_dst,
                                                 const float* __restrict__ xe,
                                                 const float* __restrict__ xef,
                                                 const int* __restrict__ rp,
                                                 int* fill,
                                                 int* colP, int* colS, int* colF,
                                                 float* __restrict__ ePbuf,
                                                 float* __restrict__ eSbuf,
                                                 float* __restrict__ eFbuf,
                                                 const float* __restrict__ Wep, const float* __restrict__ bep,
                                                 const float* __restrict__ Wes, const float* __restrict__ bes,
                                                 const float* __restrict__ Wef, const float* __restrict__ bef) {
    int i = blockIdx.x * blockDim.x + threadIdx.x;
    if (i < NE) {
        int s = prev_src[i], d = prev_dst[i];
        float4 x0 = ((const float4*)xe)[(size_t)i * 2];
        float4 x1 = ((const float4*)xe)[(size_t)i * 2 + 1];
        float x[8] = {x0.x, x0.y, x0.z, x0.w, x1.x, x1.y, x1.z, x1.w};
        float eP[8], eS[8];
#pragma unroll
        for (int j = 0; j < 8; j++) {
            float vp = bep[j], vs = bes[j];
#pragma unroll
            for (int k = 0; k < 8; k++) { vp += x[k] * Wep[k * 8 + j]; vs += x[k] * Wes[k * 8 + j]; }
            eP[j] = elu1(vp); eS[j] = elu1(vs);
        }
        int tP = rp[d] + atomicAdd(&fill[d], 1);
        colP[tP] = s;
        ((float4*)ePbuf)[(size_t)tP * 2]     = make_float4(eP[0], eP[1], eP[2], eP[3]);
        ((float4*)ePbuf)[(size_t)tP * 2 + 1] = make_float4(eP[4], eP[5], eP[6], eP[7]);
        int tS = rp[NI + s] - NE + atomicAdd(&fill[NI + s], 1);
        colS[tS] = d;
        ((float4*)eSbuf)[(size_t)tS * 2]     = make_float4(eS[0], eS[1], eS[2], eS[3]);
        ((float4*)eSbuf)[(size_t)tS * 2 + 1] = make_float4(eS[4], eS[5], eS[6], eS[7]);
    }
    if (i < NEF) {
        int s = tf_src[i], d = tf_dst[i];
        float4 x0 = ((const float4*)xef)[(size_t)i * 2];
        float4 x1 = ((const float4*)xef)[(size_t)i * 2 + 1];
        float x[8] = {x0.x, x0.y, x0.z, x0.w, x1.x, x1.y, x1.z, x1.w};
        float eF[8];
#pragma unroll
        for (int j = 0; j < 8; j++) {
            float v = bef[j];
#pragma unroll
            for (int k = 0; k < 8; k++) v += x[k] * Wef[k * 8 + j];
            eF[j] = elu1(v);
        }
        int tF = rp[2 * NI + d] - 2 * NE + atomicAdd(&fill[2 * NI + d], 1);
        colF[tF] = s;
        ((float4*)eFbuf)[(size_t)tF * 2]     = make_float4(eF[0], eF[1], eF[2], eF[3]);
        ((float4*)eFbuf)[(size_t)tF * 2 + 1] = make_float4(eF[4], eF[5], eF[6], eF[7]);
    }
}

// ---------------- edge-embed aggregation: sequential run-sum per node ----------------
__global__ __launch_bounds__(256) void k_eagg2(const int* __restrict__ rp,
                                               const float* __restrict__ ePbuf,
                                               const float* __restrict__ eSbuf,
                                               const float* __restrict__ eFbuf,
                                               float* __restrict__ aggEp,
                                               float* __restrict__ aggEs,
                                               float* __restrict__ aggEf) {
    int idx = blockIdx.x * blockDim.x + threadIdx.x;
    if (idx >= NT) return;
    const float* buf; float* out; int s, e;
    if (idx < NF) {
        int n = idx;
        s = rp[2 * NI + n] - 2 * NE; e = rp[2 * NI + n + 1] - 2 * NE;
        buf = eFbuf; out = aggEf + (size_t)n * 8;
    } else if (idx < NF + NI) {
        int n = idx - NF;
        s = rp[n]; e = rp[n + 1];
        buf = ePbuf; out = aggEp + (size_t)n * 8;
    } else {
        int n = idx - NF - NI;
        s = rp[NI + n] - NE; e = rp[NI + n + 1] - NE;
        buf = eSbuf; out = aggEs + (size_t)n * 8;
    }
    float a0 = 0.f, a1 = 0.f, a2 = 0.f, a3 = 0.f, a4 = 0.f, a5 = 0.f, a6 = 0.f, a7 = 0.f;
    for (int t = s; t < e; ++t) {
        float4 v0 = ((const float4*)buf)[(size_t)t * 2];
        float4 v1 = ((const float4*)buf)[(size_t)t * 2 + 1];
        a0 += v0.x; a1 += v0.y; a2 += v0.z; a3 += v0.w;
        a4 += v1.x; a5 += v1.y; a6 += v1.z; a7 += v1.w;
    }
    ((float4*)out)[0] = make_float4(a0, a1, a2, a3);
    ((float4*)out)[1] = make_float4(a4, a5, a6, a7);
}

// ---------------- prep X: layer-invariant me-columns + zero pad ----------------
__global__ __launch_bounds__(256) void k_prep_x(const int* __restrict__ rpAll,
                                                const float* __restrict__ aggEp,
                                                const float* __restrict__ aggEs,
                                                unsigned short* __restrict__ X) {
    int i = blockIdx.x * blockDim.x + threadIdx.x;
    if (i >= NI) return;
    int cP = rpAll[i + 1] - rpAll[i];
    int cS = rpAll[NI + i + 1] - rpAll[NI + i];
    float invP = 1.f / (float)max(cP, 1);
    float invS = 1.f / (float)max(cS, 1);
    unsigned short* xr = X + (size_t)i * KX;
#pragma unroll
    for (int c = 0; c < 2; c++) {
        float4 ep = ((const float4*)(aggEp + (size_t)i * 8))[c];
        float4 es = ((const float4*)(aggEs + (size_t)i * 8))[c];
        ushort4 up; up.x = f2bf(ep.x * invP); up.y = f2bf(ep.y * invP);
                    up.z = f2bf(ep.z * invP); up.w = f2bf(ep.w * invP);
        ushort4 us; us.x = f2bf(es.x * invS); us.y = f2bf(es.y * invS);
                    us.z = f2bf(es.z * invS); us.w = f2bf(es.w * invS);
        ((ushort4*)(xr + 64))[c]  = up;
        ((ushort4*)(xr + 136))[c] = us;
    }
    ushort4 z; z.x = z.y = z.z = z.w = 0;
#pragma unroll
    for (int c = 0; c < 4; c++) ((ushort4*)(xr + 144))[c] = z;
}

// ---------------- node embedding (wave per node, lane = output feature) ----------------
__global__ __launch_bounds__(256) void k_node_embed(const float* __restrict__ xi,
                                                    const float* __restrict__ xf,
                                                    const float* __restrict__ Wit, const float* __restrict__ bit,
                                                    const float* __restrict__ Wft, const float* __restrict__ bft,
                                                    float* __restrict__ inst, unsigned short* __restrict__ inst_bf,
                                                    float* __restrict__ fin) {
    const int NPW = 16;
    int lane = threadIdx.x & 63;
    int wave = (blockIdx.x * blockDim.x + threadIdx.x) >> 6;
    int base = wave * NPW;
    float wi[DN], wf[DN];
#pragma unroll
    for (int k = 0; k < DN; k++) { wi[k] = Wit[k * 64 + lane]; wf[k] = Wft[k * 64 + lane]; }
    float bi = bit[lane], bf = bft[lane];
    for (int n = 0; n < NPW; n++) {
        int i = base + n;
        if (i < NI) {
            const float* x = xi + (size_t)i * DN;
            float acc = bi;
#pragma unroll
            for (int k = 0; k < DN; k++) acc += x[k] * wi[k];
            float v = elu1(acc);
            inst[(size_t)i * 64 + lane] = v;
            inst_bf[(size_t)i * 64 + lane] = f2bf(v);
        } else if (i < NI + NF) {
            int f = i - NI;
            const float* x = xf + (size_t)f * DN;
            float acc = bf;
#pragma unroll
            for (int k = 0; k < DN; k++) acc += x[k] * wf[k];
            fin[(size_t)f * 64 + lane] = elu1(acc);
        }
    }
}

// ---------------- SpMM (gather-mean over bf16 rows), 4 tasks per wave ----------------
// lane = (task-slot n2 = lane>>4, feature-quad fq = lane&15). F tasks (high degree)
// mapped FIRST so long runs start early (tail reduction). Per-feature accumulation
// is a single fp32 chain in CSR order — bit-identical to the round-4-verified spmm.
__global__ __launch_bounds__(256) void k_spmm(const unsigned short* __restrict__ inst_bf,
                                              const int* __restrict__ rp,
                                              const int* __restrict__ colP,
                                              const int* __restrict__ colS,
                                              const int* __restrict__ colF,
                                              unsigned short* __restrict__ X,
                                              float* __restrict__ aggHf) {
    int lane = threadIdx.x & 63;
    int wv = (blockIdx.x * blockDim.x + threadIdx.x) >> 6;
    int n2 = lane >> 4;       // task slot 0..3
    int fq = lane & 15;       // feature quad
    int task = wv * 4 + n2;
    if (task >= NT) return;   // per-lane exit; no cross-lane ops below

    const int* col; int i, rbase, ebase, xoff;
    if (task < NF)            { i = task;           rbase = 2 * NI; ebase = 2 * NE; col = colF; xoff = -1; }
    else if (task < NF + NI)  { i = task - NF;      rbase = 0;      ebase = 0;      col = colP; xoff = 0;  }
    else                      { i = task - NF - NI; rbase = NI;     ebase = NE;     col = colS; xoff = 72; }

    int s = rp[rbase + i] - ebase, e1 = rp[rbase + i + 1] - ebase;
    const unsigned short* src = inst_bf + fq * 4;
    float4 acc = make_float4(0.f, 0.f, 0.f, 0.f);

    int pos = s;
    for (; pos + 4 <= e1; pos += 4) {            // 4 independent gathers in flight
        int c0 = col[pos], c1 = col[pos + 1], c2 = col[pos + 2], c3 = col[pos + 3];
        ushort4 v0 = *(const ushort4*)(src + (size_t)c0 * 64);
        ushort4 v1 = *(const ushort4*)(src + (size_t)c1 * 64);
        ushort4 v2 = *(const ushort4*)(src + (size_t)c2 * 64);
        ushort4 v3 = *(const ushort4*)(src + (size_t)c3 * 64);
        acc.x += bf2f(v0.x); acc.y += bf2f(v0.y); acc.z += bf2f(v0.z); acc.w += bf2f(v0.w);
        acc.x += bf2f(v1.x); acc.y += bf2f(v1.y); acc.z += bf2f(v1.z); acc.w += bf2f(v1.w);
        acc.x += bf2f(v2.x); acc.y += bf2f(v2.y); acc.z += bf2f(v2.z); acc.w += bf2f(v2.w);
        acc.x += bf2f(v3.x); acc.y += bf2f(v3.y); acc.z += bf2f(v3.z); acc.w += bf2f(v3.w);
    }
    for (; pos < e1; ++pos) {                    // tail, order preserved
        int c = col[pos];
        ushort4 v = *(const ushort4*)(src + (size_t)c * 64);
        acc.x += bf2f(v.x); acc.y += bf2f(v.y); acc.z += bf2f(v.z); acc.w += bf2f(v.w);
    }

    int cnt = e1 - s;
    float inv = cnt > 0 ? 1.f / (float)cnt : 0.f;
    if (xoff >= 0) {
        ushort4 o;
        o.x = f2bf(acc.x * inv); o.y = f2bf(acc.y * inv);
        o.z = f2bf(acc.z * inv); o.w = f2bf(acc.w * inv);
        *(ushort4*)(X + (size_t)i * KX + xoff + fq * 4) = o;
    } else {
        *(float4*)(aggHf + (size_t)i * 64 + fq * 4) =
            make_float4(acc.x * inv, acc.y * inv, acc.z * inv, acc.w * inv);
    }
}

// ---------------- per-layer dense update: inst MFMA GEMM blocks + fin blocks ----------------
// blocks [0, NBI): X[NI][160] @ 0.5*[Wp;Ws] via bf16 MFMA, residual+elu epilogue.
// blocks [NBI, NBI+NBF): fin update, thread=(node, j-quad), fp32 math bit-identical
// to the old k_dense_fin (bias -> k=0..63 -> meF k=64..71 -> residual+elu).
__global__ __launch_bounds__(256) void k_dense_layer(
    const unsigned short* __restrict__ X,
    float* __restrict__ inst, unsigned short* __restrict__ inst_bf,
    const int* __restrict__ rpAll,
    const float* __restrict__ Wp, const float* __restrict__ bp,
    const float* __restrict__ Ws, const float* __restrict__ bs,
    float* __restrict__ fin,
    const float* __restrict__ aggHf, const float* __restrict__ aggEf,
    const float* __restrict__ Wf, const float* __restrict__ bf) {
    __shared__ __align__(16) unsigned short Wt[64][168];  // [n][k] transposed 0.5*Wcat, +8 pad
    int t = threadIdx.x;

    if (blockIdx.x < NBI) {
        // ---------- instruction-node GEMM path ----------
        for (int idx = t; idx < 64 * 168; idx += 256) {
            int n = idx / 168, k = idx % 168;
            float v = 0.f;
            if (k < 72)       v = 0.5f * Wp[k * 64 + n];
            else if (k < 144) v = 0.5f * Ws[(k - 72) * 64 + n];
            Wt[n][k] = f2bf(v);
        }
        __syncthreads();

        int wave = t >> 6, lane = t & 63;
        int rowbase = blockIdx.x * 128 + wave * 32;   // this wave's 32 rows
        int lrow = lane & 15, lk = (lane >> 4) * 8;

        f32x4 acc[2][4];
#pragma unroll
        for (int rb = 0; rb < 2; rb++)
#pragma unroll
            for (int nb = 0; nb < 4; nb++) acc[rb][nb] = (f32x4){0.f, 0.f, 0.f, 0.f};

#pragma unroll
        for (int kc = 0; kc < 5; kc++) {
            int k0 = kc * 32 + lk;
            bf16x8 a[2], b[4];
#pragma unroll
            for (int rb = 0; rb < 2; rb++) {
                int r = min(rowbase + rb * 16 + lrow, NI - 1);
                a[rb] = *(const bf16x8*)(X + (size_t)r * KX + k0);
            }
#pragma unroll
            for (int nb = 0; nb < 4; nb++)
                b[nb] = *(const bf16x8*)(&Wt[nb * 16 + lrow][k0]);
#pragma unroll
            for (int rb = 0; rb < 2; rb++)
#pragma unroll
                for (int nb = 0; nb < 4; nb++)
                    acc[rb][nb] = __builtin_amdgcn_mfma_f32_16x16x32_bf16(a[rb], b[nb], acc[rb][nb], 0, 0, 0);
        }

        // epilogue: C[row= (lane>>4)*4+j, col= nb*16 + (lane&15)]
#pragma unroll
        for (int rb = 0; rb < 2; rb++) {
#pragma unroll
            for (int j = 0; j < 4; j++) {
                int node = rowbase + rb * 16 + (lane >> 4) * 4 + j;
                bool v = node < NI;
                int nn = v ? node : NI - 1;
                float mP = (v && (rpAll[nn + 1] > rpAll[nn])) ? 0.5f : 0.f;
                float mS = (v && (rpAll[NI + nn + 1] > rpAll[NI + nn])) ? 0.5f : 0.f;
#pragma unroll
                for (int nb = 0; nb < 4; nb++) {
                    int col = nb * 16 + lrow;
                    float x = inst[(size_t)nn * 64 + col] + acc[rb][nb][j] + mP * bp[col] + mS * bs[col];
                    x = elu1(x);
                    if (v) {
                        inst[(size_t)nn * 64 + col] = x;
                        inst_bf[(size_t)nn * 64 + col] = f2bf(x);
                    }
                }
            }
        }
    } else {
        // ---------- final-node path: thread = (node, j-quad) ----------
        int tid = (blockIdx.x - NBI) * 256 + t;     // 0 .. 31999
        int n = tid >> 4;                           // node 0..1999
        int jq = tid & 15;                          // j-quad 0..15
        const int* rpF = rpAll + 2 * NI;
        int cF = rpF[n + 1] - rpF[n];
        float mF = (cF > 0) ? 1.f : 0.f;
        float invF = 1.f / (float)max(cF, 1);

        float acc0 = bf[jq * 4 + 0], acc1 = bf[jq * 4 + 1];
        float acc2 = bf[jq * 4 + 2], acc3 = bf[jq * 4 + 3];
        const float* hrow = aggHf + (size_t)n * 64;
        for (int k = 0; k < 64; k++) {
            float h = hrow[k];
            float4 w = *(const float4*)(Wf + (size_t)k * 64 + jq * 4);
            acc0 += h * w.x; acc1 += h * w.y; acc2 += h * w.z; acc3 += h * w.w;
        }
        const float* erow = aggEf + (size_t)n * 8;
#pragma unroll
        for (int k = 0; k < 8; k++) {
            float h = erow[k] * invF;
            float4 w = *(const float4*)(Wf + (size_t)(64 + k) * 64 + jq * 4);
            acc0 += h * w.x; acc1 += h * w.y; acc2 += h * w.z; acc3 += h * w.w;
        }
        float4 fv = *(const float4*)(fin + (size_t)n * 64 + jq * 4);
        float4 o;
        o.x = elu1(fv.x + mF * acc0);
        o.y = elu1(fv.y + mF * acc1);
        o.z = elu1(fv.z + mF * acc2);
        o.w = elu1(fv.w + mF * acc3);
        *(float4*)(fin + (size_t)n * 64 + jq * 4) = o;
    }
}

// ---------------- readout head ----------------
__global__ __launch_bounds__(64, 1) void k_head(
    const float* __restrict__ fin,
    const float* __restrict__ Wr1, const float* __restrict__ br1,
    const float* __restrict__ Wr2, const float* __restrict__ br2,
    const float* __restrict__ Wr3, const float* __restrict__ br3,
    float* __restrict__ out) {
    __shared__ float hL[64 * 65];
    const int lane = threadIdx.x;
    const int base = blockIdx.x * 64;

    for (int idx = lane; idx < 1024; idx += 64) {
        int n = idx >> 4, k4 = idx & 15;
        float4 v = ((const float4*)fin)[(size_t)min(base + n, NF - 1) * 16 + k4];
        float* d = &hL[n * 65 + k4 * 4];
        d[0] = v.x; d[1] = v.y; d[2] = v.z; d[3] = v.w;
    }
    __syncthreads();

    float acc[64];
#pragma unroll
    for (int j = 0; j < 64; j++) acc[j] = br1[j];
#pragma unroll 4
    for (int k = 0; k < 64; k++) {
        float h = hL[lane * 65 + k];
#pragma unroll
        for (int j = 0; j < 64; j++) acc[j] += h * Wr1[k * 64 + j];
    }
#pragma unroll
    for (int j = 0; j < 64; j++) hL[lane * 65 + j] = elu1(acc[j]);

#pragma unroll
    for (int j = 0; j < 64; j++) acc[j] = br2[j];
#pragma unroll 4
    for (int k = 0; k < 64; k++) {
        float h = hL[lane * 65 + k];
#pragma unroll
        for (int j = 0; j < 64; j++) acc[j] += h * Wr2[k * 64 + j];
    }
    float r = br3[0];
#pragma unroll
    for (int j = 0; j < 64; j++) r += elu1(acc[j]) * Wr3[j];

    int i = base + lane;
    if (i < NF) out[i] = r;
}

extern "C" void kernel_launch(void* const* d_in, const int* in_sizes, int n_in,
                              void* d_out, int out_size, void* d_ws, size_t ws_size,
                              hipStream_t stream) {
    const float* xi  = (const float*)d_in[0];
    const float* xf  = (const float*)d_in[1];
    const float* xe  = (const float*)d_in[2];
    const float* xef = (const float*)d_in[3];
    const int* prev_src = (const int*)d_in[4];
    const int* prev_dst = (const int*)d_in[5];
    const int* tf_src = (const int*)d_in[6];
    const int* tf_dst = (const int*)d_in[7];
    const float* W_it = (const float*)d_in[8];  const float* b_it = (const float*)d_in[9];
    const float* W_ft = (const float*)d_in[10]; const float* b_ft = (const float*)d_in[11];
    const float* W_ep = (const float*)d_in[12]; const float* b_ep = (const float*)d_in[13];
    const float* W_es = (const float*)d_in[14]; const float* b_es = (const float*)d_in[15];
    const float* W_ef = (const float*)d_in[16]; const float* b_ef = (const float*)d_in[17];
    const float* Wg_prev = (const float*)d_in[18]; const float* bg_prev = (const float*)d_in[19];
    const float* Wg_succ = (const float*)d_in[20]; const float* bg_succ = (const float*)d_in[21];
    const float* Wg_tf   = (const float*)d_in[22]; const float* bg_tf   = (const float*)d_in[23];
    const float* Wr1 = (const float*)d_in[24]; const float* br1 = (const float*)d_in[25];
    const float* Wr2 = (const float*)d_in[26]; const float* br2 = (const float*)d_in[27];
    const float* Wr3 = (const float*)d_in[28]; const float* br3 = (const float*)d_in[29];

    char* ws = (char*)d_ws;
    size_t off = 0;
    auto alloc = [&](size_t bytes) -> char* {
        char* p = ws + off;
        off += (bytes + 255) & ~(size_t)255;
        return p;
    };
    float* inst  = (float*)alloc((size_t)NI * 64 * 4);
    unsigned short* inst_bf = (unsigned short*)alloc((size_t)NI * 64 * 2);
    unsigned short* X = (unsigned short*)alloc((size_t)NI * KX * 2);
    float* fin   = (float*)alloc((size_t)NF * 64 * 4);
    float* aggHf = (float*)alloc((size_t)NF * 64 * 4);
    float* aggEp = (float*)alloc((size_t)NI * 8 * 4);
    float* aggEs = (float*)alloc((size_t)NI * 8 * 4);
    float* aggEf = (float*)alloc((size_t)NF * 8 * 4);
    char* zero_begin = ws + off;
    int* cnt  = (int*)alloc((size_t)NT * 4);
    int* fill = (int*)alloc((size_t)NT * 4);
    char* zero_end = ws + off;
    int* rpAll = (int*)alloc((size_t)(NT + 1) * 4);
    int* colP = (int*)alloc((size_t)NE * 4);
    int* colS = (int*)alloc((size_t)NE * 4);
    int* colF = (int*)alloc((size_t)NEF * 4);
    int* bsum = (int*)alloc(1024 * 4);
    (void)ws_size; (void)in_sizes; (void)n_in; (void)out_size;

    // scatter-stage fp32 edge-embed buffers alias regions dead until after k_eagg2:
    //   ePbuf (NE*32B = 25.6MB)  -> X (32MB, live cols written by k_prep_x/spmm later)
    //   eSbuf (NE*32B = 25.6MB)  -> inst (25.6MB, first written by k_node_embed)
    //   eFbuf (NEF*32B = 6.4MB)  -> inst_bf (12.8MB, first written by k_node_embed)
    float* ePbuf = (float*)X;
    float* eSbuf = inst;
    float* eFbuf = (float*)inst_bf;

    hipMemsetAsync(zero_begin, 0, (size_t)(zero_end - zero_begin), stream);

    k_count<<<(NE + 255) / 256, 256, 0, stream>>>(prev_src, prev_dst, tf_dst, cnt);

    int nb = (NT + 255) / 256;
    k_scan1<<<nb, 256, 0, stream>>>(cnt, NT, rpAll, bsum);
    k_scan2<<<1, 1024, 0, stream>>>(bsum, nb);
    k_scan3<<<nb, 256, 0, stream>>>(rpAll, bsum, NT);

    k_scatter<<<(NE + 255) / 256, 256, 0, stream>>>(prev_src, prev_dst, tf_src, tf_dst,
                                                    xe, xef, rpAll, fill,
                                                    colP, colS, colF,
                                                    ePbuf, eSbuf, eFbuf,
                                                    W_ep, b_ep, W_es, b_es, W_ef, b_ef);

    k_eagg2<<<(NT + 255) / 256, 256, 0, stream>>>(rpAll, ePbuf, eSbuf, eFbuf,
                                                  aggEp, aggEs, aggEf);

    k_prep_x<<<(NI + 255) / 256, 256, 0, stream>>>(rpAll, aggEp, aggEs, X);

    {
        int waves = (NI + NF + 15) / 16;
        int blocks = (waves + 3) / 4;
        k_node_embed<<<blocks, 256, 0, stream>>>(xi, xf, W_it, b_it, W_ft, b_ft,
                                                 inst, inst_bf, fin);
    }

    for (int l = 0; l < NL; l++) {
        // 4 tasks per wave, 16 tasks per 256-thread block; F tasks first
        k_spmm<<<(NT + 15) / 16, 256, 0, stream>>>(inst_bf, rpAll,
                                                   colP, colS, colF,
                                                   X, aggHf);
        k_dense_layer<<<NBI + NBF, 256, 0, stream>>>(X, inst, inst_bf, rpAll,
                                                     Wg_prev + (size_t)l * 72 * 64, bg_prev + (size_t)l * 64,
                                                     Wg_succ + (size_t)l * 72 * 64, bg_succ + (size_t)l * 64,
                                                     fin, aggHf, aggEf,
                                                     Wg_tf + (size_t)l * 72 * 64, bg_tf + (size_t)l * 64);
    }

    k_head<<<(NF + 63) / 64, 64, 0, stream>>>(fin, Wr1, br1, Wr2, br2, Wr3, br3, (float*)d_out);
}

// Round 10
// 1110.608 us; speedup vs baseline: 3.7415x; 1.1234x over previous
//
#include <hip/hip_runtime.h>
#include <math.h>

#define NI 100000
#define NF 2000
#define NE 800000
#define NEF 200000
#define DN 16
#define NL 11
#define NT (2 * NI + NF)   // concatenated node-direction count: P | S | F
#define KX 160             // padded K stride of X (bf16): 64 P | 8 meP | 64 S | 8 meS | 16 zero
#define NBI 782            // inst GEMM blocks: ceil(NI/128)
#define NBF 125            // fin blocks: NF*16/256
#define WTN (64 * 168)     // Wt tile elements per layer

typedef short bf16x8 __attribute__((ext_vector_type(8)));
typedef float f32x4 __attribute__((ext_vector_type(4)));

__device__ __forceinline__ float elu1(float x) { return x > 0.f ? x : expm1f(x); }

__device__ __forceinline__ unsigned short f2bf(float f) {
    unsigned x = __float_as_uint(f);
    return (unsigned short)((x + 0x7fffu + ((x >> 16) & 1u)) >> 16);
}
__device__ __forceinline__ float bf2f(unsigned short u) {
    return __uint_as_float(((unsigned)u) << 16);
}

// ---------------- CSR build (concatenated P|S|F degree array) ----------------
__global__ __launch_bounds__(256) void k_count(const int* __restrict__ prev_src,
                                               const int* __restrict__ prev_dst,
                                               const int* __restrict__ tf_dst,
                                               int* cnt) {
    int i = blockIdx.x * blockDim.x + threadIdx.x;
    if (i < NE) {
        atomicAdd(&cnt[prev_dst[i]], 1);
        atomicAdd(&cnt[NI + prev_src[i]], 1);
    }
    if (i < NEF) atomicAdd(&cnt[2 * NI + tf_dst[i]], 1);
}

__global__ __launch_bounds__(256) void k_scan1(const int* __restrict__ cnt, int n,
                                               int* __restrict__ rp, int* __restrict__ bsum) {
    __shared__ int s[256];
    int t = threadIdx.x, b = blockIdx.x, i = b * 256 + t;
    int v = (i < n) ? cnt[i] : 0;
    s[t] = v; __syncthreads();
    for (int o = 1; o < 256; o <<= 1) {
        int x = (t >= o) ? s[t - o] : 0;
        __syncthreads();
        s[t] += x;
        __syncthreads();
    }
    if (i < n) rp[i + 1] = s[t];
    if (t == 255) bsum[b] = s[255];
}

__global__ __launch_bounds__(1024) void k_scan2(int* __restrict__ bsum, int nb) {
    __shared__ int s[1024];
    int t = threadIdx.x;
    int v = (t < nb) ? bsum[t] : 0;
    s[t] = v; __syncthreads();
    for (int o = 1; o < 1024; o <<= 1) {
        int x = (t >= o) ? s[t - o] : 0;
        __syncthreads();
        s[t] += x;
        __syncthreads();
    }
    if (t < nb) bsum[t] = s[t] - v;   // exclusive block offsets
}

__global__ __launch_bounds__(256) void k_scan3(int* __restrict__ rp, const int* __restrict__ bsum, int n) {
    int i = blockIdx.x * blockDim.x + threadIdx.x;
    if (i < n) rp[i + 1] += bsum[i >> 8];
    if (i == 0) rp[0] = 0;
}

// ---------------- precompute bf16 GEMM weight tiles for all layers ----------------
// wcat[l][n][k] = f2bf( k<72 ? 0.5*Wp_l[k][n] : k<144 ? 0.5*Ws_l[k-72][n] : 0 )
// Identical values/layout to the old in-block staging -> bit-identical GEMM.
__global__ __launch_bounds__(256) void k_prep_w(const float* __restrict__ Wg_prev,
                                                const float* __restrict__ Wg_succ,
                                                unsigned short* __restrict__ wcat) {
    int idx = blockIdx.x * blockDim.x + threadIdx.x;
    if (idx >= NL * WTN) return;
    int l = idx / WTN;
    int r = idx - l * WTN;
    int n = r / 168, k = r - n * 168;
    float v = 0.f;
    if (k < 72)       v = 0.5f * Wg_prev[(size_t)l * 72 * 64 + k * 64 + n];
    else if (k < 144) v = 0.5f * Wg_succ[(size_t)l * 72 * 64 + (k - 72) * 64 + n];
    wcat[idx] = f2bf(v);
}

// ---------------- scatter: CSR cols + fused edge-embed (fp32) in CSR slot order ----
__global__ __launch_bounds__(256) void k_scatter(const int* __restrict__ prev_src,
                                                 const int* __restrict__ prev_dst,
                                                 const int* __restrict__ tf_src,
                                                 const int* __restrict__ tf_dst,
                                                 const float* __restrict__ xe,
                                                 const float* __restrict__ xef,
                                                 const int* __restrict__ rp,
                                                 int* fill,
                                                 int* colP, int* colS, int* colF,
                                                 float* __restrict__ ePbuf,
                                                 float* __restrict__ eSbuf,
                                                 float* __restrict__ eFbuf,
                                                 const float* __restrict__ Wep, const float* __restrict__ bep,
                                                 const float* __restrict__ Wes, const float* __restrict__ bes,
                                                 const float* __restrict__ Wef, const float* __restrict__ bef) {
    int i = blockIdx.x * blockDim.x + threadIdx.x;
    if (i < NE) {
        int s = prev_src[i], d = prev_dst[i];
        float4 x0 = ((const float4*)xe)[(size_t)i * 2];
        float4 x1 = ((const float4*)xe)[(size_t)i * 2 + 1];
        float x[8] = {x0.x, x0.y, x0.z, x0.w, x1.x, x1.y, x1.z, x1.w};
        float eP[8], eS[8];
#pragma unroll
        for (int j = 0; j < 8; j++) {
            float vp = bep[j], vs = bes[j];
#pragma unroll
            for (int k = 0; k < 8; k++) { vp += x[k] * Wep[k * 8 + j]; vs += x[k] * Wes[k * 8 + j]; }
            eP[j] = elu1(vp); eS[j] = elu1(vs);
        }
        int tP = rp[d] + atomicAdd(&fill[d], 1);
        colP[tP] = s;
        ((float4*)ePbuf)[(size_t)tP * 2]     = make_float4(eP[0], eP[1], eP[2], eP[3]);
        ((float4*)ePbuf)[(size_t)tP * 2 + 1] = make_float4(eP[4], eP[5], eP[6], eP[7]);
        int tS = rp[NI + s] - NE + atomicAdd(&fill[NI + s], 1);
        colS[tS] = d;
        ((float4*)eSbuf)[(size_t)tS * 2]     = make_float4(eS[0], eS[1], eS[2], eS[3]);
        ((float4*)eSbuf)[(size_t)tS * 2 + 1] = make_float4(eS[4], eS[5], eS[6], eS[7]);
    }
    if (i < NEF) {
        int s = tf_src[i], d = tf_dst[i];
        float4 x0 = ((const float4*)xef)[(size_t)i * 2];
        float4 x1 = ((const float4*)xef)[(size_t)i * 2 + 1];
        float x[8] = {x0.x, x0.y, x0.z, x0.w, x1.x, x1.y, x1.z, x1.w};
        float eF[8];
#pragma unroll
        for (int j = 0; j < 8; j++) {
            float v = bef[j];
#pragma unroll
            for (int k = 0; k < 8; k++) v += x[k] * Wef[k * 8 + j];
            eF[j] = elu1(v);
        }
        int tF = rp[2 * NI + d] - 2 * NE + atomicAdd(&fill[2 * NI + d], 1);
        colF[tF] = s;
        ((float4*)eFbuf)[(size_t)tF * 2]     = make_float4(eF[0], eF[1], eF[2], eF[3]);
        ((float4*)eFbuf)[(size_t)tF * 2 + 1] = make_float4(eF[4], eF[5], eF[6], eF[7]);
    }
}

// ---------------- edge-embed aggregation: sequential run-sum per node ----------------
__global__ __launch_bounds__(256) void k_eagg2(const int* __restrict__ rp,
                                               const float* __restrict__ ePbuf,
                                               const float* __restrict__ eSbuf,
                                               const float* __restrict__ eFbuf,
                                               float* __restrict__ aggEp,
                                               float* __restrict__ aggEs,
                                               float* __restrict__ aggEf) {
    int idx = blockIdx.x * blockDim.x + threadIdx.x;
    if (idx >= NT) return;
    const float* buf; float* out; int s, e;
    if (idx < NF) {
        int n = idx;
        s = rp[2 * NI + n] - 2 * NE; e = rp[2 * NI + n + 1] - 2 * NE;
        buf = eFbuf; out = aggEf + (size_t)n * 8;
    } else if (idx < NF + NI) {
        int n = idx - NF;
        s = rp[n]; e = rp[n + 1];
        buf = ePbuf; out = aggEp + (size_t)n * 8;
    } else {
        int n = idx - NF - NI;
        s = rp[NI + n] - NE; e = rp[NI + n + 1] - NE;
        buf = eSbuf; out = aggEs + (size_t)n * 8;
    }
    float a0 = 0.f, a1 = 0.f, a2 = 0.f, a3 = 0.f, a4 = 0.f, a5 = 0.f, a6 = 0.f, a7 = 0.f;
    for (int t = s; t < e; ++t) {
        float4 v0 = ((const float4*)buf)[(size_t)t * 2];
        float4 v1 = ((const float4*)buf)[(size_t)t * 2 + 1];
        a0 += v0.x; a1 += v0.y; a2 += v0.z; a3 += v0.w;
        a4 += v1.x; a5 += v1.y; a6 += v1.z; a7 += v1.w;
    }
    ((float4*)out)[0] = make_float4(a0, a1, a2, a3);
    ((float4*)out)[1] = make_float4(a4, a5, a6, a7);
}

// ---------------- prep X: layer-invariant me-columns + zero pad ----------------
__global__ __launch_bounds__(256) void k_prep_x(const int* __restrict__ rpAll,
                                                const float* __restrict__ aggEp,
                                                const float* __restrict__ aggEs,
                                                unsigned short* __restrict__ X) {
    int i = blockIdx.x * blockDim.x + threadIdx.x;
    if (i >= NI) return;
    int cP = rpAll[i + 1] - rpAll[i];
    int cS = rpAll[NI + i + 1] - rpAll[NI + i];
    float invP = 1.f / (float)max(cP, 1);
    float invS = 1.f / (float)max(cS, 1);
    unsigned short* xr = X + (size_t)i * KX;
#pragma unroll
    for (int c = 0; c < 2; c++) {
        float4 ep = ((const float4*)(aggEp + (size_t)i * 8))[c];
        float4 es = ((const float4*)(aggEs + (size_t)i * 8))[c];
        ushort4 up; up.x = f2bf(ep.x * invP); up.y = f2bf(ep.y * invP);
                    up.z = f2bf(ep.z * invP); up.w = f2bf(ep.w * invP);
        ushort4 us; us.x = f2bf(es.x * invS); us.y = f2bf(es.y * invS);
                    us.z = f2bf(es.z * invS); us.w = f2bf(es.w * invS);
        ((ushort4*)(xr + 64))[c]  = up;
        ((ushort4*)(xr + 136))[c] = us;
    }
    ushort4 z; z.x = z.y = z.z = z.w = 0;
#pragma unroll
    for (int c = 0; c < 4; c++) ((ushort4*)(xr + 144))[c] = z;
}

// ---------------- node embedding (wave per node, lane = output feature) ----------------
__global__ __launch_bounds__(256) void k_node_embed(const float* __restrict__ xi,
                                                    const float* __restrict__ xf,
                                                    const float* __restrict__ Wit, const float* __restrict__ bit,
                                                    const float* __restrict__ Wft, const float* __restrict__ bft,
                                                    float* __restrict__ inst, unsigned short* __restrict__ inst_bf,
                                                    float* __restrict__ fin) {
    const int NPW = 16;
    int lane = threadIdx.x & 63;
    int wave = (blockIdx.x * blockDim.x + threadIdx.x) >> 6;
    int base = wave * NPW;
    float wi[DN], wf[DN];
#pragma unroll
    for (int k = 0; k < DN; k++) { wi[k] = Wit[k * 64 + lane]; wf[k] = Wft[k * 64 + lane]; }
    float bi = bit[lane], bf = bft[lane];
    for (int n = 0; n < NPW; n++) {
        int i = base + n;
        if (i < NI) {
            const float* x = xi + (size_t)i * DN;
            float acc = bi;
#pragma unroll
            for (int k = 0; k < DN; k++) acc += x[k] * wi[k];
            float v = elu1(acc);
            inst[(size_t)i * 64 + lane] = v;
            inst_bf[(size_t)i * 64 + lane] = f2bf(v);
        } else if (i < NI + NF) {
            int f = i - NI;
            const float* x = xf + (size_t)f * DN;
            float acc = bf;
#pragma unroll
            for (int k = 0; k < DN; k++) acc += x[k] * wf[k];
            fin[(size_t)f * 64 + lane] = elu1(acc);
        }
    }
}

// ---------------- SpMM (gather-mean over bf16 rows), 4 tasks per wave ----------------
// lane = (task-slot n2 = lane>>4, feature-quad fq = lane&15). F tasks first.
// 8-deep gather unroll; fp32 add chain strictly pos-ascending -> bit-identical
// to the round-4-verified spmm. No cross-lane ops.
__global__ __launch_bounds__(256) void k_spmm(const unsigned short* __restrict__ inst_bf,
                                              const int* __restrict__ rp,
                                              const int* __restrict__ colP,
                                              const int* __restrict__ colS,
                                              const int* __restrict__ colF,
                                              unsigned short* __restrict__ X,
                                              float* __restrict__ aggHf) {
    int lane = threadIdx.x & 63;
    int wv = (blockIdx.x * blockDim.x + threadIdx.x) >> 6;
    int n2 = lane >> 4;       // task slot 0..3
    int fq = lane & 15;       // feature quad
    int task = wv * 4 + n2;
    if (task >= NT) return;   // per-lane exit; no cross-lane ops below

    const int* col; int i, rbase, ebase, xoff;
    if (task < NF)            { i = task;           rbase = 2 * NI; ebase = 2 * NE; col = colF; xoff = -1; }
    else if (task < NF + NI)  { i = task - NF;      rbase = 0;      ebase = 0;      col = colP; xoff = 0;  }
    else                      { i = task - NF - NI; rbase = NI;     ebase = NE;     col = colS; xoff = 72; }

    int s = rp[rbase + i] - ebase, e1 = rp[rbase + i + 1] - ebase;
    const unsigned short* src = inst_bf + fq * 4;
    float4 acc = make_float4(0.f, 0.f, 0.f, 0.f);

    int pos = s;
    for (; pos + 8 <= e1; pos += 8) {            // 8 independent gathers in flight
        int c[8];
#pragma unroll
        for (int u = 0; u < 8; u++) c[u] = col[pos + u];
        ushort4 v[8];
#pragma unroll
        for (int u = 0; u < 8; u++) v[u] = *(const ushort4*)(src + (size_t)c[u] * 64);
#pragma unroll
        for (int u = 0; u < 8; u++) {
            acc.x += bf2f(v[u].x); acc.y += bf2f(v[u].y);
            acc.z += bf2f(v[u].z); acc.w += bf2f(v[u].w);
        }
    }
    for (; pos + 4 <= e1; pos += 4) {            // 4-deep
        int c0 = col[pos], c1 = col[pos + 1], c2 = col[pos + 2], c3 = col[pos + 3];
        ushort4 v0 = *(const ushort4*)(src + (size_t)c0 * 64);
        ushort4 v1 = *(const ushort4*)(src + (size_t)c1 * 64);
        ushort4 v2 = *(const ushort4*)(src + (size_t)c2 * 64);
        ushort4 v3 = *(const ushort4*)(src + (size_t)c3 * 64);
        acc.x += bf2f(v0.x); acc.y += bf2f(v0.y); acc.z += bf2f(v0.z); acc.w += bf2f(v0.w);
        acc.x += bf2f(v1.x); acc.y += bf2f(v1.y); acc.z += bf2f(v1.z); acc.w += bf2f(v1.w);
        acc.x += bf2f(v2.x); acc.y += bf2f(v2.y); acc.z += bf2f(v2.z); acc.w += bf2f(v2.w);
        acc.x += bf2f(v3.x); acc.y += bf2f(v3.y); acc.z += bf2f(v3.z); acc.w += bf2f(v3.w);
    }
    for (; pos < e1; ++pos) {                    // tail, order preserved
        int c = col[pos];
        ushort4 v = *(const ushort4*)(src + (size_t)c * 64);
        acc.x += bf2f(v.x); acc.y += bf2f(v.y); acc.z += bf2f(v.z); acc.w += bf2f(v.w);
    }

    int cnt = e1 - s;
    float inv = cnt > 0 ? 1.f / (float)cnt : 0.f;
    if (xoff >= 0) {
        ushort4 o;
        o.x = f2bf(acc.x * inv); o.y = f2bf(acc.y * inv);
        o.z = f2bf(acc.z * inv); o.w = f2bf(acc.w * inv);
        *(ushort4*)(X + (size_t)i * KX + xoff + fq * 4) = o;
    } else {
        *(float4*)(aggHf + (size_t)i * 64 + fq * 4) =
            make_float4(acc.x * inv, acc.y * inv, acc.z * inv, acc.w * inv);
    }
}

// ---------------- per-layer dense update: inst MFMA GEMM blocks + fin blocks ----------------
// blocks [0, NBI): X[NI][160] @ wcat_l (precomputed bf16) via MFMA, residual+elu.
// blocks [NBI, NBI+NBF): fin update, thread=(node, j-quad), fp32 bit-identical.
__global__ __launch_bounds__(256) void k_dense_layer(
    const unsigned short* __restrict__ X,
    float* __restrict__ inst, unsigned short* __restrict__ inst_bf,
    const int* __restrict__ rpAll,
    const unsigned short* __restrict__ wcat_l,
    const float* __restrict__ bp, const float* __restrict__ bs,
    float* __restrict__ fin,
    const float* __restrict__ aggHf, const float* __restrict__ aggEf,
    const float* __restrict__ Wf, const float* __restrict__ bf) {
    __shared__ __align__(16) unsigned short Wt[64][168];  // [n][k], 336B rows (16-aligned)
    int t = threadIdx.x;

    if (blockIdx.x < NBI) {
        // ---------- instruction-node GEMM path ----------
        // linear 16B copy of the precomputed tile: 1344 uint4s
        {
            const uint4* wsrc = (const uint4*)wcat_l;
            uint4* wdst = (uint4*)&Wt[0][0];
            for (int idx = t; idx < 1344; idx += 256) wdst[idx] = wsrc[idx];
        }
        __syncthreads();

        int wave = t >> 6, lane = t & 63;
        int rowbase = blockIdx.x * 128 + wave * 32;   // this wave's 32 rows
        int lrow = lane & 15, lk = (lane >> 4) * 8;

        f32x4 acc[2][4];
#pragma unroll
        for (int rb = 0; rb < 2; rb++)
#pragma unroll
            for (int nb = 0; nb < 4; nb++) acc[rb][nb] = (f32x4){0.f, 0.f, 0.f, 0.f};

#pragma unroll
        for (int kc = 0; kc < 5; kc++) {
            int k0 = kc * 32 + lk;
            bf16x8 a[2], b[4];
#pragma unroll
            for (int rb = 0; rb < 2; rb++) {
                int r = min(rowbase + rb * 16 + lrow, NI - 1);
                a[rb] = *(const bf16x8*)(X + (size_t)r * KX + k0);
            }
#pragma unroll
            for (int nb = 0; nb < 4; nb++)
                b[nb] = *(const bf16x8*)(&Wt[nb * 16 + lrow][k0]);
#pragma unroll
            for (int rb = 0; rb < 2; rb++)
#pragma unroll
                for (int nb = 0; nb < 4; nb++)
                    acc[rb][nb] = __builtin_amdgcn_mfma_f32_16x16x32_bf16(a[rb], b[nb], acc[rb][nb], 0, 0, 0);
        }

        // epilogue: C[row= (lane>>4)*4+j, col= nb*16 + (lane&15)]
#pragma unroll
        for (int rb = 0; rb < 2; rb++) {
#pragma unroll
            for (int j = 0; j < 4; j++) {
                int node = rowbase + rb * 16 + (lane >> 4) * 4 + j;
                bool v = node < NI;
                int nn = v ? node : NI - 1;
                float mP = (v && (rpAll[nn + 1] > rpAll[nn])) ? 0.5f : 0.f;
                float mS = (v && (rpAll[NI + nn + 1] > rpAll[NI + nn])) ? 0.5f : 0.f;
#pragma unroll
                for (int nb = 0; nb < 4; nb++) {
                    int col = nb * 16 + lrow;
                    float x = inst[(size_t)nn * 64 + col] + acc[rb][nb][j] + mP * bp[col] + mS * bs[col];
                    x = elu1(x);
                    if (v) {
                        inst[(size_t)nn * 64 + col] = x;
                        inst_bf[(size_t)nn * 64 + col] = f2bf(x);
                    }
                }
            }
        }
    } else {
        // ---------- final-node path: thread = (node, j-quad) ----------
        int tid = (blockIdx.x - NBI) * 256 + t;     // 0 .. 31999
        int n = tid >> 4;                           // node 0..1999
        int jq = tid & 15;                          // j-quad 0..15
        const int* rpF = rpAll + 2 * NI;
        int cF = rpF[n + 1] - rpF[n];
        float mF = (cF > 0) ? 1.f : 0.f;
        float invF = 1.f / (float)max(cF, 1);

        float acc0 = bf[jq * 4 + 0], acc1 = bf[jq * 4 + 1];
        float acc2 = bf[jq * 4 + 2], acc3 = bf[jq * 4 + 3];
        const float* hrow = aggHf + (size_t)n * 64;
        for (int k = 0; k < 64; k++) {
            float h = hrow[k];
            float4 w = *(const float4*)(Wf + (size_t)k * 64 + jq * 4);
            acc0 += h * w.x; acc1 += h * w.y; acc2 += h * w.z; acc3 += h * w.w;
        }
        const float* erow = aggEf + (size_t)n * 8;
#pragma unroll
        for (int k = 0; k < 8; k++) {
            float h = erow[k] * invF;
            float4 w = *(const float4*)(Wf + (size_t)(64 + k) * 64 + jq * 4);
            acc0 += h * w.x; acc1 += h * w.y; acc2 += h * w.z; acc3 += h * w.w;
        }
        float4 fv = *(const float4*)(fin + (size_t)n * 64 + jq * 4);
        float4 o;
        o.x = elu1(fv.x + mF * acc0);
        o.y = elu1(fv.y + mF * acc1);
        o.z = elu1(fv.z + mF * acc2);
        o.w = elu1(fv.w + mF * acc3);
        *(float4*)(fin + (size_t)n * 64 + jq * 4) = o;
    }
}

// ---------------- readout head ----------------
__global__ __launch_bounds__(64, 1) void k_head(
    const float* __restrict__ fin,
    const float* __restrict__ Wr1, const float* __restrict__ br1,
    const float* __restrict__ Wr2, const float* __restrict__ br2,
    const float* __restrict__ Wr3, const float* __restrict__ br3,
    float* __restrict__ out) {
    __shared__ float hL[64 * 65];
    const int lane = threadIdx.x;
    const int base = blockIdx.x * 64;

    for (int idx = lane; idx < 1024; idx += 64) {
        int n = idx >> 4, k4 = idx & 15;
        float4 v = ((const float4*)fin)[(size_t)min(base + n, NF - 1) * 16 + k4];
        float* d = &hL[n * 65 + k4 * 4];
        d[0] = v.x; d[1] = v.y; d[2] = v.z; d[3] = v.w;
    }
    __syncthreads();

    float acc[64];
#pragma unroll
    for (int j = 0; j < 64; j++) acc[j] = br1[j];
#pragma unroll 4
    for (int k = 0; k < 64; k++) {
        float h = hL[lane * 65 + k];
#pragma unroll
        for (int j = 0; j < 64; j++) acc[j] += h * Wr1[k * 64 + j];
    }
#pragma unroll
    for (int j = 0; j < 64; j++) hL[lane * 65 + j] = elu1(acc[j]);

#pragma unroll
    for (int j = 0; j < 64; j++) acc[j] = br2[j];
#pragma unroll 4
    for (int k = 0; k < 64; k++) {
        float h = hL[lane * 65 + k];
#pragma unroll
        for (int j = 0; j < 64; j++) acc[j] += h * Wr2[k * 64 + j];
    }
    float r = br3[0];
#pragma unroll
    for (int j = 0; j < 64; j++) r += elu1(acc[j]) * Wr3[j];

    int i = base + lane;
    if (i < NF) out[i] = r;
}

extern "C" void kernel_launch(void* const* d_in, const int* in_sizes, int n_in,
                              void* d_out, int out_size, void* d_ws, size_t ws_size,
                              hipStream_t stream) {
    const float* xi  = (const float*)d_in[0];
    const float* xf  = (const float*)d_in[1];
    const float* xe  = (const float*)d_in[2];
    const float* xef = (const float*)d_in[3];
    const int* prev_src = (const int*)d_in[4];
    const int* prev_dst = (const int*)d_in[5];
    const int* tf_src = (const int*)d_in[6];
    const int* tf_dst = (const int*)d_in[7];
    const float* W_it = (const float*)d_in[8];  const float* b_it = (const float*)d_in[9];
    const float* W_ft = (const float*)d_in[10]; const float* b_ft = (const float*)d_in[11];
    const float* W_ep = (const float*)d_in[12]; const float* b_ep = (const float*)d_in[13];
    const float* W_es = (const float*)d_in[14]; const float* b_es = (const float*)d_in[15];
    const float* W_ef = (const float*)d_in[16]; const float* b_ef = (const float*)d_in[17];
    const float* Wg_prev = (const float*)d_in[18]; const float* bg_prev = (const float*)d_in[19];
    const float* Wg_succ = (const float*)d_in[20]; const float* bg_succ = (const float*)d_in[21];
    const float* Wg_tf   = (const float*)d_in[22]; const float* bg_tf   = (const float*)d_in[23];
    const float* Wr1 = (const float*)d_in[24]; const float* br1 = (const float*)d_in[25];
    const float* Wr2 = (const float*)d_in[26]; const float* br2 = (const float*)d_in[27];
    const float* Wr3 = (const float*)d_in[28]; const float* br3 = (const float*)d_in[29];

    char* ws = (char*)d_ws;
    size_t off = 0;
    auto alloc = [&](size_t bytes) -> char* {
        char* p = ws + off;
        off += (bytes + 255) & ~(size_t)255;
        return p;
    };
    float* inst  = (float*)alloc((size_t)NI * 64 * 4);
    unsigned short* inst_bf = (unsigned short*)alloc((size_t)NI * 64 * 2);
    unsigned short* X = (unsigned short*)alloc((size_t)NI * KX * 2);
    float* fin   = (float*)alloc((size_t)NF * 64 * 4);
    float* aggHf = (float*)alloc((size_t)NF * 64 * 4);
    float* aggEp = (float*)alloc((size_t)NI * 8 * 4);
    float* aggEs = (float*)alloc((size_t)NI * 8 * 4);
    float* aggEf = (float*)alloc((size_t)NF * 8 * 4);
    unsigned short* wcat = (unsigned short*)alloc((size_t)NL * WTN * 2);
    char* zero_begin = ws + off;
    int* cnt  = (int*)alloc((size_t)NT * 4);
    int* fill = (int*)alloc((size_t)NT * 4);
    char* zero_end = ws + off;
    int* rpAll = (int*)alloc((size_t)(NT + 1) * 4);
    int* colP = (int*)alloc((size_t)NE * 4);
    int* colS = (int*)alloc((size_t)NE * 4);
    int* colF = (int*)alloc((size_t)NEF * 4);
    int* bsum = (int*)alloc(1024 * 4);
    (void)ws_size; (void)in_sizes; (void)n_in; (void)out_size;

    // scatter-stage fp32 edge-embed buffers alias regions dead until after k_eagg2:
    //   ePbuf (NE*32B = 25.6MB)  -> X (32MB, live cols written by k_prep_x/spmm later)
    //   eSbuf (NE*32B = 25.6MB)  -> inst (25.6MB, first written by k_node_embed)
    //   eFbuf (NEF*32B = 6.4MB)  -> inst_bf (12.8MB, first written by k_node_embed)
    float* ePbuf = (float*)X;
    float* eSbuf = inst;
    float* eFbuf = (float*)inst_bf;

    hipMemsetAsync(zero_begin, 0, (size_t)(zero_end - zero_begin), stream);

    k_prep_w<<<(NL * WTN + 255) / 256, 256, 0, stream>>>(Wg_prev, Wg_succ, wcat);

    k_count<<<(NE + 255) / 256, 256, 0, stream>>>(prev_src, prev_dst, tf_dst, cnt);

    int nb = (NT + 255) / 256;
    k_scan1<<<nb, 256, 0, stream>>>(cnt, NT, rpAll, bsum);
    k_scan2<<<1, 1024, 0, stream>>>(bsum, nb);
    k_scan3<<<nb, 256, 0, stream>>>(rpAll, bsum, NT);

    k_scatter<<<(NE + 255) / 256, 256, 0, stream>>>(prev_src, prev_dst, tf_src, tf_dst,
                                                    xe, xef, rpAll, fill,
                                                    colP, colS, colF,
                                                    ePbuf, eSbuf, eFbuf,
                                                    W_ep, b_ep, W_es, b_es, W_ef, b_ef);

    k_eagg2<<<(NT + 255) / 256, 256, 0, stream>>>(rpAll, ePbuf, eSbuf, eFbuf,
                                                  aggEp, aggEs, aggEf);

    k_prep_x<<<(NI + 255) / 256, 256, 0, stream>>>(rpAll, aggEp, aggEs, X);

    {
        int waves = (NI + NF + 15) / 16;
        int blocks = (waves + 3) / 4;
        k_node_embed<<<blocks, 256, 0, stream>>>(xi, xf, W_it, b_it, W_ft, b_ft,
                                                 inst, inst_bf, fin);
    }

    for (int l = 0; l < NL; l++) {
        k_spmm<<<(NT + 15) / 16, 256, 0, stream>>>(inst_bf, rpAll,
                                                   colP, colS, colF,
                                                   X, aggHf);
        k_dense_layer<<<NBI + NBF, 256, 0, stream>>>(X, inst, inst_bf, rpAll,
                                                     wcat + (size_t)l * WTN,
                                                     bg_prev + (size_t)l * 64, bg_succ + (size_t)l * 64,
                                                     fin, aggHf, aggEf,
                                                     Wg_tf + (size_t)l * 72 * 64, bg_tf + (size_t)l * 64);
    }

    k_head<<<(NF + 63) / 64, 64, 0, stream>>>(fin, Wr1, br1, Wr2, br2, Wr3, br3, (float*)d_out);
}

// Round 11
// 1057.962 us; speedup vs baseline: 3.9277x; 1.0498x over previous
//
#include <hip/hip_runtime.h>
#include <math.h>

#define NI 100000
#define NF 2000
#define NE 800000
#define NEF 200000
#define DN 16
#define NL 11
#define NT (2 * NI + NF)   // concatenated node-direction count: P | S | F
#define KX 160             // padded K stride of X (bf16): 64 P | 8 meP | 64 S | 8 meS | 16 zero
#define NBI 782            // inst GEMM blocks: ceil(NI/128)
#define NBF 125            // fin blocks: NF*16/256
#define WTN (64 * 168)     // Wt tile elements per layer

typedef short bf16x8 __attribute__((ext_vector_type(8)));
typedef float f32x4 __attribute__((ext_vector_type(4)));

__device__ __forceinline__ float elu1(float x) { return x > 0.f ? x : expm1f(x); }

__device__ __forceinline__ unsigned short f2bf(float f) {
    unsigned x = __float_as_uint(f);
    return (unsigned short)((x + 0x7fffu + ((x >> 16) & 1u)) >> 16);
}
__device__ __forceinline__ float bf2f(unsigned short u) {
    return __uint_as_float(((unsigned)u) << 16);
}

// ---------------- CSR build (concatenated P|S|F degree array) ----------------
__global__ __launch_bounds__(256) void k_count(const int* __restrict__ prev_src,
                                               const int* __restrict__ prev_dst,
                                               const int* __restrict__ tf_dst,
                                               int* cnt) {
    int i = blockIdx.x * blockDim.x + threadIdx.x;
    if (i < NE) {
        atomicAdd(&cnt[prev_dst[i]], 1);
        atomicAdd(&cnt[NI + prev_src[i]], 1);
    }
    if (i < NEF) atomicAdd(&cnt[2 * NI + tf_dst[i]], 1);
}

__global__ __launch_bounds__(256) void k_scan1(const int* __restrict__ cnt, int n,
                                               int* __restrict__ rp, int* __restrict__ bsum) {
    __shared__ int s[256];
    int t = threadIdx.x, b = blockIdx.x, i = b * 256 + t;
    int v = (i < n) ? cnt[i] : 0;
    s[t] = v; __syncthreads();
    for (int o = 1; o < 256; o <<= 1) {
        int x = (t >= o) ? s[t - o] : 0;
        __syncthreads();
        s[t] += x;
        __syncthreads();
    }
    if (i < n) rp[i + 1] = s[t];
    if (t == 255) bsum[b] = s[255];
}

__global__ __launch_bounds__(1024) void k_scan2(int* __restrict__ bsum, int nb) {
    __shared__ int s[1024];
    int t = threadIdx.x;
    int v = (t < nb) ? bsum[t] : 0;
    s[t] = v; __syncthreads();
    for (int o = 1; o < 1024; o <<= 1) {
        int x = (t >= o) ? s[t - o] : 0;
        __syncthreads();
        s[t] += x;
        __syncthreads();
    }
    if (t < nb) bsum[t] = s[t] - v;   // exclusive block offsets
}

__global__ __launch_bounds__(256) void k_scan3(int* __restrict__ rp, const int* __restrict__ bsum, int n) {
    int i = blockIdx.x * blockDim.x + threadIdx.x;
    if (i < n) rp[i + 1] += bsum[i >> 8];
    if (i == 0) rp[0] = 0;
}

// ---------------- precompute bf16 GEMM weight tiles for all layers ----------------
__global__ __launch_bounds__(256) void k_prep_w(const float* __restrict__ Wg_prev,
                                                const float* __restrict__ Wg_succ,
                                                unsigned short* __restrict__ wcat) {
    int idx = blockIdx.x * blockDim.x + threadIdx.x;
    if (idx >= NL * WTN) return;
    int l = idx / WTN;
    int r = idx - l * WTN;
    int n = r / 168, k = r - n * 168;
    float v = 0.f;
    if (k < 72)       v = 0.5f * Wg_prev[(size_t)l * 72 * 64 + k * 64 + n];
    else if (k < 144) v = 0.5f * Wg_succ[(size_t)l * 72 * 64 + (k - 72) * 64 + n];
    wcat[idx] = f2bf(v);
}

// ---------------- scatter: CSR cols + fused edge-embed (fp32) in CSR slot order ----
__global__ __launch_bounds__(256) void k_scatter(const int* __restrict__ prev_src,
                                                 const int* __restrict__ prev_dst,
                                                 const int* __restrict__ tf_src,
                                                 const int* __restrict__ tf_dst,
                                                 const float* __restrict__ xe,
                                                 const float* __restrict__ xef,
                                                 const int* __restrict__ rp,
                                                 int* fill,
                                                 int* colP, int* colS, int* colF,
                                                 float* __restrict__ ePbuf,
                                                 float* __restrict__ eSbuf,
                                                 float* __restrict__ eFbuf,
                                                 const float* __restrict__ Wep, const float* __restrict__ bep,
                                                 const float* __restrict__ Wes, const float* __restrict__ bes,
                                                 const float* __restrict__ Wef, const float* __restrict__ bef) {
    int i = blockIdx.x * blockDim.x + threadIdx.x;
    if (i < NE) {
        int s = prev_src[i], d = prev_dst[i];
        float4 x0 = ((const float4*)xe)[(size_t)i * 2];
        float4 x1 = ((const float4*)xe)[(size_t)i * 2 + 1];
        float x[8] = {x0.x, x0.y, x0.z, x0.w, x1.x, x1.y, x1.z, x1.w};
        float eP[8], eS[8];
#pragma unroll
        for (int j = 0; j < 8; j++) {
            float vp = bep[j], vs = bes[j];
#pragma unroll
            for (int k = 0; k < 8; k++) { vp += x[k] * Wep[k * 8 + j]; vs += x[k] * Wes[k * 8 + j]; }
            eP[j] = elu1(vp); eS[j] = elu1(vs);
        }
        int tP = rp[d] + atomicAdd(&fill[d], 1);
        colP[tP] = s;
        ((float4*)ePbuf)[(size_t)tP * 2]     = make_float4(eP[0], eP[1], eP[2], eP[3]);
        ((float4*)ePbuf)[(size_t)tP * 2 + 1] = make_float4(eP[4], eP[5], eP[6], eP[7]);
        int tS = rp[NI + s] - NE + atomicAdd(&fill[NI + s], 1);
        colS[tS] = d;
        ((float4*)eSbuf)[(size_t)tS * 2]     = make_float4(eS[0], eS[1], eS[2], eS[3]);
        ((float4*)eSbuf)[(size_t)tS * 2 + 1] = make_float4(eS[4], eS[5], eS[6], eS[7]);
    }
    if (i < NEF) {
        int s = tf_src[i], d = tf_dst[i];
        float4 x0 = ((const float4*)xef)[(size_t)i * 2];
        float4 x1 = ((const float4*)xef)[(size_t)i * 2 + 1];
        float x[8] = {x0.x, x0.y, x0.z, x0.w, x1.x, x1.y, x1.z, x1.w};
        float eF[8];
#pragma unroll
        for (int j = 0; j < 8; j++) {
            float v = bef[j];
#pragma unroll
            for (int k = 0; k < 8; k++) v += x[k] * Wef[k * 8 + j];
            eF[j] = elu1(v);
        }
        int tF = rp[2 * NI + d] - 2 * NE + atomicAdd(&fill[2 * NI + d], 1);
        colF[tF] = s;
        ((float4*)eFbuf)[(size_t)tF * 2]     = make_float4(eF[0], eF[1], eF[2], eF[3]);
        ((float4*)eFbuf)[(size_t)tF * 2 + 1] = make_float4(eF[4], eF[5], eF[6], eF[7]);
    }
}

// ---------------- edge-embed aggregation: sequential run-sum per node ----------------
__global__ __launch_bounds__(256) void k_eagg2(const int* __restrict__ rp,
                                               const float* __restrict__ ePbuf,
                                               const float* __restrict__ eSbuf,
                                               const float* __restrict__ eFbuf,
                                               float* __restrict__ aggEp,
                                               float* __restrict__ aggEs,
                                               float* __restrict__ aggEf) {
    int idx = blockIdx.x * blockDim.x + threadIdx.x;
    if (idx >= NT) return;
    const float* buf; float* out; int s, e;
    if (idx < NF) {
        int n = idx;
        s = rp[2 * NI + n] - 2 * NE; e = rp[2 * NI + n + 1] - 2 * NE;
        buf = eFbuf; out = aggEf + (size_t)n * 8;
    } else if (idx < NF + NI) {
        int n = idx - NF;
        s = rp[n]; e = rp[n + 1];
        buf = ePbuf; out = aggEp + (size_t)n * 8;
    } else {
        int n = idx - NF - NI;
        s = rp[NI + n] - NE; e = rp[NI + n + 1] - NE;
        buf = eSbuf; out = aggEs + (size_t)n * 8;
    }
    float a0 = 0.f, a1 = 0.f, a2 = 0.f, a3 = 0.f, a4 = 0.f, a5 = 0.f, a6 = 0.f, a7 = 0.f;
    for (int t = s; t < e; ++t) {
        float4 v0 = ((const float4*)buf)[(size_t)t * 2];
        float4 v1 = ((const float4*)buf)[(size_t)t * 2 + 1];
        a0 += v0.x; a1 += v0.y; a2 += v0.z; a3 += v0.w;
        a4 += v1.x; a5 += v1.y; a6 += v1.z; a7 += v1.w;
    }
    ((float4*)out)[0] = make_float4(a0, a1, a2, a3);
    ((float4*)out)[1] = make_float4(a4, a5, a6, a7);
}

// ---------------- prep X: layer-invariant me-columns + zero pad ----------------
__global__ __launch_bounds__(256) void k_prep_x(const int* __restrict__ rpAll,
                                                const float* __restrict__ aggEp,
                                                const float* __restrict__ aggEs,
                                                unsigned short* __restrict__ X) {
    int i = blockIdx.x * blockDim.x + threadIdx.x;
    if (i >= NI) return;
    int cP = rpAll[i + 1] - rpAll[i];
    int cS = rpAll[NI + i + 1] - rpAll[NI + i];
    float invP = 1.f / (float)max(cP, 1);
    float invS = 1.f / (float)max(cS, 1);
    unsigned short* xr = X + (size_t)i * KX;
#pragma unroll
    for (int c = 0; c < 2; c++) {
        float4 ep = ((const float4*)(aggEp + (size_t)i * 8))[c];
        float4 es = ((const float4*)(aggEs + (size_t)i * 8))[c];
        ushort4 up; up.x = f2bf(ep.x * invP); up.y = f2bf(ep.y * invP);
                    up.z = f2bf(ep.z * invP); up.w = f2bf(ep.w * invP);
        ushort4 us; us.x = f2bf(es.x * invS); us.y = f2bf(es.y * invS);
                    us.z = f2bf(es.z * invS); us.w = f2bf(es.w * invS);
        ((ushort4*)(xr + 64))[c]  = up;
        ((ushort4*)(xr + 136))[c] = us;
    }
    ushort4 z; z.x = z.y = z.z = z.w = 0;
#pragma unroll
    for (int c = 0; c < 4; c++) ((ushort4*)(xr + 144))[c] = z;
}

// ---------------- node embedding (wave per node, lane = output feature) ----------------
__global__ __launch_bounds__(256) void k_node_embed(const float* __restrict__ xi,
                                                    const float* __restrict__ xf,
                                                    const float* __restrict__ Wit, const float* __restrict__ bit,
                                                    const float* __restrict__ Wft, const float* __restrict__ bft,
                                                    float* __restrict__ inst, unsigned short* __restrict__ inst_bf,
                                                    float* __restrict__ fin) {
    const int NPW = 16;
    int lane = threadIdx.x & 63;
    int wave = (blockIdx.x * blockDim.x + threadIdx.x) >> 6;
    int base = wave * NPW;
    float wi[DN], wf[DN];
#pragma unroll
    for (int k = 0; k < DN; k++) { wi[k] = Wit[k * 64 + lane]; wf[k] = Wft[k * 64 + lane]; }
    float bi = bit[lane], bf = bft[lane];
    for (int n = 0; n < NPW; n++) {
        int i = base + n;
        if (i < NI) {
            const float4* x4 = (const float4*)(xi + (size_t)i * DN);
            float4 xa = x4[0], xb = x4[1], xc = x4[2], xd = x4[3];
            float x[DN] = {xa.x, xa.y, xa.z, xa.w, xb.x, xb.y, xb.z, xb.w,
                           xc.x, xc.y, xc.z, xc.w, xd.x, xd.y, xd.z, xd.w};
            float acc = bi;
#pragma unroll
            for (int k = 0; k < DN; k++) acc += x[k] * wi[k];
            float v = elu1(acc);
            inst[(size_t)i * 64 + lane] = v;
            inst_bf[(size_t)i * 64 + lane] = f2bf(v);
        } else if (i < NI + NF) {
            int f = i - NI;
            const float4* x4 = (const float4*)(xf + (size_t)f * DN);
            float4 xa = x4[0], xb = x4[1], xc = x4[2], xd = x4[3];
            float x[DN] = {xa.x, xa.y, xa.z, xa.w, xb.x, xb.y, xb.z, xb.w,
                           xc.x, xc.y, xc.z, xc.w, xd.x, xd.y, xd.z, xd.w};
            float acc = bf;
#pragma unroll
            for (int k = 0; k < DN; k++) acc += x[k] * wf[k];
            fin[(size_t)f * 64 + lane] = elu1(acc);
        }
    }
}

// ---------------- SpMM (gather-mean over bf16 rows), 8 tasks per wave ----------------
// lane = (task-slot n3 = lane>>3, feature-oct f8 = lane&7). Each 8-lane slot owns
// one node-direction task; each lane loads bf16x8 (16B) of its task's edge row
// -> one vmem instruction gathers 8 rows x 128B = 1KB (coalescing sweet spot).
// Per-feature fp32 accumulation in strictly ascending CSR order — bit-identical
// to the verified round-4/8 spmm. No cross-lane ops. F tasks first.
__global__ __launch_bounds__(256) void k_spmm(const unsigned short* __restrict__ inst_bf,
                                              const int* __restrict__ rp,
                                              const int* __restrict__ colP,
                                              const int* __restrict__ colS,
                                              const int* __restrict__ colF,
                                              unsigned short* __restrict__ X,
                                              float* __restrict__ aggHf) {
    int lane = threadIdx.x & 63;
    int wv = (blockIdx.x * blockDim.x + threadIdx.x) >> 6;
    int n3 = lane >> 3;       // task slot 0..7
    int f8 = lane & 7;        // feature oct
    int task = wv * 8 + n3;
    if (task >= NT) return;   // per-lane exit; no cross-lane ops below

    const int* col; int i, rbase, ebase, xoff;
    if (task < NF)            { i = task;           rbase = 2 * NI; ebase = 2 * NE; col = colF; xoff = -1; }
    else if (task < NF + NI)  { i = task - NF;      rbase = 0;      ebase = 0;      col = colP; xoff = 0;  }
    else                      { i = task - NF - NI; rbase = NI;     ebase = NE;     col = colS; xoff = 72; }

    int s = rp[rbase + i] - ebase, e1 = rp[rbase + i + 1] - ebase;
    const unsigned short* src = inst_bf + f8 * 8;
    float a[8];
#pragma unroll
    for (int j = 0; j < 8; j++) a[j] = 0.f;

    int pos = s;
    for (; pos + 8 <= e1; pos += 8) {            // 8 independent 16B gathers in flight
        int c[8];
#pragma unroll
        for (int u = 0; u < 8; u++) c[u] = col[pos + u];
        bf16x8 v[8];
#pragma unroll
        for (int u = 0; u < 8; u++) v[u] = *(const bf16x8*)(src + (size_t)c[u] * 64);
#pragma unroll
        for (int u = 0; u < 8; u++) {
#pragma unroll
            for (int j = 0; j < 8; j++) a[j] += bf2f((unsigned short)v[u][j]);
        }
    }
    for (; pos + 4 <= e1; pos += 4) {            // 4-deep
        int c0 = col[pos], c1 = col[pos + 1], c2 = col[pos + 2], c3 = col[pos + 3];
        bf16x8 v0 = *(const bf16x8*)(src + (size_t)c0 * 64);
        bf16x8 v1 = *(const bf16x8*)(src + (size_t)c1 * 64);
        bf16x8 v2 = *(const bf16x8*)(src + (size_t)c2 * 64);
        bf16x8 v3 = *(const bf16x8*)(src + (size_t)c3 * 64);
#pragma unroll
        for (int j = 0; j < 8; j++) a[j] += bf2f((unsigned short)v0[j]);
#pragma unroll
        for (int j = 0; j < 8; j++) a[j] += bf2f((unsigned short)v1[j]);
#pragma unroll
        for (int j = 0; j < 8; j++) a[j] += bf2f((unsigned short)v2[j]);
#pragma unroll
        for (int j = 0; j < 8; j++) a[j] += bf2f((unsigned short)v3[j]);
    }
    for (; pos < e1; ++pos) {                    // tail, order preserved
        int c = col[pos];
        bf16x8 v = *(const bf16x8*)(src + (size_t)c * 64);
#pragma unroll
        for (int j = 0; j < 8; j++) a[j] += bf2f((unsigned short)v[j]);
    }

    int cnt = e1 - s;
    float inv = cnt > 0 ? 1.f / (float)cnt : 0.f;
    if (xoff >= 0) {
        ushort4 o0, o1;
        o0.x = f2bf(a[0] * inv); o0.y = f2bf(a[1] * inv);
        o0.z = f2bf(a[2] * inv); o0.w = f2bf(a[3] * inv);
        o1.x = f2bf(a[4] * inv); o1.y = f2bf(a[5] * inv);
        o1.z = f2bf(a[6] * inv); o1.w = f2bf(a[7] * inv);
        unsigned short* dst = X + (size_t)i * KX + xoff + f8 * 8;
        *(ushort4*)dst = o0;
        *(ushort4*)(dst + 4) = o1;
    } else {
        float* dst = aggHf + (size_t)i * 64 + f8 * 8;
        *(float4*)dst = make_float4(a[0] * inv, a[1] * inv, a[2] * inv, a[3] * inv);
        *(float4*)(dst + 4) = make_float4(a[4] * inv, a[5] * inv, a[6] * inv, a[7] * inv);
    }
}

// ---------------- per-layer dense update: inst MFMA GEMM blocks + fin blocks ----------------
__global__ __launch_bounds__(256) void k_dense_layer(
    const unsigned short* __restrict__ X,
    float* __restrict__ inst, unsigned short* __restrict__ inst_bf,
    const int* __restrict__ rpAll,
    const unsigned short* __restrict__ wcat_l,
    const float* __restrict__ bp, const float* __restrict__ bs,
    float* __restrict__ fin,
    const float* __restrict__ aggHf, const float* __restrict__ aggEf,
    const float* __restrict__ Wf, const float* __restrict__ bf) {
    __shared__ __align__(16) unsigned short Wt[64][168];  // [n][k], 336B rows (16-aligned)
    int t = threadIdx.x;

    if (blockIdx.x < NBI) {
        // ---------- instruction-node GEMM path ----------
        {
            const uint4* wsrc = (const uint4*)wcat_l;
            uint4* wdst = (uint4*)&Wt[0][0];
            for (int idx = t; idx < 1344; idx += 256) wdst[idx] = wsrc[idx];
        }
        __syncthreads();

        int wave = t >> 6, lane = t & 63;
        int rowbase = blockIdx.x * 128 + wave * 32;   // this wave's 32 rows
        int lrow = lane & 15, lk = (lane >> 4) * 8;

        f32x4 acc[2][4];
#pragma unroll
        for (int rb = 0; rb < 2; rb++)
#pragma unroll
            for (int nb = 0; nb < 4; nb++) acc[rb][nb] = (f32x4){0.f, 0.f, 0.f, 0.f};

#pragma unroll
        for (int kc = 0; kc < 5; kc++) {
            int k0 = kc * 32 + lk;
            bf16x8 a[2], b[4];
#pragma unroll
            for (int rb = 0; rb < 2; rb++) {
                int r = min(rowbase + rb * 16 + lrow, NI - 1);
                a[rb] = *(const bf16x8*)(X + (size_t)r * KX + k0);
            }
#pragma unroll
            for (int nb = 0; nb < 4; nb++)
                b[nb] = *(const bf16x8*)(&Wt[nb * 16 + lrow][k0]);
#pragma unroll
            for (int rb = 0; rb < 2; rb++)
#pragma unroll
                for (int nb = 0; nb < 4; nb++)
                    acc[rb][nb] = __builtin_amdgcn_mfma_f32_16x16x32_bf16(a[rb], b[nb], acc[rb][nb], 0, 0, 0);
        }

        // epilogue: C[row= (lane>>4)*4+j, col= nb*16 + (lane&15)]
#pragma unroll
        for (int rb = 0; rb < 2; rb++) {
#pragma unroll
            for (int j = 0; j < 4; j++) {
                int node = rowbase + rb * 16 + (lane >> 4) * 4 + j;
                bool v = node < NI;
                int nn = v ? node : NI - 1;
                float mP = (v && (rpAll[nn + 1] > rpAll[nn])) ? 0.5f : 0.f;
                float mS = (v && (rpAll[NI + nn + 1] > rpAll[NI + nn])) ? 0.5f : 0.f;
#pragma unroll
                for (int nb = 0; nb < 4; nb++) {
                    int col = nb * 16 + lrow;
                    float x = inst[(size_t)nn * 64 + col] + acc[rb][nb][j] + mP * bp[col] + mS * bs[col];
                    x = elu1(x);
                    if (v) {
                        inst[(size_t)nn * 64 + col] = x;
                        inst_bf[(size_t)nn * 64 + col] = f2bf(x);
                    }
                }
            }
        }
    } else {
        // ---------- final-node path: thread = (node, j-quad) ----------
        int tid = (blockIdx.x - NBI) * 256 + t;     // 0 .. 31999
        int n = tid >> 4;                           // node 0..1999
        int jq = tid & 15;                          // j-quad 0..15
        const int* rpF = rpAll + 2 * NI;
        int cF = rpF[n + 1] - rpF[n];
        float mF = (cF > 0) ? 1.f : 0.f;
        float invF = 1.f / (float)max(cF, 1);

        float acc0 = bf[jq * 4 + 0], acc1 = bf[jq * 4 + 1];
        float acc2 = bf[jq * 4 + 2], acc3 = bf[jq * 4 + 3];
        const float* hrow = aggHf + (size_t)n * 64;
        for (int k = 0; k < 64; k++) {
            float h = hrow[k];
            float4 w = *(const float4*)(Wf + (size_t)k * 64 + jq * 4);
            acc0 += h * w.x; acc1 += h * w.y; acc2 += h * w.z; acc3 += h * w.w;
        }
        const float* erow = aggEf + (size_t)n * 8;
#pragma unroll
        for (int k = 0; k < 8; k++) {
            float h = erow[k] * invF;
            float4 w = *(const float4*)(Wf + (size_t)(64 + k) * 64 + jq * 4);
            acc0 += h * w.x; acc1 += h * w.y; acc2 += h * w.z; acc3 += h * w.w;
        }
        float4 fv = *(const float4*)(fin + (size_t)n * 64 + jq * 4);
        float4 o;
        o.x = elu1(fv.x + mF * acc0);
        o.y = elu1(fv.y + mF * acc1);
        o.z = elu1(fv.z + mF * acc2);
        o.w = elu1(fv.w + mF * acc3);
        *(float4*)(fin + (size_t)n * 64 + jq * 4) = o;
    }
}

// ---------------- readout head ----------------
__global__ __launch_bounds__(64, 1) void k_head(
    const float* __restrict__ fin,
    const float* __restrict__ Wr1, const float* __restrict__ br1,
    const float* __restrict__ Wr2, const float* __restrict__ br2,
    const float* __restrict__ Wr3, const float* __restrict__ br3,
    float* __restrict__ out) {
    __shared__ float hL[64 * 65];
    const int lane = threadIdx.x;
    const int base = blockIdx.x * 64;

    for (int idx = lane; idx < 1024; idx += 64) {
        int n = idx >> 4, k4 = idx & 15;
        float4 v = ((const float4*)fin)[(size_t)min(base + n, NF - 1) * 16 + k4];
        float* d = &hL[n * 65 + k4 * 4];
        d[0] = v.x; d[1] = v.y; d[2] = v.z; d[3] = v.w;
    }
    __syncthreads();

    float acc[64];
#pragma unroll
    for (int j = 0; j < 64; j++) acc[j] = br1[j];
#pragma unroll 4
    for (int k = 0; k < 64; k++) {
        float h = hL[lane * 65 + k];
#pragma unroll
        for (int j = 0; j < 64; j++) acc[j] += h * Wr1[k * 64 + j];
    }
#pragma unroll
    for (int j = 0; j < 64; j++) hL[lane * 65 + j] = elu1(acc[j]);

#pragma unroll
    for (int j = 0; j < 64; j++) acc[j] = br2[j];
#pragma unroll 4
    for (int k = 0; k < 64; k++) {
        float h = hL[lane * 65 + k];
#pragma unroll
        for (int j = 0; j < 64; j++) acc[j] += h * Wr2[k * 64 + j];
    }
    float r = br3[0];
#pragma unroll
    for (int j = 0; j < 64; j++) r += elu1(acc[j]) * Wr3[j];

    int i = base + lane;
    if (i < NF) out[i] = r;
}

extern "C" void kernel_launch(void* const* d_in, const int* in_sizes, int n_in,
                              void* d_out, int out_size, void* d_ws, size_t ws_size,
                              hipStream_t stream) {
    const float* xi  = (const float*)d_in[0];
    const float* xf  = (const float*)d_in[1];
    const float* xe  = (const float*)d_in[2];
    const float* xef = (const float*)d_in[3];
    const int* prev_src = (const int*)d_in[4];
    const int* prev_dst = (const int*)d_in[5];
    const int* tf_src = (const int*)d_in[6];
    const int* tf_dst = (const int*)d_in[7];
    const float* W_it = (const float*)d_in[8];  const float* b_it = (const float*)d_in[9];
    const float* W_ft = (const float*)d_in[10]; const float* b_ft = (const float*)d_in[11];
    const float* W_ep = (const float*)d_in[12]; const float* b_ep = (const float*)d_in[13];
    const float* W_es = (const float*)d_in[14]; const float* b_es = (const float*)d_in[15];
    const float* W_ef = (const float*)d_in[16]; const float* b_ef = (const float*)d_in[17];
    const float* Wg_prev = (const float*)d_in[18]; const float* bg_prev = (const float*)d_in[19];
    const float* Wg_succ = (const float*)d_in[20]; const float* bg_succ = (const float*)d_in[21];
    const float* Wg_tf   = (const float*)d_in[22]; const float* bg_tf   = (const float*)d_in[23];
    const float* Wr1 = (const float*)d_in[24]; const float* br1 = (const float*)d_in[25];
    const float* Wr2 = (const float*)d_in[26]; const float* br2 = (const float*)d_in[27];
    const float* Wr3 = (const float*)d_in[28]; const float* br3 = (const float*)d_in[29];

    char* ws = (char*)d_ws;
    size_t off = 0;
    auto alloc = [&](size_t bytes) -> char* {
        char* p = ws + off;
        off += (bytes + 255) & ~(size_t)255;
        return p;
    };
    float* inst  = (float*)alloc((size_t)NI * 64 * 4);
    unsigned short* inst_bf = (unsigned short*)alloc((size_t)NI * 64 * 2);
    unsigned short* X = (unsigned short*)alloc((size_t)NI * KX * 2);
    float* fin   = (float*)alloc((size_t)NF * 64 * 4);
    float* aggHf = (float*)alloc((size_t)NF * 64 * 4);
    float* aggEp = (float*)alloc((size_t)NI * 8 * 4);
    float* aggEs = (float*)alloc((size_t)NI * 8 * 4);
    float* aggEf = (float*)alloc((size_t)NF * 8 * 4);
    unsigned short* wcat = (unsigned short*)alloc((size_t)NL * WTN * 2);
    char* zero_begin = ws + off;
    int* cnt  = (int*)alloc((size_t)NT * 4);
    int* fill = (int*)alloc((size_t)NT * 4);
    char* zero_end = ws + off;
    int* rpAll = (int*)alloc((size_t)(NT + 1) * 4);
    int* colP = (int*)alloc((size_t)NE * 4);
    int* colS = (int*)alloc((size_t)NE * 4);
    int* colF = (int*)alloc((size_t)NEF * 4);
    int* bsum = (int*)alloc(1024 * 4);
    (void)ws_size; (void)in_sizes; (void)n_in; (void)out_size;

    // scatter-stage fp32 edge-embed buffers alias regions dead until after k_eagg2:
    //   ePbuf (NE*32B = 25.6MB)  -> X (32MB, live cols written by k_prep_x/spmm later)
    //   eSbuf (NE*32B = 25.6MB)  -> inst (25.6MB, first written by k_node_embed)
    //   eFbuf (NEF*32B = 6.4MB)  -> inst_bf (12.8MB, first written by k_node_embed)
    float* ePbuf = (float*)X;
    float* eSbuf = inst;
    float* eFbuf = (float*)inst_bf;

    hipMemsetAsync(zero_begin, 0, (size_t)(zero_end - zero_begin), stream);

    k_prep_w<<<(NL * WTN + 255) / 256, 256, 0, stream>>>(Wg_prev, Wg_succ, wcat);

    k_count<<<(NE + 255) / 256, 256, 0, stream>>>(prev_src, prev_dst, tf_dst, cnt);

    int nb = (NT + 255) / 256;
    k_scan1<<<nb, 256, 0, stream>>>(cnt, NT, rpAll, bsum);
    k_scan2<<<1, 1024, 0, stream>>>(bsum, nb);
    k_scan3<<<nb, 256, 0, stream>>>(rpAll, bsum, NT);

    k_scatter<<<(NE + 255) / 256, 256, 0, stream>>>(prev_src, prev_dst, tf_src, tf_dst,
                                                    xe, xef, rpAll, fill,
                                                    colP, colS, colF,
                                                    ePbuf, eSbuf, eFbuf,
                                                    W_ep, b_ep, W_es, b_es, W_ef, b_ef);

    k_eagg2<<<(NT + 255) / 256, 256, 0, stream>>>(rpAll, ePbuf, eSbuf, eFbuf,
                                                  aggEp, aggEs, aggEf);

    k_prep_x<<<(NI + 255) / 256, 256, 0, stream>>>(rpAll, aggEp, aggEs, X);

    {
        int waves = (NI + NF + 15) / 16;
        int blocks = (waves + 3) / 4;
        k_node_embed<<<blocks, 256, 0, stream>>>(xi, xf, W_it, b_it, W_ft, b_ft,
                                                 inst, inst_bf, fin);
    }

    for (int l = 0; l < NL; l++) {
        // 8 tasks per wave, 32 tasks per 256-thread block; F tasks first
        k_spmm<<<(NT + 31) / 32, 256, 0, stream>>>(inst_bf, rpAll,
                                                   colP, colS, colF,
                                                   X, aggHf);
        k_dense_layer<<<NBI + NBF, 256, 0, stream>>>(X, inst, inst_bf, rpAll,
                                                     wcat + (size_t)l * WTN,
                                                     bg_prev + (size_t)l * 64, bg_succ + (size_t)l * 64,
                                                     fin, aggHf, aggEf,
                                                     Wg_tf + (size_t)l * 72 * 64, bg_tf + (size_t)l * 64);
    }

    k_head<<<(NF + 63) / 64, 64, 0, stream>>>(fin, Wr1, br1, Wr2, br2, Wr3, br3, (float*)d_out);
}